// Round 1
// 377.893 us; speedup vs baseline: 1.0761x; 1.0761x over previous
//
#include <hip/hip_runtime.h>

#define N_ 16384
#define E_ 131072
#define G_ 32
#define EPSF 1e-5f

typedef unsigned short bf16u;
typedef __attribute__((ext_vector_type(8))) short s8v;   // 8 bf16 (4 VGPRs)
typedef __attribute__((ext_vector_type(4))) float f4v;   // 4 fp32 acc

__device__ __forceinline__ bf16u f2bf(float v) {
    union { float f; unsigned u; } x; x.f = v;
    unsigned r = x.u + 0x7FFF + ((x.u >> 16) & 1);   // RNE
    return (bf16u)(r >> 16);
}
__device__ __forceinline__ float bf2f(bf16u u) {
    union { unsigned u; float f; } x; x.u = (unsigned)u << 16;
    return x.f;
}

// ---------------- workspace layout (bytes) ----------------
static const size_t OFF_INDEG = 0;          // int[N]        } single
static const size_t OFF_ROWS  = 65536;      // int[N+1]      } memset
static const size_t OFF_CURSOR= 131584;     // int[N]        } covers
static const size_t OFF_CSR   = 197120;     // int[E]        } 0..OFF_XA1
static const size_t OFF_DIS   = 721408;     // float[N]
static const size_t OFF_ES    = 786944;     // float[4N]
static const size_t OFF_ED    = 1049088;    // float[4N]
static const size_t OFF_BNS   = 1311232;    // float[4][512]
static const size_t OFF_BNQ   = 1319424;    // float[4][512]
static const size_t OFF_GB    = 1327616;    // int[33]
static const size_t OFF_POOL  = 1327872;    // float[32*1024]
static const size_t OFF_XA1   = 1458944;    // (memset end marker)
static const size_t OFF_H1    = 1786624;    // float[64N]   4 MB
static const size_t OFF_AB    = 5980928;    // bf16[128N]   4 MB ([agg|h1] concat)
static const size_t OFF_H2P   = 10175232;   // bf16[128N]   4 MB (pre-BN)
static const size_t OFF_H2B   = 14369536;   // bf16[128N]   4 MB (post-BN)
static const size_t OFF_H3B   = 18563840;   // bf16[256N]   8 MB
static const size_t OFF_AGG   = 35328768;   // bf16[512N]  16 MB (GAT head-agg of h2b)
static const size_t OFF_XA4B  = 52105984;   // bf16[256N]   8 MB
static const size_t OFF_WT1   = 68883200;   // bf16[256*512] (0.25*gat_w stacked-head ^T)
static const size_t OFF_WT2   = 69145344;   // bf16[512*256]
static const size_t OFF_WT3   = 69407488;   // bf16[128*128]
static const size_t OFF_H4B   = 69440256;   // bf16[512N] 16 MB
static const size_t OFF_VES   = 86479616;   // float[4][128]  W_h·a_src_h
static const size_t OFF_VED   = 86481664;   // float[4][128]  W_h·a_dst_h
// total ≈ 86.5 MB

// scan + fused dis + cursor copy
__global__ __launch_bounds__(1024) void k_scan(const int* __restrict__ indeg,
                                               int* __restrict__ rows,
                                               int* __restrict__ cursor,
                                               float* __restrict__ dis) {
    __shared__ int part[1024];
    int t = threadIdx.x;
    int base = t * 16;
    int local[16];
    int s = 0;
#pragma unroll
    for (int i = 0; i < 16; ++i) {
        local[i] = indeg[base + i]; s += local[i];
        dis[base + i] = rsqrtf((float)local[i] + 1.0f);
    }
    part[t] = s;
    __syncthreads();
    for (int off = 1; off < 1024; off <<= 1) {
        int v = (t >= off) ? part[t - off] : 0;
        __syncthreads();
        part[t] += v;
        __syncthreads();
    }
    int run = (t == 0) ? 0 : part[t - 1];
#pragma unroll
    for (int i = 0; i < 16; ++i) {
        rows[base + i] = run; cursor[base + i] = run; run += local[i];
    }
    if (t == 1023) rows[N_] = run;
}

__global__ void k_fill(const int* __restrict__ src, const int* __restrict__ dst,
                       int* __restrict__ cursor, int* __restrict__ csr) {
    int e = blockIdx.x * 256 + threadIdx.x;
    if (e < E_) {
        int p = atomicAdd(&cursor[dst[e]], 1);
        csr[p] = src[e];
    }
}

// ------- fused setup: weight transpose/convert + gbounds + v_es/v_ed + indeg -------
// wT1 is the stacked-head GAT weight for the post-aggregation GEMM:
//   wT1[c][h*128+k] = 0.25 * gat_w[k][h*256+c]   (BT layout, [256][512])
// v_es[h][k] = sum_c gat_w[k][h*256+c]*asrc[h][c]: attention-by-associativity —
// lets es/ed be computed from h2b (4 MB) instead of the projected features.
__global__ void k_wconv_all(const float* __restrict__ gat_w,
                            const float* __restrict__ gcn4_w,
                            const float* __restrict__ wl, const float* __restrict__ wr,
                            const int* __restrict__ batch,
                            const float* __restrict__ gat_as,
                            const float* __restrict__ gat_ad,
                            const int* __restrict__ dstE,
                            bf16u* __restrict__ wT1, bf16u* __restrict__ wT2,
                            bf16u* __restrict__ wT3, int* __restrict__ gb,
                            float* __restrict__ ves, float* __restrict__ ved,
                            int* __restrict__ indeg) {
    int idx = blockIdx.x * 256 + threadIdx.x;
    if (idx < 131072) {          // gat_w [128][1024] -> wT1[c][h*128+k] (stacked heads, /4)
        int c = idx >> 9;                        // output channel 0..255
        int kk = idx & 511;                      // h*128+k
        int h = kk >> 7, k = kk & 127;
        wT1[idx] = f2bf(0.25f * gat_w[(size_t)k * 1024 + h * 256 + c]);
    } else if (idx < 262144) {   // gcn4_w [256][512] -> wT2[512][256]
        int j = idx - 131072;
        int m = j >> 8, k = j & 255;
        wT2[j] = f2bf(gcn4_w[(size_t)k * 512 + m]);
    } else if (idx < 278528) {   // [wl;wr] -> wT3[128][128]
        int j = idx - 262144;
        int m = j >> 7, k = j & 127;
        float v = (k < 64) ? wl[k*128 + m] : wr[(k-64)*128 + m];
        wT3[j] = f2bf(v);
    } else if (idx < 278592) {   // graph-batch bounds
        int g = idx - 278528;
        if (g > G_) return;
        if (g == G_) { gb[G_] = N_; return; }
        int lo = 0, hi = N_;
        while (lo < hi) { int mid = (lo + hi) >> 1; if (batch[mid] < g) lo = mid + 1; else hi = mid; }
        gb[g] = lo;
    } else if (idx < 279104) {   // v_es (4 heads x 128 k)
        int j = idx - 278592;
        int h = j >> 7, k = j & 127;
        float s = 0.f;
        for (int c = 0; c < 256; ++c)
            s += gat_w[(size_t)k * 1024 + h*256 + c] * gat_as[h*256 + c];
        ves[j] = s;
    } else if (idx < 279616) {   // v_ed
        int j = idx - 279104;
        int h = j >> 7, k = j & 127;
        float s = 0.f;
        for (int c = 0; c < 256; ++c)
            s += gat_w[(size_t)k * 1024 + h*256 + c] * gat_ad[h*256 + c];
        ved[j] = s;
    } else if (idx < 410688) {   // indeg (was k_indeg)
        int e = idx - 279616;
        atomicAdd(&indeg[dstE[e]], 1);
    }
}

// ---------------- layer 1: fused GCN aggregate(5) + matmul(5->64), wave-per-node ----------------
__global__ __launch_bounds__(256) void k_gcn1(const float* __restrict__ x,
                                              const float* __restrict__ dis,
                                              const int* __restrict__ rows,
                                              const int* __restrict__ csr,
                                              const float* __restrict__ w,
                                              const float* __restrict__ b,
                                              float* __restrict__ h1) {
    int wave = threadIdx.x >> 6, lane = threadIdx.x & 63;
    int i = blockIdx.x * 4 + wave;
    float a0=0,a1=0,a2=0,a3=0,a4=0;
    int e0 = rows[i], e1 = rows[i+1];
    for (int e = e0 + lane; e < e1; e += 64) {
        int s = csr[e];
        float wt = dis[s];
        a0 += x[s*5+0]*wt; a1 += x[s*5+1]*wt; a2 += x[s*5+2]*wt;
        a3 += x[s*5+3]*wt; a4 += x[s*5+4]*wt;
    }
#pragma unroll
    for (int off = 32; off > 0; off >>= 1) {
        a0 += __shfl_xor(a0, off, 64); a1 += __shfl_xor(a1, off, 64);
        a2 += __shfl_xor(a2, off, 64); a3 += __shfl_xor(a3, off, 64);
        a4 += __shfl_xor(a4, off, 64);
    }
    float di = dis[i];
    float xa0 = di*(a0 + di*x[i*5+0]);
    float xa1v = di*(a1 + di*x[i*5+1]);
    float xa2 = di*(a2 + di*x[i*5+2]);
    float xa3 = di*(a3 + di*x[i*5+3]);
    float xa4 = di*(a4 + di*x[i*5+4]);
    float hv = b[lane] + xa0*w[lane] + xa1v*w[64+lane] + xa2*w[128+lane]
             + xa3*w[192+lane] + xa4*w[256+lane];
    h1[(size_t)i*64 + lane] = hv;
}

// ---------------- batchnorm stats (fp32, C=64) ----------------
__global__ void k_bn_stats(const float* __restrict__ x, float* __restrict__ sum,
                           float* __restrict__ sumsq, int C, int rowsPerBlock) {
    int t = threadIdx.x;
    size_t base = (size_t)blockIdx.x * rowsPerBlock * C;
    size_t end  = base + (size_t)rowsPerBlock * C;
    float s0=0,q0=0;
    for (size_t f = base + t; f < end; f += 256) {
        float v = x[f]; s0 += v; q0 += v*v;
    }
    __shared__ float ls[256], lq[256];
    ls[t]=s0; lq[t]=q0;
    __syncthreads();
    if (t < C) {
        for (int j = t + C; j < 256; j += C) { s0 += ls[j]; q0 += lq[j]; }
        atomicAdd(&sum[t], s0); atomicAdd(&sumsq[t], q0);
    }
}

// ---------------- batchnorm stats (bf16, C=128/256/512) ----------------
__global__ void k_bn_stats_b(const bf16u* __restrict__ x, float* __restrict__ sum,
                             float* __restrict__ sumsq, int C, int rowsPerBlock) {
    int t = threadIdx.x;
    size_t base = (size_t)blockIdx.x * rowsPerBlock * C;
    size_t end  = base + (size_t)rowsPerBlock * C;
    if (C == 512) {
        float s0=0,q0=0,s1=0,q1=0;
        for (size_t f = base + t; f < end; f += 512) {
            float v = bf2f(x[f]);     s0 += v; q0 += v*v;
            float w = bf2f(x[f+256]); s1 += w; q1 += w*w;
        }
        atomicAdd(&sum[t], s0);      atomicAdd(&sumsq[t], q0);
        atomicAdd(&sum[t+256], s1);  atomicAdd(&sumsq[t+256], q1);
    } else {  // C <= 256
        float s0=0,q0=0;
        for (size_t f = base + t; f < end; f += 256) {
            float v = bf2f(x[f]); s0 += v; q0 += v*v;
        }
        atomicAdd(&sum[t & (C-1)], s0); atomicAdd(&sumsq[t & (C-1)], q0);
    }
}

// ---------------- BN1 apply: fp32 h1 -> bf16 mirror in ab[:,64:128] only ----------------
__global__ void k_bn_apply1(const float* __restrict__ h, const float* __restrict__ sum,
                            const float* __restrict__ sumsq, const float* __restrict__ g,
                            const float* __restrict__ b, bf16u* __restrict__ ab) {
    int idx = blockIdx.x * 256 + threadIdx.x;   // N*64
    int c = idx & 63, row = idx >> 6;
    const float invN = 1.0f / (float)N_;
    float mu  = sum[c] * invN;
    float var = sumsq[c] * invN - mu * mu;
    float v = (h[idx] - mu) * rsqrtf(var + EPSF) * g[c] + b[c];
    v = v > 0.f ? v : 0.f;
    ab[(size_t)row * 128 + 64 + c] = f2bf(v);
}

// ---------------- BN2 apply + fused GAT attention coefficients (wave-per-node) ----------------
// es[i,h] = h2b[i,:]·v_es[h] (associativity: (A·W)·a = A·(W·a)) — reads 4 MB h2p.
__global__ __launch_bounds__(256) void k_bn_apply2b_attn(
        const bf16u* __restrict__ hp, const float* __restrict__ sum,
        const float* __restrict__ sumsq, const float* __restrict__ g,
        const float* __restrict__ b, const float* __restrict__ ves,
        const float* __restrict__ ved, bf16u* __restrict__ hb,
        float* __restrict__ es, float* __restrict__ ed) {
    int wave = threadIdx.x >> 6, lane = threadIdx.x & 63;
    int i = blockIdx.x * 4 + wave;
    int c = lane * 2;
    const float invN = 1.0f / (float)N_;
    float2 sm = *(const float2*)&sum[c];
    float2 sq = *(const float2*)&sumsq[c];
    float2 gg = *(const float2*)&g[c];
    float2 bb = *(const float2*)&b[c];
    float mu0 = sm.x*invN, mu1 = sm.y*invN;
    float sc0 = rsqrtf(sq.x*invN - mu0*mu0 + EPSF)*gg.x, sh0 = bb.x - mu0*sc0;
    float sc1 = rsqrtf(sq.y*invN - mu1*mu1 + EPSF)*gg.y, sh1 = bb.y - mu1*sc1;
    unsigned pv = *(const unsigned*)&hp[(size_t)i*128 + c];
    float v0 = bf2f((bf16u)(pv & 0xFFFF));
    float v1 = bf2f((bf16u)(pv >> 16));
    v0 = fmaf(v0, sc0, sh0); v0 = v0 > 0.f ? v0 : 0.f;
    v1 = fmaf(v1, sc1, sh1); v1 = v1 > 0.f ? v1 : 0.f;
    unsigned ow = (unsigned)f2bf(v0) | ((unsigned)f2bf(v1) << 16);
    *(unsigned*)&hb[(size_t)i*128 + c] = ow;
    float vs[4], vd[4];
#pragma unroll
    for (int h = 0; h < 4; ++h) {
        float2 a = *(const float2*)&ves[h*128 + c];
        float2 d = *(const float2*)&ved[h*128 + c];
        vs[h] = v0*a.x + v1*a.y;
        vd[h] = v0*d.x + v1*d.y;
    }
#pragma unroll
    for (int off = 32; off > 0; off >>= 1) {
#pragma unroll
        for (int h = 0; h < 4; ++h) {
            vs[h] += __shfl_xor(vs[h], off, 64);
            vd[h] += __shfl_xor(vd[h], off, 64);
        }
    }
    if (lane == 0) {
        *(float4*)&es[i*4] = make_float4(vs[0], vs[1], vs[2], vs[3]);
        *(float4*)&ed[i*4] = make_float4(vd[0], vd[1], vd[2], vd[3]);
    }
}

// ---------------- SAGE aggregate (mean) from bf16 mirror -> ab[:,0:64] ----------------
__global__ void k_sage_agg(const int* __restrict__ rows, const int* __restrict__ csr,
                           bf16u* __restrict__ ab) {
    int i = blockIdx.x * 4 + (threadIdx.x >> 6);
    int c = threadIdx.x & 63;
    int e0 = rows[i], e1 = rows[i+1];
    float s = 0.f;
    for (int e = e0; e < e1; ++e) s += bf2f(ab[(size_t)csr[e]*128 + 64 + c]);
    ab[(size_t)i*128 + c] = f2bf(s / fmaxf((float)(e1 - e0), 1.0f));
}

// ---------------- bf16 MFMA GEMM: C[n,m] = A[n,k]*BT[m,k]^T (+bias) ----------------
// 128x128 tile, BK=32, 4 waves x (4x4) mfma_f32_16x16x32_bf16 (layouts m89/m91/m120).
__global__ __launch_bounds__(256) void k_gemm_mfma(const bf16u* __restrict__ A,
                                                   const bf16u* __restrict__ BT,
                                                   const float* __restrict__ bias,
                                                   float* __restrict__ C,
                                                   int K, int M, int obf) {
    __shared__ bf16u As[128][40];
    __shared__ bf16u Bs[128][40];
    int tid = threadIdx.x;
    int wave = tid >> 6, lane = tid & 63;
    int wr = (wave >> 1) * 64, wc = (wave & 1) * 64;
    int row0 = blockIdx.y * 128, col0 = blockIdx.x * 128;
    f4v acc[4][4];
#pragma unroll
    for (int i = 0; i < 4; ++i)
#pragma unroll
        for (int j = 0; j < 4; ++j) acc[i][j] = (f4v)0.0f;

    int sr = tid >> 1;             // 0..127
    int sh = (tid & 1) * 16;       // k-half within BK
    int lr = lane & 15, lq = lane >> 4;

    for (int k0 = 0; k0 < K; k0 += 32) {
        const bf16u* ap = A + (size_t)(row0 + sr) * K + k0 + sh;
        *(uint4*)&As[sr][sh]     = *(const uint4*)ap;
        *(uint4*)&As[sr][sh + 8] = *(const uint4*)(ap + 8);
        const bf16u* bp = BT + (size_t)(col0 + sr) * K + k0 + sh;
        *(uint4*)&Bs[sr][sh]     = *(const uint4*)bp;
        *(uint4*)&Bs[sr][sh + 8] = *(const uint4*)(bp + 8);
        __syncthreads();
        s8v af[4], bfr[4];
#pragma unroll
        for (int i = 0; i < 4; ++i)
            af[i] = *(const s8v*)&As[wr + i*16 + lr][lq*8];
#pragma unroll
        for (int j = 0; j < 4; ++j)
            bfr[j] = *(const s8v*)&Bs[wc + j*16 + lr][lq*8];
#pragma unroll
        for (int i = 0; i < 4; ++i)
#pragma unroll
            for (int j = 0; j < 4; ++j)
                acc[i][j] = __builtin_amdgcn_mfma_f32_16x16x32_bf16(af[i], bfr[j], acc[i][j], 0, 0, 0);
        __syncthreads();
    }

    if (obf) {
        bf16u* Cb = (bf16u*)C;
#pragma unroll
        for (int i = 0; i < 4; ++i)
#pragma unroll
            for (int j = 0; j < 4; ++j) {
                int col = col0 + wc + j*16 + lr;
                float bv = bias ? bias[col] : 0.f;
#pragma unroll
                for (int r = 0; r < 4; ++r) {
                    int row = row0 + wr + i*16 + lq*4 + r;
                    Cb[(size_t)row * M + col] = f2bf(acc[i][j][r] + bv);
                }
            }
    } else {
#pragma unroll
        for (int i = 0; i < 4; ++i)
#pragma unroll
            for (int j = 0; j < 4; ++j) {
                int col = col0 + wc + j*16 + lr;
                float bv = bias ? bias[col] : 0.f;
#pragma unroll
                for (int r = 0; r < 4; ++r) {
                    int row = row0 + wr + i*16 + lq*4 + r;
                    C[(size_t)row * M + col] = acc[i][j][r] + bv;
                }
            }
    }
}

// ---------------- GAT: fused max + single-pass softmax aggregation of h2b ----------------
// Associativity: mean_h Σ_s α_h(s,i)(h2b[s]·W_h) = mean_h (Σ_s α_h h2b[s])·W_h.
// Aggregate the 128-dim h2b (4 MB, L2/L3-resident) instead of the 1024-dim
// projection (32 MB) — 8× less gather traffic, and the 128→1024 GEMM becomes
// a 512→256 GEMM on agg. Wave-per-node; pass 1 = lane-parallel logit max,
// pass 2 = serial edge loop, lanes own 2 channels × 4 heads.
__global__ __launch_bounds__(256) void k_gat_agg2(const bf16u* __restrict__ h2b,
                                                  const float* __restrict__ es,
                                                  const float* __restrict__ ed,
                                                  const int* __restrict__ rows,
                                                  const int* __restrict__ csr,
                                                  bf16u* __restrict__ agg) {
    int wave = threadIdx.x >> 6, lane = threadIdx.x & 63;
    int i = blockIdx.x * 4 + wave;
    int c = lane * 2;
    float4 edv = *(const float4*)&ed[i*4];
    float4 sv  = *(const float4*)&es[i*4];
    int e0 = rows[i], e1 = rows[i+1];
    // ---- pass 1: exact per-node logit max (incl self-loop), lane-parallel ----
    float e, m0, m1, m2, m3;
    e = sv.x + edv.x; m0 = e >= 0.f ? e : 0.2f*e;
    e = sv.y + edv.y; m1 = e >= 0.f ? e : 0.2f*e;
    e = sv.z + edv.z; m2 = e >= 0.f ? e : 0.2f*e;
    e = sv.w + edv.w; m3 = e >= 0.f ? e : 0.2f*e;
    for (int ee = e0 + lane; ee < e1; ee += 64) {
        int s = csr[ee];
        float4 s2 = *(const float4*)&es[s*4];
        e = s2.x + edv.x; m0 = fmaxf(m0, e >= 0.f ? e : 0.2f*e);
        e = s2.y + edv.y; m1 = fmaxf(m1, e >= 0.f ? e : 0.2f*e);
        e = s2.z + edv.z; m2 = fmaxf(m2, e >= 0.f ? e : 0.2f*e);
        e = s2.w + edv.w; m3 = fmaxf(m3, e >= 0.f ? e : 0.2f*e);
    }
#pragma unroll
    for (int off = 32; off > 0; off >>= 1) {
        m0 = fmaxf(m0, __shfl_xor(m0, off, 64));
        m1 = fmaxf(m1, __shfl_xor(m1, off, 64));
        m2 = fmaxf(m2, __shfl_xor(m2, off, 64));
        m3 = fmaxf(m3, __shfl_xor(m3, off, 64));
    }
    // ---- pass 2: softmax-weighted aggregation (serial edges, lanes = channels) ----
    float z0, z1, z2, z3;
    float a00, a01, a10, a11, a20, a21, a30, a31;
    {
        e = sv.x + edv.x; e = e >= 0.f ? e : 0.2f*e; z0 = __expf(e - m0);
        e = sv.y + edv.y; e = e >= 0.f ? e : 0.2f*e; z1 = __expf(e - m1);
        e = sv.z + edv.z; e = e >= 0.f ? e : 0.2f*e; z2 = __expf(e - m2);
        e = sv.w + edv.w; e = e >= 0.f ? e : 0.2f*e; z3 = __expf(e - m3);
        unsigned pv = *(const unsigned*)&h2b[(size_t)i*128 + c];
        float v0 = bf2f((bf16u)(pv & 0xFFFF)), v1 = bf2f((bf16u)(pv >> 16));
        a00 = z0*v0; a01 = z0*v1; a10 = z1*v0; a11 = z1*v1;
        a20 = z2*v0; a21 = z2*v1; a30 = z3*v0; a31 = z3*v1;
    }
    for (int ee = e0; ee < e1; ++ee) {
        int s = csr[ee];
        float4 s2 = *(const float4*)&es[s*4];
        unsigned pv = *(const unsigned*)&h2b[(size_t)s*128 + c];
        float v0 = bf2f((bf16u)(pv & 0xFFFF)), v1 = bf2f((bf16u)(pv >> 16));
        float ex;
        e = s2.x + edv.x; e = e >= 0.f ? e : 0.2f*e; ex = __expf(e - m0);
        z0 += ex; a00 = fmaf(ex, v0, a00); a01 = fmaf(ex, v1, a01);
        e = s2.y + edv.y; e = e >= 0.f ? e : 0.2f*e; ex = __expf(e - m1);
        z1 += ex; a10 = fmaf(ex, v0, a10); a11 = fmaf(ex, v1, a11);
        e = s2.z + edv.z; e = e >= 0.f ? e : 0.2f*e; ex = __expf(e - m2);
        z2 += ex; a20 = fmaf(ex, v0, a20); a21 = fmaf(ex, v1, a21);
        e = s2.w + edv.w; e = e >= 0.f ? e : 0.2f*e; ex = __expf(e - m3);
        z3 += ex; a30 = fmaf(ex, v0, a30); a31 = fmaf(ex, v1, a31);
    }
    size_t base = (size_t)i * 512 + c;
    float r; unsigned ow;
    r = 1.f/z0; ow = (unsigned)f2bf(a00*r) | ((unsigned)f2bf(a01*r) << 16);
    *(unsigned*)&agg[base]       = ow;
    r = 1.f/z1; ow = (unsigned)f2bf(a10*r) | ((unsigned)f2bf(a11*r) << 16);
    *(unsigned*)&agg[base + 128] = ow;
    r = 1.f/z2; ow = (unsigned)f2bf(a20*r) | ((unsigned)f2bf(a21*r) << 16);
    *(unsigned*)&agg[base + 256] = ow;
    r = 1.f/z3; ow = (unsigned)f2bf(a30*r) | ((unsigned)f2bf(a31*r) << 16);
    *(unsigned*)&agg[base + 384] = ow;
}

// ---------------- layer 4: fused BN3+ReLU + GCN aggregate (wave-per-node, ushort4) ----------------
__global__ __launch_bounds__(256) void k_gcn4_agg(const bf16u* __restrict__ h3b,
                                                  const float* __restrict__ dis,
                                                  const int* __restrict__ rows,
                                                  const int* __restrict__ csr,
                                                  const float* __restrict__ sum,
                                                  const float* __restrict__ sumsq,
                                                  const float* __restrict__ g,
                                                  const float* __restrict__ b,
                                                  bf16u* __restrict__ xab) {
    int wave = threadIdx.x >> 6, q = threadIdx.x & 63;
    int i = blockIdx.x * 4 + wave;
    int c = q * 4;
    const float invN = 1.0f / (float)N_;
    float4 sm = *(const float4*)&sum[c];
    float4 sq = *(const float4*)&sumsq[c];
    float4 gg = *(const float4*)&g[c];
    float4 bb = *(const float4*)&b[c];
    float mu, sc0, sc1, sc2, sc3, sh0, sh1, sh2, sh3;
    mu = sm.x*invN; sc0 = rsqrtf(sq.x*invN - mu*mu + EPSF)*gg.x; sh0 = bb.x - mu*sc0;
    mu = sm.y*invN; sc1 = rsqrtf(sq.y*invN - mu*mu + EPSF)*gg.y; sh1 = bb.y - mu*sc1;
    mu = sm.z*invN; sc2 = rsqrtf(sq.z*invN - mu*mu + EPSF)*gg.z; sh2 = bb.z - mu*sc2;
    mu = sm.w*invN; sc3 = rsqrtf(sq.w*invN - mu*mu + EPSF)*gg.w; sh3 = bb.w - mu*sc3;
    float di = dis[i];
    float a0, a1, a2, a3;
    {
        ushort4 u = *(const ushort4*)(h3b + (size_t)i*256 + c);
        float v, dd = di * di;
        v = fmaf(bf2f(u.x), sc0, sh0); v = v > 0.f ? v : 0.f; a0 = v * dd;
        v = fmaf(bf2f(u.y), sc1, sh1); v = v > 0.f ? v : 0.f; a1 = v * dd;
        v = fmaf(bf2f(u.z), sc2, sh2); v = v > 0.f ? v : 0.f; a2 = v * dd;
        v = fmaf(bf2f(u.w), sc3, sh3); v = v > 0.f ? v : 0.f; a3 = v * dd;
    }
    int e0 = rows[i], e1 = rows[i+1];
    for (int e = e0; e < e1; ++e) {
        int s = csr[e];
        float w = dis[s] * di;
        ushort4 u = *(const ushort4*)(h3b + (size_t)s*256 + c);
        float v;
        v = fmaf(bf2f(u.x), sc0, sh0); v = v > 0.f ? v : 0.f; a0 += v * w;
        v = fmaf(bf2f(u.y), sc1, sh1); v = v > 0.f ? v : 0.f; a1 += v * w;
        v = fmaf(bf2f(u.z), sc2, sh2); v = v > 0.f ? v : 0.f; a2 += v * w;
        v = fmaf(bf2f(u.w), sc3, sh3); v = v > 0.f ? v : 0.f; a3 += v * w;
    }
    ushort4 o;
    o.x = f2bf(a0); o.y = f2bf(a1); o.z = f2bf(a2); o.w = f2bf(a3);
    *(ushort4*)(xab + (size_t)i*256 + c) = o;
}

// ---------------- pooling with fused BN4+ReLU (+ folded fc-init blocks) ----------------
__global__ void k_pool(const bf16u* __restrict__ h4b, const int* __restrict__ gb,
                       const float* __restrict__ sum, const float* __restrict__ sumsq,
                       const float* __restrict__ g, const float* __restrict__ b,
                       const float* __restrict__ fcb,
                       float* __restrict__ pooled, float* __restrict__ out) {
    int bidx = blockIdx.x;
    int t = threadIdx.x;
    if (bidx >= 512) {                 // fc-init: out = bias (independent work)
        int i = (bidx - 512) * 256 + t;
        out[i] = fcb[i & 1023];
        return;
    }
    int gi = bidx >> 4;
    int chunk = bidx & 15;
    const float invN = 1.0f / (float)N_;
    float mu0 = sum[t] * invN;
    float sc0 = rsqrtf(sumsq[t] * invN - mu0*mu0 + EPSF) * g[t];
    float sh0 = b[t] - mu0 * sc0;
    float mu1 = sum[t+256] * invN;
    float sc1 = rsqrtf(sumsq[t+256] * invN - mu1*mu1 + EPSF) * g[t+256];
    float sh1 = b[t+256] - mu1 * sc1;
    int r0g = gb[gi], r1g = gb[gi+1];
    int n = r1g - r0g;
    if (n <= 0) return;
    int per = (n + 15) >> 4;
    int r0 = r0g + chunk * per;
    int r1 = min(r0 + per, r1g);
    if (r0 >= r1) return;
    float s0=0.f, s1=0.f, m0=0.f, m1=0.f;   // post-ReLU >= 0: max init 0 valid
    for (int r = r0; r < r1; ++r) {
        float v = fmaf(bf2f(h4b[(size_t)r*512 + t]), sc0, sh0);
        v = v > 0.f ? v : 0.f;
        s0 += v; m0 = fmaxf(m0, v);
        float w = fmaf(bf2f(h4b[(size_t)r*512 + 256 + t]), sc1, sh1);
        w = w > 0.f ? w : 0.f;
        s1 += w; m1 = fmaxf(m1, w);
    }
    atomicAdd(&pooled[gi*1024 + t], s0);
    atomicAdd(&pooled[gi*1024 + 256 + t], s1);
    atomicMax((int*)&pooled[gi*1024 + 512 + t],  __float_as_int(m0));
    atomicMax((int*)&pooled[gi*1024 + 768 + t],  __float_as_int(m1));
}

// ---------------- FC (K-split, float4, atomic reduce; mean-scale folded in) ----------------
#define FCKZ 16
#define FCKC (1024 / FCKZ)   // 64

__global__ __launch_bounds__(256) void k_fc2(const float* __restrict__ pooled,
                                             const float* __restrict__ w,
                                             const int* __restrict__ gb,
                                             float* __restrict__ out) {
    __shared__ float pr[FCKC];
    int g = blockIdx.x;
    int z = blockIdx.y;
    int t = threadIdx.x;
    int k0 = z * FCKC;
    if (t < FCKC) {
        float scale = (z < 8) ? 1.0f / fmaxf((float)(gb[g+1] - gb[g]), 1.0f) : 1.0f;
        pr[t] = pooled[g * 1024 + k0 + t] * scale;   // mean part needs 1/cnt
    }
    __syncthreads();
    int m0 = t * 4;
    float ax = 0.f, ay = 0.f, az = 0.f, aw = 0.f;
#pragma unroll 8
    for (int k = 0; k < FCKC; ++k) {
        const float4 wv = *(const float4*)&w[(size_t)(k0 + k) * 1024 + m0];
        float p = pr[k];
        ax += p * wv.x; ay += p * wv.y; az += p * wv.z; aw += p * wv.w;
    }
    atomicAdd(&out[g * 1024 + m0 + 0], ax);
    atomicAdd(&out[g * 1024 + m0 + 1], ay);
    atomicAdd(&out[g * 1024 + m0 + 2], az);
    atomicAdd(&out[g * 1024 + m0 + 3], aw);
}

// ---------------- host ----------------
extern "C" void kernel_launch(void* const* d_in, const int* in_sizes, int n_in,
                              void* d_out, int out_size, void* d_ws, size_t ws_size,
                              hipStream_t stream) {
    (void)in_sizes; (void)n_in; (void)out_size; (void)ws_size;
    const float* x       = (const float*)d_in[0];
    const int*   ei      = (const int*)d_in[1];
    const int*   batch   = (const int*)d_in[2];
    const float* gcn1_w  = (const float*)d_in[3];
    const float* gcn1_b  = (const float*)d_in[4];
    const float* sage_wl = (const float*)d_in[5];
    const float* sage_wr = (const float*)d_in[6];
    const float* sage_b  = (const float*)d_in[7];
    const float* gat_w   = (const float*)d_in[8];
    const float* gat_as  = (const float*)d_in[9];
    const float* gat_ad  = (const float*)d_in[10];
    const float* gat_b   = (const float*)d_in[11];
    const float* gcn4_w  = (const float*)d_in[12];
    const float* gcn4_b  = (const float*)d_in[13];
    const float* bn1_g   = (const float*)d_in[14];
    const float* bn1_b   = (const float*)d_in[15];
    const float* bn2_g   = (const float*)d_in[16];
    const float* bn2_b   = (const float*)d_in[17];
    const float* bn3_g   = (const float*)d_in[18];
    const float* bn3_b   = (const float*)d_in[19];
    const float* bn4_g   = (const float*)d_in[20];
    const float* bn4_b   = (const float*)d_in[21];
    const float* fc_w    = (const float*)d_in[22];
    const float* fc_b    = (const float*)d_in[23];
    float* out = (float*)d_out;

    char* w8 = (char*)d_ws;
    int*   indeg  = (int*)(w8 + OFF_INDEG);
    int*   rows   = (int*)(w8 + OFF_ROWS);
    int*   cursor = (int*)(w8 + OFF_CURSOR);
    int*   csr    = (int*)(w8 + OFF_CSR);
    float* dis    = (float*)(w8 + OFF_DIS);
    float* es     = (float*)(w8 + OFF_ES);
    float* ed     = (float*)(w8 + OFF_ED);
    float* bns    = (float*)(w8 + OFF_BNS);   // [4][512] per-layer slices
    float* bnq    = (float*)(w8 + OFF_BNQ);
    int*   gb     = (int*)(w8 + OFF_GB);
    float* pooled = (float*)(w8 + OFF_POOL);
    float* h1     = (float*)(w8 + OFF_H1);
    bf16u* ab     = (bf16u*)(w8 + OFF_AB);
    bf16u* h2p    = (bf16u*)(w8 + OFF_H2P);
    bf16u* h2b    = (bf16u*)(w8 + OFF_H2B);
    bf16u* h3b    = (bf16u*)(w8 + OFF_H3B);
    bf16u* agg    = (bf16u*)(w8 + OFF_AGG);
    bf16u* xa4b   = (bf16u*)(w8 + OFF_XA4B);
    bf16u* wT1    = (bf16u*)(w8 + OFF_WT1);
    bf16u* wT2    = (bf16u*)(w8 + OFF_WT2);
    bf16u* wT3    = (bf16u*)(w8 + OFF_WT3);
    bf16u* h4b    = (bf16u*)(w8 + OFF_H4B);
    float* ves    = (float*)(w8 + OFF_VES);
    float* ved    = (float*)(w8 + OFF_VED);

    const int* srcE = ei;        // edge_index[0,:]
    const int* dstE = ei + E_;   // edge_index[1,:]

    const int BNB = 512;
    const int BNR = N_ / BNB;

    // ---- setup: ONE memset, then fused setup kernel (weights+gbounds+ves/ved+indeg) ----
    hipMemsetAsync(w8, 0, OFF_XA1, stream);
    k_wconv_all<<<1605, 256, 0, stream>>>(gat_w, gcn4_w, sage_wl, sage_wr, batch,
                                          gat_as, gat_ad, dstE,
                                          wT1, wT2, wT3, gb, ves, ved, indeg);
    k_scan<<<1, 1024, 0, stream>>>(indeg, rows, cursor, dis);
    k_fill<<<E_/256, 256, 0, stream>>>(srcE, dstE, cursor, csr);

    // ---- layer 1: fused GCN 5->64 (agg+matmul), BN, ReLU (bf16 mirror only) ----
    k_gcn1<<<N_/4, 256, 0, stream>>>(x, dis, rows, csr, gcn1_w, gcn1_b, h1);
    k_bn_stats<<<BNB, 256, 0, stream>>>(h1, bns, bnq, 64, BNR);
    k_bn_apply1<<<(N_*64)/256, 256, 0, stream>>>(h1, bns, bnq, bn1_g, bn1_b, ab);

    // ---- layer 2: SAGE 64->128 via single MFMA GEMM on [agg|h1], BN+attn fused ----
    k_sage_agg<<<N_/4, 256, 0, stream>>>(rows, csr, ab);
    {
        dim3 grid(1, N_/128);
        k_gemm_mfma<<<grid, 256, 0, stream>>>(ab, wT3, sage_b, (float*)h2p, 128, 128, 1);
    }
    k_bn_stats_b<<<BNB, 256, 0, stream>>>(h2p, bns + 512, bnq + 512, 128, BNR);
    k_bn_apply2b_attn<<<N_/4, 256, 0, stream>>>(h2p, bns + 512, bnq + 512, bn2_g, bn2_b,
                                                ves, ved, h2b, es, ed);

    // ---- layer 3: GAT — aggregate h2b per head (fused max+softmax), then 512->256 GEMM ----
    k_gat_agg2<<<N_/4, 256, 0, stream>>>(h2b, es, ed, rows, csr, agg);
    {
        dim3 grid(256/128, N_/128);
        k_gemm_mfma<<<grid, 256, 0, stream>>>(agg, wT1, gat_b, (float*)h3b, 512, 256, 1);
    }
    k_bn_stats_b<<<BNB, 256, 0, stream>>>(h3b, bns + 1024, bnq + 1024, 256, BNR);

    // ---- layer 4: fused BN3+ReLU+aggregate, MFMA GEMM 256->512 (bf16 out) ----
    k_gcn4_agg<<<N_/4, 256, 0, stream>>>(h3b, dis, rows, csr, bns + 1024, bnq + 1024,
                                         bn3_g, bn3_b, xa4b);
    {
        dim3 grid(512/128, N_/128);
        k_gemm_mfma<<<grid, 256, 0, stream>>>(xa4b, wT2, gcn4_b, (float*)h4b, 256, 512, 1);
    }
    k_bn_stats_b<<<BNB, 256, 0, stream>>>(h4b, bns + 1536, bnq + 1536, 512, BNR);

    // ---- pooling with fused BN4+ReLU (+fc-init blocks) -> [32,1024] ----
    k_pool<<<640, 256, 0, stream>>>(h4b, gb, bns + 1536, bnq + 1536, bn4_g, bn4_b,
                                    fc_b, pooled, out);

    // ---- FC 1024->1024 ----
    {
        dim3 grid(G_, FCKZ);
        k_fc2<<<grid, 256, 0, stream>>>(pooled, fc_w, gb, out);
    }
}

// Round 2
// 359.872 us; speedup vs baseline: 1.1300x; 1.0501x over previous
//
#include <hip/hip_runtime.h>

#define N_ 16384
#define E_ 131072
#define G_ 32
#define EPSF 1e-5f

typedef unsigned short bf16u;
typedef __attribute__((ext_vector_type(8))) short s8v;   // 8 bf16 (4 VGPRs)
typedef __attribute__((ext_vector_type(4))) float f4v;   // 4 fp32 acc

__device__ __forceinline__ bf16u f2bf(float v) {
    union { float f; unsigned u; } x; x.f = v;
    unsigned r = x.u + 0x7FFF + ((x.u >> 16) & 1);   // RNE
    return (bf16u)(r >> 16);
}
__device__ __forceinline__ float bf2f(bf16u u) {
    union { unsigned u; float f; } x; x.u = (unsigned)u << 16;
    return x.f;
}

// ---------------- workspace layout (bytes) ----------------
static const size_t OFF_INDEG = 0;          // int[N]        } single
static const size_t OFF_ROWS  = 65536;      // int[N+1]      } memset
static const size_t OFF_CURSOR= 131584;     // int[N]        } covers
static const size_t OFF_CSR   = 197120;     // int[E]        } 0..OFF_MSET
static const size_t OFF_DIS   = 721408;     // float[N]
static const size_t OFF_ES    = 786944;     // float[4N]
static const size_t OFF_ED    = 1049088;    // float[4N]
static const size_t OFF_BNS   = 1311232;    // float[4][512]
static const size_t OFF_BNQ   = 1319424;    // float[4][512]
static const size_t OFF_GB    = 1327616;    // int[33]
static const size_t OFF_POOL  = 1327872;    // float[32*1024]
static const size_t OFF_MOM   = 1458944;    // float[20] xa moments (5 mean + 15 second)
static const size_t OFF_MSET  = 1459072;    // (memset end marker)
static const size_t OFF_XA    = 1786624;    // float[8N]  512 KB (padded [N][8] GCN1 agg)
static const size_t OFF_AB    = 5980928;    // bf16[128N]   4 MB ([agg|h1] concat)
static const size_t OFF_H2P   = 10175232;   // bf16[128N]   4 MB (pre-BN)
static const size_t OFF_H2B   = 14369536;   // bf16[128N]   4 MB (post-BN)
static const size_t OFF_H3B   = 18563840;   // bf16[256N]   8 MB
static const size_t OFF_AGG   = 35328768;   // bf16[512N]  16 MB (GAT head-agg of h2b)
static const size_t OFF_XA4B  = 52105984;   // bf16[256N]   8 MB
static const size_t OFF_WT1   = 68883200;   // bf16[256*512] (0.25*gat_w stacked-head ^T)
static const size_t OFF_WT2   = 69145344;   // bf16[512*256]
static const size_t OFF_WT3   = 69407488;   // bf16[128*128]
static const size_t OFF_H4B   = 69440256;   // bf16[512N] 16 MB
static const size_t OFF_VES   = 86479616;   // float[4][128]  W_h·a_src_h
static const size_t OFF_VED   = 86481664;   // float[4][128]  W_h·a_dst_h
// total ≈ 86.5 MB

// scan + fused dis + cursor copy
__global__ __launch_bounds__(1024) void k_scan(const int* __restrict__ indeg,
                                               int* __restrict__ rows,
                                               int* __restrict__ cursor,
                                               float* __restrict__ dis) {
    __shared__ int part[1024];
    int t = threadIdx.x;
    int base = t * 16;
    int local[16];
    int s = 0;
#pragma unroll
    for (int i = 0; i < 16; ++i) {
        local[i] = indeg[base + i]; s += local[i];
        dis[base + i] = rsqrtf((float)local[i] + 1.0f);
    }
    part[t] = s;
    __syncthreads();
    for (int off = 1; off < 1024; off <<= 1) {
        int v = (t >= off) ? part[t - off] : 0;
        __syncthreads();
        part[t] += v;
        __syncthreads();
    }
    int run = (t == 0) ? 0 : part[t - 1];
#pragma unroll
    for (int i = 0; i < 16; ++i) {
        rows[base + i] = run; cursor[base + i] = run; run += local[i];
    }
    if (t == 1023) rows[N_] = run;
}

__global__ void k_fill(const int* __restrict__ src, const int* __restrict__ dst,
                       int* __restrict__ cursor, int* __restrict__ csr) {
    int e = blockIdx.x * 256 + threadIdx.x;
    if (e < E_) {
        int p = atomicAdd(&cursor[dst[e]], 1);
        csr[p] = src[e];
    }
}

// ------- fused setup: weight transpose/convert + gbounds + v_es/v_ed + indeg -------
// wT1 is the stacked-head GAT weight for the post-aggregation GEMM:
//   wT1[c][h*128+k] = 0.25 * gat_w[k][h*256+c]   (BT layout, [256][512])
// v_es[h][k] = sum_c gat_w[k][h*256+c]*asrc[h][c]: attention-by-associativity.
__global__ void k_wconv_all(const float* __restrict__ gat_w,
                            const float* __restrict__ gcn4_w,
                            const float* __restrict__ wl, const float* __restrict__ wr,
                            const int* __restrict__ batch,
                            const float* __restrict__ gat_as,
                            const float* __restrict__ gat_ad,
                            const int* __restrict__ dstE,
                            bf16u* __restrict__ wT1, bf16u* __restrict__ wT2,
                            bf16u* __restrict__ wT3, int* __restrict__ gb,
                            float* __restrict__ ves, float* __restrict__ ved,
                            int* __restrict__ indeg) {
    int idx = blockIdx.x * 256 + threadIdx.x;
    if (idx < 131072) {          // gat_w [128][1024] -> wT1[c][h*128+k] (stacked heads, /4)
        int c = idx >> 9;                        // output channel 0..255
        int kk = idx & 511;                      // h*128+k
        int h = kk >> 7, k = kk & 127;
        wT1[idx] = f2bf(0.25f * gat_w[(size_t)k * 1024 + h * 256 + c]);
    } else if (idx < 262144) {   // gcn4_w [256][512] -> wT2[512][256]
        int j = idx - 131072;
        int m = j >> 8, k = j & 255;
        wT2[j] = f2bf(gcn4_w[(size_t)k * 512 + m]);
    } else if (idx < 278528) {   // [wl;wr] -> wT3[128][128]
        int j = idx - 262144;
        int m = j >> 7, k = j & 127;
        float v = (k < 64) ? wl[k*128 + m] : wr[(k-64)*128 + m];
        wT3[j] = f2bf(v);
    } else if (idx < 278592) {   // graph-batch bounds
        int g = idx - 278528;
        if (g > G_) return;
        if (g == G_) { gb[G_] = N_; return; }
        int lo = 0, hi = N_;
        while (lo < hi) { int mid = (lo + hi) >> 1; if (batch[mid] < g) lo = mid + 1; else hi = mid; }
        gb[g] = lo;
    } else if (idx < 279104) {   // v_es (4 heads x 128 k)
        int j = idx - 278592;
        int h = j >> 7, k = j & 127;
        float s = 0.f;
        for (int c = 0; c < 256; ++c)
            s += gat_w[(size_t)k * 1024 + h*256 + c] * gat_as[h*256 + c];
        ves[j] = s;
    } else if (idx < 279616) {   // v_ed
        int j = idx - 279104;
        int h = j >> 7, k = j & 127;
        float s = 0.f;
        for (int c = 0; c < 256; ++c)
            s += gat_w[(size_t)k * 1024 + h*256 + c] * gat_ad[h*256 + c];
        ved[j] = s;
    } else if (idx < 410688) {   // indeg
        int e = idx - 279616;
        atomicAdd(&indeg[dstE[e]], 1);
    }
}

// ---------------- layer 1: GCN aggregate only -> xa [N][8] fp32 (512 KB) ----------------
// Matmul 5->64 + BN moved downstream (analytic stats from 5x5 moments).
__global__ __launch_bounds__(256) void k_gcn1x(const float* __restrict__ x,
                                               const float* __restrict__ dis,
                                               const int* __restrict__ rows,
                                               const int* __restrict__ csr,
                                               float* __restrict__ xa) {
    int wave = threadIdx.x >> 6, lane = threadIdx.x & 63;
    int i = blockIdx.x * 4 + wave;
    float a0=0,a1=0,a2=0,a3=0,a4=0;
    int e0 = rows[i], e1 = rows[i+1];
    for (int e = e0 + lane; e < e1; e += 64) {
        int s = csr[e];
        float wt = dis[s];
        a0 += x[s*5+0]*wt; a1 += x[s*5+1]*wt; a2 += x[s*5+2]*wt;
        a3 += x[s*5+3]*wt; a4 += x[s*5+4]*wt;
    }
#pragma unroll
    for (int off = 32; off > 0; off >>= 1) {
        a0 += __shfl_xor(a0, off, 64); a1 += __shfl_xor(a1, off, 64);
        a2 += __shfl_xor(a2, off, 64); a3 += __shfl_xor(a3, off, 64);
        a4 += __shfl_xor(a4, off, 64);
    }
    float di = dis[i];
    float v0 = di*(a0 + di*x[i*5+0]);
    float v1 = di*(a1 + di*x[i*5+1]);
    float v2 = di*(a2 + di*x[i*5+2]);
    float v3 = di*(a3 + di*x[i*5+3]);
    float v4 = di*(a4 + di*x[i*5+4]);
    if (lane < 5) {
        float v = lane == 0 ? v0 : lane == 1 ? v1 : lane == 2 ? v2 : lane == 3 ? v3 : v4;
        xa[(size_t)i*8 + lane] = v;
    }
}

// ---------------- xa moments: 5 means + 15 second moments (for analytic BN1) ----------------
__global__ __launch_bounds__(256) void k_xstats(const float* __restrict__ xa,
                                                float* __restrict__ mom) {
    int tid = blockIdx.x * 256 + threadIdx.x;    // grid 64 -> exactly N threads
    float v0 = xa[(size_t)tid*8+0], v1 = xa[(size_t)tid*8+1], v2 = xa[(size_t)tid*8+2];
    float v3 = xa[(size_t)tid*8+3], v4 = xa[(size_t)tid*8+4];
    float m[20];
    m[0]=v0; m[1]=v1; m[2]=v2; m[3]=v3; m[4]=v4;
    m[5]=v0*v0;  m[6]=v0*v1;  m[7]=v0*v2;  m[8]=v0*v3;  m[9]=v0*v4;
    m[10]=v1*v1; m[11]=v1*v2; m[12]=v1*v3; m[13]=v1*v4;
    m[14]=v2*v2; m[15]=v2*v3; m[16]=v2*v4;
    m[17]=v3*v3; m[18]=v3*v4;
    m[19]=v4*v4;
#pragma unroll
    for (int off = 32; off > 0; off >>= 1)
#pragma unroll
        for (int j = 0; j < 20; ++j) m[j] += __shfl_xor(m[j], off, 64);
    if ((threadIdx.x & 63) == 0)
#pragma unroll
        for (int j = 0; j < 20; ++j) atomicAdd(&mom[j], m[j]);
}

// ---------------- fused layer-1 apply + SAGE aggregate (wave-per-node) ----------------
// h = xa·W + b; BN1 stats analytic: mu = E[xa]·W + b, var = wᵀ Cov(xa) w (5x5).
// Self post-BN-ReLU -> ab[:,64:128]; neighbor mean of post-BN-ReLU -> ab[:,0:64].
// Neighbor gather hits the 512 KB xa array (L1/L2-resident) — per-edge recompute
// is 6 FMA/lane, cheaper than the old 4 MB bf16-mirror gather.
__global__ __launch_bounds__(256) void k_sage_l1(const float* __restrict__ xa,
                                                 const float* __restrict__ mom,
                                                 const float* __restrict__ w,   // [5][64]
                                                 const float* __restrict__ b,
                                                 const float* __restrict__ bng,
                                                 const float* __restrict__ bnb,
                                                 const int* __restrict__ rows,
                                                 const int* __restrict__ csr,
                                                 bf16u* __restrict__ ab) {
    int wave = threadIdx.x >> 6, lane = threadIdx.x & 63;
    int i = blockIdx.x * 4 + wave;
    int c = lane;
    const float invN = 1.0f / (float)N_;
    float wc0 = w[c], wc1 = w[64+c], wc2 = w[128+c], wc3 = w[192+c], wc4 = w[256+c];
    float m0 = mom[0]*invN, m1 = mom[1]*invN, m2 = mom[2]*invN, m3 = mom[3]*invN, m4 = mom[4]*invN;
    float mu = b[c] + m0*wc0 + m1*wc1 + m2*wc2 + m3*wc3 + m4*wc4;
    // var = sum_{k<=l} cov_kl * w_k * w_l * (k==l ? 1 : 2)
    float var = 0.f;
    var += (mom[5]*invN  - m0*m0) * wc0*wc0;
    var += (mom[6]*invN  - m0*m1) * wc0*wc1 * 2.f;
    var += (mom[7]*invN  - m0*m2) * wc0*wc2 * 2.f;
    var += (mom[8]*invN  - m0*m3) * wc0*wc3 * 2.f;
    var += (mom[9]*invN  - m0*m4) * wc0*wc4 * 2.f;
    var += (mom[10]*invN - m1*m1) * wc1*wc1;
    var += (mom[11]*invN - m1*m2) * wc1*wc2 * 2.f;
    var += (mom[12]*invN - m1*m3) * wc1*wc3 * 2.f;
    var += (mom[13]*invN - m1*m4) * wc1*wc4 * 2.f;
    var += (mom[14]*invN - m2*m2) * wc2*wc2;
    var += (mom[15]*invN - m2*m3) * wc2*wc3 * 2.f;
    var += (mom[16]*invN - m2*m4) * wc2*wc4 * 2.f;
    var += (mom[17]*invN - m3*m3) * wc3*wc3;
    var += (mom[18]*invN - m3*m4) * wc3*wc4 * 2.f;
    var += (mom[19]*invN - m4*m4) * wc4*wc4;
    float scale = rsqrtf(var + EPSF) * bng[c];
    float base  = fmaf(b[c], scale, bnb[c] - mu * scale);   // v = (Σ xa_k w_k)*scale + base
    // self
    {
        const float* p = &xa[(size_t)i*8];
        float t = p[0]*wc0 + p[1]*wc1 + p[2]*wc2 + p[3]*wc3 + p[4]*wc4;
        float v = fmaf(t, scale, base); v = v > 0.f ? v : 0.f;
        ab[(size_t)i*128 + 64 + c] = f2bf(v);
    }
    // neighbors (mean of post-BN-ReLU)
    int e0 = rows[i], e1 = rows[i+1];
    float s = 0.f;
    for (int e = e0; e < e1; ++e) {
        const float* p = &xa[(size_t)csr[e]*8];
        float t = p[0]*wc0 + p[1]*wc1 + p[2]*wc2 + p[3]*wc3 + p[4]*wc4;
        float v = fmaf(t, scale, base); v = v > 0.f ? v : 0.f;
        s += v;
    }
    ab[(size_t)i*128 + c] = f2bf(s / fmaxf((float)(e1 - e0), 1.0f));
}

// ---------------- bf16 MFMA GEMM: C[n,m] = A[n,k]*BT[m,k]^T (+bias), bf16 out ----------------
// 128x128 tile, BK=32, 4 waves x (4x4) mfma_f32_16x16x32_bf16 (layouts m89/m91/m120).
// Epilogue also accumulates per-column sum/sumsq (fused BN stats) when sum != null:
// per-lane partial over (i,r), shfl_xor over lq, 16 lanes atomicAdd per wave/j.
__global__ __launch_bounds__(256) void k_gemm_mfma(const bf16u* __restrict__ A,
                                                   const bf16u* __restrict__ BT,
                                                   const float* __restrict__ bias,
                                                   bf16u* __restrict__ C,
                                                   float* __restrict__ sum,
                                                   float* __restrict__ sumsq,
                                                   int K, int M) {
    __shared__ bf16u As[128][40];
    __shared__ bf16u Bs[128][40];
    int tid = threadIdx.x;
    int wave = tid >> 6, lane = tid & 63;
    int wr = (wave >> 1) * 64, wc = (wave & 1) * 64;
    int row0 = blockIdx.y * 128, col0 = blockIdx.x * 128;
    f4v acc[4][4];
#pragma unroll
    for (int i = 0; i < 4; ++i)
#pragma unroll
        for (int j = 0; j < 4; ++j) acc[i][j] = (f4v)0.0f;

    int sr = tid >> 1;             // 0..127
    int sh = (tid & 1) * 16;       // k-half within BK
    int lr = lane & 15, lq = lane >> 4;

    for (int k0 = 0; k0 < K; k0 += 32) {
        const bf16u* ap = A + (size_t)(row0 + sr) * K + k0 + sh;
        *(uint4*)&As[sr][sh]     = *(const uint4*)ap;
        *(uint4*)&As[sr][sh + 8] = *(const uint4*)(ap + 8);
        const bf16u* bp = BT + (size_t)(col0 + sr) * K + k0 + sh;
        *(uint4*)&Bs[sr][sh]     = *(const uint4*)bp;
        *(uint4*)&Bs[sr][sh + 8] = *(const uint4*)(bp + 8);
        __syncthreads();
        s8v af[4], bfr[4];
#pragma unroll
        for (int i = 0; i < 4; ++i)
            af[i] = *(const s8v*)&As[wr + i*16 + lr][lq*8];
#pragma unroll
        for (int j = 0; j < 4; ++j)
            bfr[j] = *(const s8v*)&Bs[wc + j*16 + lr][lq*8];
#pragma unroll
        for (int i = 0; i < 4; ++i)
#pragma unroll
            for (int j = 0; j < 4; ++j)
                acc[i][j] = __builtin_amdgcn_mfma_f32_16x16x32_bf16(af[i], bfr[j], acc[i][j], 0, 0, 0);
        __syncthreads();
    }

#pragma unroll
    for (int j = 0; j < 4; ++j) {
        int col = col0 + wc + j*16 + lr;
        float bv = bias ? bias[col] : 0.f;
        float s = 0.f, q = 0.f;
#pragma unroll
        for (int i = 0; i < 4; ++i) {
#pragma unroll
            for (int r = 0; r < 4; ++r) {
                float v = acc[i][j][r] + bv;
                int row = row0 + wr + i*16 + lq*4 + r;
                C[(size_t)row * M + col] = f2bf(v);
                s += v; q += v*v;
            }
        }
        if (sum) {
            s += __shfl_xor(s, 16, 64); q += __shfl_xor(q, 16, 64);
            s += __shfl_xor(s, 32, 64); q += __shfl_xor(q, 32, 64);
            if (lq == 0) { atomicAdd(&sum[col], s); atomicAdd(&sumsq[col], q); }
        }
    }
}

// ---------------- BN2 apply + fused GAT attention coefficients (wave-per-node) ----------------
__global__ __launch_bounds__(256) void k_bn_apply2b_attn(
        const bf16u* __restrict__ hp, const float* __restrict__ sum,
        const float* __restrict__ sumsq, const float* __restrict__ g,
        const float* __restrict__ b, const float* __restrict__ ves,
        const float* __restrict__ ved, bf16u* __restrict__ hb,
        float* __restrict__ es, float* __restrict__ ed) {
    int wave = threadIdx.x >> 6, lane = threadIdx.x & 63;
    int i = blockIdx.x * 4 + wave;
    int c = lane * 2;
    const float invN = 1.0f / (float)N_;
    float2 sm = *(const float2*)&sum[c];
    float2 sq = *(const float2*)&sumsq[c];
    float2 gg = *(const float2*)&g[c];
    float2 bb = *(const float2*)&b[c];
    float mu0 = sm.x*invN, mu1 = sm.y*invN;
    float sc0 = rsqrtf(sq.x*invN - mu0*mu0 + EPSF)*gg.x, sh0 = bb.x - mu0*sc0;
    float sc1 = rsqrtf(sq.y*invN - mu1*mu1 + EPSF)*gg.y, sh1 = bb.y - mu1*sc1;
    unsigned pv = *(const unsigned*)&hp[(size_t)i*128 + c];
    float v0 = bf2f((bf16u)(pv & 0xFFFF));
    float v1 = bf2f((bf16u)(pv >> 16));
    v0 = fmaf(v0, sc0, sh0); v0 = v0 > 0.f ? v0 : 0.f;
    v1 = fmaf(v1, sc1, sh1); v1 = v1 > 0.f ? v1 : 0.f;
    unsigned ow = (unsigned)f2bf(v0) | ((unsigned)f2bf(v1) << 16);
    *(unsigned*)&hb[(size_t)i*128 + c] = ow;
    float vs[4], vd[4];
#pragma unroll
    for (int h = 0; h < 4; ++h) {
        float2 a = *(const float2*)&ves[h*128 + c];
        float2 d = *(const float2*)&ved[h*128 + c];
        vs[h] = v0*a.x + v1*a.y;
        vd[h] = v0*d.x + v1*d.y;
    }
#pragma unroll
    for (int off = 32; off > 0; off >>= 1) {
#pragma unroll
        for (int h = 0; h < 4; ++h) {
            vs[h] += __shfl_xor(vs[h], off, 64);
            vd[h] += __shfl_xor(vd[h], off, 64);
        }
    }
    if (lane == 0) {
        *(float4*)&es[i*4] = make_float4(vs[0], vs[1], vs[2], vs[3]);
        *(float4*)&ed[i*4] = make_float4(vd[0], vd[1], vd[2], vd[3]);
    }
}

// ---------------- GAT: fused max + single-pass softmax aggregation of h2b ----------------
__global__ __launch_bounds__(256) void k_gat_agg2(const bf16u* __restrict__ h2b,
                                                  const float* __restrict__ es,
                                                  const float* __restrict__ ed,
                                                  const int* __restrict__ rows,
                                                  const int* __restrict__ csr,
                                                  bf16u* __restrict__ agg) {
    int wave = threadIdx.x >> 6, lane = threadIdx.x & 63;
    int i = blockIdx.x * 4 + wave;
    int c = lane * 2;
    float4 edv = *(const float4*)&ed[i*4];
    float4 sv  = *(const float4*)&es[i*4];
    int e0 = rows[i], e1 = rows[i+1];
    // ---- pass 1: exact per-node logit max (incl self-loop), lane-parallel ----
    float e, m0, m1, m2, m3;
    e = sv.x + edv.x; m0 = e >= 0.f ? e : 0.2f*e;
    e = sv.y + edv.y; m1 = e >= 0.f ? e : 0.2f*e;
    e = sv.z + edv.z; m2 = e >= 0.f ? e : 0.2f*e;
    e = sv.w + edv.w; m3 = e >= 0.f ? e : 0.2f*e;
    for (int ee = e0 + lane; ee < e1; ee += 64) {
        int s = csr[ee];
        float4 s2 = *(const float4*)&es[s*4];
        e = s2.x + edv.x; m0 = fmaxf(m0, e >= 0.f ? e : 0.2f*e);
        e = s2.y + edv.y; m1 = fmaxf(m1, e >= 0.f ? e : 0.2f*e);
        e = s2.z + edv.z; m2 = fmaxf(m2, e >= 0.f ? e : 0.2f*e);
        e = s2.w + edv.w; m3 = fmaxf(m3, e >= 0.f ? e : 0.2f*e);
    }
#pragma unroll
    for (int off = 32; off > 0; off >>= 1) {
        m0 = fmaxf(m0, __shfl_xor(m0, off, 64));
        m1 = fmaxf(m1, __shfl_xor(m1, off, 64));
        m2 = fmaxf(m2, __shfl_xor(m2, off, 64));
        m3 = fmaxf(m3, __shfl_xor(m3, off, 64));
    }
    // ---- pass 2: softmax-weighted aggregation (serial edges, lanes = channels) ----
    float z0, z1, z2, z3;
    float a00, a01, a10, a11, a20, a21, a30, a31;
    {
        e = sv.x + edv.x; e = e >= 0.f ? e : 0.2f*e; z0 = __expf(e - m0);
        e = sv.y + edv.y; e = e >= 0.f ? e : 0.2f*e; z1 = __expf(e - m1);
        e = sv.z + edv.z; e = e >= 0.f ? e : 0.2f*e; z2 = __expf(e - m2);
        e = sv.w + edv.w; e = e >= 0.f ? e : 0.2f*e; z3 = __expf(e - m3);
        unsigned pv = *(const unsigned*)&h2b[(size_t)i*128 + c];
        float v0 = bf2f((bf16u)(pv & 0xFFFF)), v1 = bf2f((bf16u)(pv >> 16));
        a00 = z0*v0; a01 = z0*v1; a10 = z1*v0; a11 = z1*v1;
        a20 = z2*v0; a21 = z2*v1; a30 = z3*v0; a31 = z3*v1;
    }
    for (int ee = e0; ee < e1; ++ee) {
        int s = csr[ee];
        float4 s2 = *(const float4*)&es[s*4];
        unsigned pv = *(const unsigned*)&h2b[(size_t)s*128 + c];
        float v0 = bf2f((bf16u)(pv & 0xFFFF)), v1 = bf2f((bf16u)(pv >> 16));
        float ex;
        e = s2.x + edv.x; e = e >= 0.f ? e : 0.2f*e; ex = __expf(e - m0);
        z0 += ex; a00 = fmaf(ex, v0, a00); a01 = fmaf(ex, v1, a01);
        e = s2.y + edv.y; e = e >= 0.f ? e : 0.2f*e; ex = __expf(e - m1);
        z1 += ex; a10 = fmaf(ex, v0, a10); a11 = fmaf(ex, v1, a11);
        e = s2.z + edv.z; e = e >= 0.f ? e : 0.2f*e; ex = __expf(e - m2);
        z2 += ex; a20 = fmaf(ex, v0, a20); a21 = fmaf(ex, v1, a21);
        e = s2.w + edv.w; e = e >= 0.f ? e : 0.2f*e; ex = __expf(e - m3);
        z3 += ex; a30 = fmaf(ex, v0, a30); a31 = fmaf(ex, v1, a31);
    }
    size_t base = (size_t)i * 512 + c;
    float r; unsigned ow;
    r = 1.f/z0; ow = (unsigned)f2bf(a00*r) | ((unsigned)f2bf(a01*r) << 16);
    *(unsigned*)&agg[base]       = ow;
    r = 1.f/z1; ow = (unsigned)f2bf(a10*r) | ((unsigned)f2bf(a11*r) << 16);
    *(unsigned*)&agg[base + 128] = ow;
    r = 1.f/z2; ow = (unsigned)f2bf(a20*r) | ((unsigned)f2bf(a21*r) << 16);
    *(unsigned*)&agg[base + 256] = ow;
    r = 1.f/z3; ow = (unsigned)f2bf(a30*r) | ((unsigned)f2bf(a31*r) << 16);
    *(unsigned*)&agg[base + 384] = ow;
}

// ---------------- layer 4: fused BN3+ReLU + GCN aggregate (wave-per-node, ushort4) ----------------
__global__ __launch_bounds__(256) void k_gcn4_agg(const bf16u* __restrict__ h3b,
                                                  const float* __restrict__ dis,
                                                  const int* __restrict__ rows,
                                                  const int* __restrict__ csr,
                                                  const float* __restrict__ sum,
                                                  const float* __restrict__ sumsq,
                                                  const float* __restrict__ g,
                                                  const float* __restrict__ b,
                                                  bf16u* __restrict__ xab) {
    int wave = threadIdx.x >> 6, q = threadIdx.x & 63;
    int i = blockIdx.x * 4 + wave;
    int c = q * 4;
    const float invN = 1.0f / (float)N_;
    float4 sm = *(const float4*)&sum[c];
    float4 sq = *(const float4*)&sumsq[c];
    float4 gg = *(const float4*)&g[c];
    float4 bb = *(const float4*)&b[c];
    float mu, sc0, sc1, sc2, sc3, sh0, sh1, sh2, sh3;
    mu = sm.x*invN; sc0 = rsqrtf(sq.x*invN - mu*mu + EPSF)*gg.x; sh0 = bb.x - mu*sc0;
    mu = sm.y*invN; sc1 = rsqrtf(sq.y*invN - mu*mu + EPSF)*gg.y; sh1 = bb.y - mu*sc1;
    mu = sm.z*invN; sc2 = rsqrtf(sq.z*invN - mu*mu + EPSF)*gg.z; sh2 = bb.z - mu*sc2;
    mu = sm.w*invN; sc3 = rsqrtf(sq.w*invN - mu*mu + EPSF)*gg.w; sh3 = bb.w - mu*sc3;
    float di = dis[i];
    float a0, a1, a2, a3;
    {
        ushort4 u = *(const ushort4*)(h3b + (size_t)i*256 + c);
        float v, dd = di * di;
        v = fmaf(bf2f(u.x), sc0, sh0); v = v > 0.f ? v : 0.f; a0 = v * dd;
        v = fmaf(bf2f(u.y), sc1, sh1); v = v > 0.f ? v : 0.f; a1 = v * dd;
        v = fmaf(bf2f(u.z), sc2, sh2); v = v > 0.f ? v : 0.f; a2 = v * dd;
        v = fmaf(bf2f(u.w), sc3, sh3); v = v > 0.f ? v : 0.f; a3 = v * dd;
    }
    int e0 = rows[i], e1 = rows[i+1];
    for (int e = e0; e < e1; ++e) {
        int s = csr[e];
        float w = dis[s] * di;
        ushort4 u = *(const ushort4*)(h3b + (size_t)s*256 + c);
        float v;
        v = fmaf(bf2f(u.x), sc0, sh0); v = v > 0.f ? v : 0.f; a0 += v * w;
        v = fmaf(bf2f(u.y), sc1, sh1); v = v > 0.f ? v : 0.f; a1 += v * w;
        v = fmaf(bf2f(u.z), sc2, sh2); v = v > 0.f ? v : 0.f; a2 += v * w;
        v = fmaf(bf2f(u.w), sc3, sh3); v = v > 0.f ? v : 0.f; a3 += v * w;
    }
    ushort4 o;
    o.x = f2bf(a0); o.y = f2bf(a1); o.z = f2bf(a2); o.w = f2bf(a3);
    *(ushort4*)(xab + (size_t)i*256 + c) = o;
}

// ---------------- pooling with fused BN4+ReLU (+ folded fc-init blocks) ----------------
__global__ void k_pool(const bf16u* __restrict__ h4b, const int* __restrict__ gb,
                       const float* __restrict__ sum, const float* __restrict__ sumsq,
                       const float* __restrict__ g, const float* __restrict__ b,
                       const float* __restrict__ fcb,
                       float* __restrict__ pooled, float* __restrict__ out) {
    int bidx = blockIdx.x;
    int t = threadIdx.x;
    if (bidx >= 512) {                 // fc-init: out = bias (independent work)
        int i = (bidx - 512) * 256 + t;
        out[i] = fcb[i & 1023];
        return;
    }
    int gi = bidx >> 4;
    int chunk = bidx & 15;
    const float invN = 1.0f / (float)N_;
    float mu0 = sum[t] * invN;
    float sc0 = rsqrtf(sumsq[t] * invN - mu0*mu0 + EPSF) * g[t];
    float sh0 = b[t] - mu0 * sc0;
    float mu1 = sum[t+256] * invN;
    float sc1 = rsqrtf(sumsq[t+256] * invN - mu1*mu1 + EPSF) * g[t+256];
    float sh1 = b[t+256] - mu1 * sc1;
    int r0g = gb[gi], r1g = gb[gi+1];
    int n = r1g - r0g;
    if (n <= 0) return;
    int per = (n + 15) >> 4;
    int r0 = r0g + chunk * per;
    int r1 = min(r0 + per, r1g);
    if (r0 >= r1) return;
    float s0=0.f, s1=0.f, m0=0.f, m1=0.f;   // post-ReLU >= 0: max init 0 valid
    for (int r = r0; r < r1; ++r) {
        float v = fmaf(bf2f(h4b[(size_t)r*512 + t]), sc0, sh0);
        v = v > 0.f ? v : 0.f;
        s0 += v; m0 = fmaxf(m0, v);
        float w = fmaf(bf2f(h4b[(size_t)r*512 + 256 + t]), sc1, sh1);
        w = w > 0.f ? w : 0.f;
        s1 += w; m1 = fmaxf(m1, w);
    }
    atomicAdd(&pooled[gi*1024 + t], s0);
    atomicAdd(&pooled[gi*1024 + 256 + t], s1);
    atomicMax((int*)&pooled[gi*1024 + 512 + t],  __float_as_int(m0));
    atomicMax((int*)&pooled[gi*1024 + 768 + t],  __float_as_int(m1));
}

// ---------------- FC (K-split, float4, atomic reduce; mean-scale folded in) ----------------
#define FCKZ 16
#define FCKC (1024 / FCKZ)   // 64

__global__ __launch_bounds__(256) void k_fc2(const float* __restrict__ pooled,
                                             const float* __restrict__ w,
                                             const int* __restrict__ gb,
                                             float* __restrict__ out) {
    __shared__ float pr[FCKC];
    int g = blockIdx.x;
    int z = blockIdx.y;
    int t = threadIdx.x;
    int k0 = z * FCKC;
    if (t < FCKC) {
        float scale = (z < 8) ? 1.0f / fmaxf((float)(gb[g+1] - gb[g]), 1.0f) : 1.0f;
        pr[t] = pooled[g * 1024 + k0 + t] * scale;   // mean part needs 1/cnt
    }
    __syncthreads();
    int m0 = t * 4;
    float ax = 0.f, ay = 0.f, az = 0.f, aw = 0.f;
#pragma unroll 8
    for (int k = 0; k < FCKC; ++k) {
        const float4 wv = *(const float4*)&w[(size_t)(k0 + k) * 1024 + m0];
        float p = pr[k];
        ax += p * wv.x; ay += p * wv.y; az += p * wv.z; aw += p * wv.w;
    }
    atomicAdd(&out[g * 1024 + m0 + 0], ax);
    atomicAdd(&out[g * 1024 + m0 + 1], ay);
    atomicAdd(&out[g * 1024 + m0 + 2], az);
    atomicAdd(&out[g * 1024 + m0 + 3], aw);
}

// ---------------- host ----------------
extern "C" void kernel_launch(void* const* d_in, const int* in_sizes, int n_in,
                              void* d_out, int out_size, void* d_ws, size_t ws_size,
                              hipStream_t stream) {
    (void)in_sizes; (void)n_in; (void)out_size; (void)ws_size;
    const float* x       = (const float*)d_in[0];
    const int*   ei      = (const int*)d_in[1];
    const int*   batch   = (const int*)d_in[2];
    const float* gcn1_w  = (const float*)d_in[3];
    const float* gcn1_b  = (const float*)d_in[4];
    const float* sage_wl = (const float*)d_in[5];
    const float* sage_wr = (const float*)d_in[6];
    const float* sage_b  = (const float*)d_in[7];
    const float* gat_w   = (const float*)d_in[8];
    const float* gat_as  = (const float*)d_in[9];
    const float* gat_ad  = (const float*)d_in[10];
    const float* gat_b   = (const float*)d_in[11];
    const float* gcn4_w  = (const float*)d_in[12];
    const float* gcn4_b  = (const float*)d_in[13];
    const float* bn1_g   = (const float*)d_in[14];
    const float* bn1_b   = (const float*)d_in[15];
    const float* bn2_g   = (const float*)d_in[16];
    const float* bn2_b   = (const float*)d_in[17];
    const float* bn3_g   = (const float*)d_in[18];
    const float* bn3_b   = (const float*)d_in[19];
    const float* bn4_g   = (const float*)d_in[20];
    const float* bn4_b   = (const float*)d_in[21];
    const float* fc_w    = (const float*)d_in[22];
    const float* fc_b    = (const float*)d_in[23];
    float* out = (float*)d_out;

    char* w8 = (char*)d_ws;
    int*   indeg  = (int*)(w8 + OFF_INDEG);
    int*   rows   = (int*)(w8 + OFF_ROWS);
    int*   cursor = (int*)(w8 + OFF_CURSOR);
    int*   csr    = (int*)(w8 + OFF_CSR);
    float* dis    = (float*)(w8 + OFF_DIS);
    float* es     = (float*)(w8 + OFF_ES);
    float* ed     = (float*)(w8 + OFF_ED);
    float* bns    = (float*)(w8 + OFF_BNS);   // [4][512] per-layer slices
    float* bnq    = (float*)(w8 + OFF_BNQ);
    int*   gb     = (int*)(w8 + OFF_GB);
    float* pooled = (float*)(w8 + OFF_POOL);
    float* mom    = (float*)(w8 + OFF_MOM);
    float* xa     = (float*)(w8 + OFF_XA);
    bf16u* ab     = (bf16u*)(w8 + OFF_AB);
    bf16u* h2p    = (bf16u*)(w8 + OFF_H2P);
    bf16u* h2b    = (bf16u*)(w8 + OFF_H2B);
    bf16u* h3b    = (bf16u*)(w8 + OFF_H3B);
    bf16u* agg    = (bf16u*)(w8 + OFF_AGG);
    bf16u* xa4b   = (bf16u*)(w8 + OFF_XA4B);
    bf16u* wT1    = (bf16u*)(w8 + OFF_WT1);
    bf16u* wT2    = (bf16u*)(w8 + OFF_WT2);
    bf16u* wT3    = (bf16u*)(w8 + OFF_WT3);
    bf16u* h4b    = (bf16u*)(w8 + OFF_H4B);
    float* ves    = (float*)(w8 + OFF_VES);
    float* ved    = (float*)(w8 + OFF_VED);

    const int* srcE = ei;        // edge_index[0,:]
    const int* dstE = ei + E_;   // edge_index[1,:]

    // ---- setup: ONE memset, then fused setup kernel (weights+gbounds+ves/ved+indeg) ----
    hipMemsetAsync(w8, 0, OFF_MSET, stream);
    k_wconv_all<<<1605, 256, 0, stream>>>(gat_w, gcn4_w, sage_wl, sage_wr, batch,
                                          gat_as, gat_ad, dstE,
                                          wT1, wT2, wT3, gb, ves, ved, indeg);
    k_scan<<<1, 1024, 0, stream>>>(indeg, rows, cursor, dis);
    k_fill<<<E_/256, 256, 0, stream>>>(srcE, dstE, cursor, csr);

    // ---- layer 1+2 front: GCN agg -> xa; analytic BN1 moments; fused apply+SAGE ----
    k_gcn1x<<<N_/4, 256, 0, stream>>>(x, dis, rows, csr, xa);
    k_xstats<<<64, 256, 0, stream>>>(xa, mom);
    k_sage_l1<<<N_/4, 256, 0, stream>>>(xa, mom, gcn1_w, gcn1_b, bn1_g, bn1_b,
                                        rows, csr, ab);

    // ---- layer 2: SAGE 64->128 via single MFMA GEMM (stats fused in epilogue) ----
    {
        dim3 grid(1, N_/128);
        k_gemm_mfma<<<grid, 256, 0, stream>>>(ab, wT3, sage_b, h2p,
                                              bns + 512, bnq + 512, 128, 128);
    }
    k_bn_apply2b_attn<<<N_/4, 256, 0, stream>>>(h2p, bns + 512, bnq + 512, bn2_g, bn2_b,
                                                ves, ved, h2b, es, ed);

    // ---- layer 3: GAT — aggregate h2b per head (fused max+softmax), then 512->256 GEMM ----
    k_gat_agg2<<<N_/4, 256, 0, stream>>>(h2b, es, ed, rows, csr, agg);
    {
        dim3 grid(256/128, N_/128);
        k_gemm_mfma<<<grid, 256, 0, stream>>>(agg, wT1, gat_b, h3b,
                                              bns + 1024, bnq + 1024, 512, 256);
    }

    // ---- layer 4: fused BN3+ReLU+aggregate, MFMA GEMM 256->512 (stats fused) ----
    k_gcn4_agg<<<N_/4, 256, 0, stream>>>(h3b, dis, rows, csr, bns + 1024, bnq + 1024,
                                         bn3_g, bn3_b, xa4b);
    {
        dim3 grid(512/128, N_/128);
        k_gemm_mfma<<<grid, 256, 0, stream>>>(xa4b, wT2, gcn4_b, h4b,
                                              bns + 1536, bnq + 1536, 256, 512);
    }

    // ---- pooling with fused BN4+ReLU (+fc-init blocks) -> [32,1024] ----
    k_pool<<<640, 256, 0, stream>>>(h4b, gb, bns + 1536, bnq + 1536, bn4_g, bn4_b,
                                    fc_b, pooled, out);

    // ---- FC 1024->1024 ----
    {
        dim3 grid(G_, FCKZ);
        k_fc2<<<grid, 256, 0, stream>>>(pooled, fc_w, gb, out);
    }
}

// Round 3
// 305.015 us; speedup vs baseline: 1.3332x; 1.1799x over previous
//
#include <hip/hip_runtime.h>

#define N_ 16384
#define E_ 131072
#define G_ 32
#define EPSF 1e-5f

typedef unsigned short bf16u;
typedef __attribute__((ext_vector_type(8))) short s8v;   // 8 bf16 (4 VGPRs)
typedef __attribute__((ext_vector_type(4))) float f4v;   // 4 fp32 acc

__device__ __forceinline__ bf16u f2bf(float v) {
    union { float f; unsigned u; } x; x.f = v;
    unsigned r = x.u + 0x7FFF + ((x.u >> 16) & 1);   // RNE
    return (bf16u)(r >> 16);
}
__device__ __forceinline__ float bf2f(bf16u u) {
    union { unsigned u; float f; } x; x.u = (unsigned)u << 16;
    return x.f;
}

// ---------------- workspace layout (bytes) ----------------
// Zeroed region [0, OFF_MSET):
static const size_t OFF_INDEG = 0;          // int[N]
static const size_t OFF_ROWS  = 65536;      // int[N+1]
static const size_t OFF_CURSOR= 131584;     // int[N]
static const size_t OFF_CSR   = 197120;     // int[E]
static const size_t OFF_DIS   = 721408;     // float[N]
static const size_t OFF_ES    = 786944;     // float[4N]
static const size_t OFF_ED    = 1049088;    // float[4N]
static const size_t OFF_BNS   = 1311232;    // float[4][8][512] 8-slot stats slabs (64 KB)
static const size_t OFF_BNQ   = 1376768;    // float[4][8][512] (64 KB)
static const size_t OFF_GB    = 1442304;    // int[33]
static const size_t OFF_POOL  = 1442560;    // float[32*1024]
static const size_t OFF_MSET  = 1573632;    // (memset end marker)
// Unzeroed (fully written before read):
static const size_t OFF_PART  = 1573632;    // float[64][20] xa-moment partials
static const size_t OFF_BN1C  = 1578752;    // float[64] scale + float[64] base
static const size_t OFF_XA    = 1786624;    // float[8N]  512 KB (padded [N][8] GCN1 agg)
static const size_t OFF_AB    = 5980928;    // bf16[128N]   4 MB ([agg|h1] concat)
static const size_t OFF_H2P   = 10175232;   // bf16[128N]   4 MB (pre-BN)
static const size_t OFF_H2B   = 14369536;   // bf16[128N]   4 MB (post-BN)
static const size_t OFF_H3B   = 18563840;   // bf16[256N]   8 MB
static const size_t OFF_AGG   = 35328768;   // bf16[512N]  16 MB (GAT head-agg of h2b)
static const size_t OFF_XA4B  = 52105984;   // bf16[256N]   8 MB
static const size_t OFF_WT1   = 68883200;   // bf16[256*512] (0.25*gat_w stacked-head ^T)
static const size_t OFF_WT2   = 69145344;   // bf16[512*256]
static const size_t OFF_WT3   = 69407488;   // bf16[128*128]
static const size_t OFF_H4B   = 69440256;   // bf16[512N] 16 MB
static const size_t OFF_VES   = 86479616;   // float[4][128]  W_h·a_src_h
static const size_t OFF_VED   = 86481664;   // float[4][128]  W_h·a_dst_h
// total ≈ 86.5 MB

// scan + fused dis + cursor copy
__global__ __launch_bounds__(1024) void k_scan(const int* __restrict__ indeg,
                                               int* __restrict__ rows,
                                               int* __restrict__ cursor,
                                               float* __restrict__ dis) {
    __shared__ int part[1024];
    int t = threadIdx.x;
    int base = t * 16;
    int local[16];
    int s = 0;
#pragma unroll
    for (int i = 0; i < 16; ++i) {
        local[i] = indeg[base + i]; s += local[i];
        dis[base + i] = rsqrtf((float)local[i] + 1.0f);
    }
    part[t] = s;
    __syncthreads();
    for (int off = 1; off < 1024; off <<= 1) {
        int v = (t >= off) ? part[t - off] : 0;
        __syncthreads();
        part[t] += v;
        __syncthreads();
    }
    int run = (t == 0) ? 0 : part[t - 1];
#pragma unroll
    for (int i = 0; i < 16; ++i) {
        rows[base + i] = run; cursor[base + i] = run; run += local[i];
    }
    if (t == 1023) rows[N_] = run;
}

__global__ void k_fill(const int* __restrict__ src, const int* __restrict__ dst,
                       int* __restrict__ cursor, int* __restrict__ csr) {
    int e = blockIdx.x * 256 + threadIdx.x;
    if (e < E_) {
        int p = atomicAdd(&cursor[dst[e]], 1);
        csr[p] = src[e];
    }
}

// ------- fused setup: weight transpose/convert + gbounds + v_es/v_ed + indeg -------
__global__ void k_wconv_all(const float* __restrict__ gat_w,
                            const float* __restrict__ gcn4_w,
                            const float* __restrict__ wl, const float* __restrict__ wr,
                            const int* __restrict__ batch,
                            const float* __restrict__ gat_as,
                            const float* __restrict__ gat_ad,
                            const int* __restrict__ dstE,
                            bf16u* __restrict__ wT1, bf16u* __restrict__ wT2,
                            bf16u* __restrict__ wT3, int* __restrict__ gb,
                            float* __restrict__ ves, float* __restrict__ ved,
                            int* __restrict__ indeg) {
    int idx = blockIdx.x * 256 + threadIdx.x;
    if (idx < 131072) {          // gat_w [128][1024] -> wT1[c][h*128+k] (stacked heads, /4)
        int c = idx >> 9;                        // output channel 0..255
        int kk = idx & 511;                      // h*128+k
        int h = kk >> 7, k = kk & 127;
        wT1[idx] = f2bf(0.25f * gat_w[(size_t)k * 1024 + h * 256 + c]);
    } else if (idx < 262144) {   // gcn4_w [256][512] -> wT2[512][256]
        int j = idx - 131072;
        int m = j >> 8, k = j & 255;
        wT2[j] = f2bf(gcn4_w[(size_t)k * 512 + m]);
    } else if (idx < 278528) {   // [wl;wr] -> wT3[128][128]
        int j = idx - 262144;
        int m = j >> 7, k = j & 127;
        float v = (k < 64) ? wl[k*128 + m] : wr[(k-64)*128 + m];
        wT3[j] = f2bf(v);
    } else if (idx < 278592) {   // graph-batch bounds
        int g = idx - 278528;
        if (g > G_) return;
        if (g == G_) { gb[G_] = N_; return; }
        int lo = 0, hi = N_;
        while (lo < hi) { int mid = (lo + hi) >> 1; if (batch[mid] < g) lo = mid + 1; else hi = mid; }
        gb[g] = lo;
    } else if (idx < 279104) {   // v_es (4 heads x 128 k)
        int j = idx - 278592;
        int h = j >> 7, k = j & 127;
        float s = 0.f;
        for (int c = 0; c < 256; ++c)
            s += gat_w[(size_t)k * 1024 + h*256 + c] * gat_as[h*256 + c];
        ves[j] = s;
    } else if (idx < 279616) {   // v_ed
        int j = idx - 279104;
        int h = j >> 7, k = j & 127;
        float s = 0.f;
        for (int c = 0; c < 256; ++c)
            s += gat_w[(size_t)k * 1024 + h*256 + c] * gat_ad[h*256 + c];
        ved[j] = s;
    } else if (idx < 410688) {   // indeg
        int e = idx - 279616;
        atomicAdd(&indeg[dstE[e]], 1);
    }
}

// ---------------- layer 1: GCN aggregate only -> xa [N][8] fp32 (512 KB) ----------------
__global__ __launch_bounds__(256) void k_gcn1x(const float* __restrict__ x,
                                               const float* __restrict__ dis,
                                               const int* __restrict__ rows,
                                               const int* __restrict__ csr,
                                               float* __restrict__ xa) {
    int wave = threadIdx.x >> 6, lane = threadIdx.x & 63;
    int i = blockIdx.x * 4 + wave;
    float a0=0,a1=0,a2=0,a3=0,a4=0;
    int e0 = rows[i], e1 = rows[i+1];
    for (int e = e0 + lane; e < e1; e += 64) {
        int s = csr[e];
        float wt = dis[s];
        a0 += x[s*5+0]*wt; a1 += x[s*5+1]*wt; a2 += x[s*5+2]*wt;
        a3 += x[s*5+3]*wt; a4 += x[s*5+4]*wt;
    }
#pragma unroll
    for (int off = 32; off > 0; off >>= 1) {
        a0 += __shfl_xor(a0, off, 64); a1 += __shfl_xor(a1, off, 64);
        a2 += __shfl_xor(a2, off, 64); a3 += __shfl_xor(a3, off, 64);
        a4 += __shfl_xor(a4, off, 64);
    }
    float di = dis[i];
    float v0 = di*(a0 + di*x[i*5+0]);
    float v1 = di*(a1 + di*x[i*5+1]);
    float v2 = di*(a2 + di*x[i*5+2]);
    float v3 = di*(a3 + di*x[i*5+3]);
    float v4 = di*(a4 + di*x[i*5+4]);
    if (lane < 5) {
        float v = lane == 0 ? v0 : lane == 1 ? v1 : lane == 2 ? v2 : lane == 3 ? v3 : v4;
        xa[(size_t)i*8 + lane] = v;
    }
}

// ---------------- xa moments stage A: block-reduce -> partial[64][20], NO global atomics ----------------
// (round-2 lesson: 256-deep same-address float-atomic chains serialize at ~220ns each = 56us)
__global__ __launch_bounds__(256) void k_xstats(const float* __restrict__ xa,
                                                float* __restrict__ partial) {
    __shared__ float wsum[80];   // 4 waves x 20
    int t = threadIdx.x;
    int tid = blockIdx.x * 256 + t;    // grid 64 -> exactly N threads
    float v0 = xa[(size_t)tid*8+0], v1 = xa[(size_t)tid*8+1], v2 = xa[(size_t)tid*8+2];
    float v3 = xa[(size_t)tid*8+3], v4 = xa[(size_t)tid*8+4];
    float m[20];
    m[0]=v0; m[1]=v1; m[2]=v2; m[3]=v3; m[4]=v4;
    m[5]=v0*v0;  m[6]=v0*v1;  m[7]=v0*v2;  m[8]=v0*v3;  m[9]=v0*v4;
    m[10]=v1*v1; m[11]=v1*v2; m[12]=v1*v3; m[13]=v1*v4;
    m[14]=v2*v2; m[15]=v2*v3; m[16]=v2*v4;
    m[17]=v3*v3; m[18]=v3*v4;
    m[19]=v4*v4;
#pragma unroll
    for (int off = 32; off > 0; off >>= 1)
#pragma unroll
        for (int j = 0; j < 20; ++j) m[j] += __shfl_xor(m[j], off, 64);
    int wave = t >> 6, lane = t & 63;
    if (lane == 0)
#pragma unroll
        for (int j = 0; j < 20; ++j) wsum[wave*20 + j] = m[j];
    __syncthreads();
    if (t < 20)
        partial[blockIdx.x * 20 + t] = wsum[t] + wsum[20+t] + wsum[40+t] + wsum[60+t];
}

// ---------------- stage B: 1 wave merges 64 partials, emits BN1 scale/base per channel ----------------
// h = xa·W + b; BN1 stats analytic: mu = E[xa]·W + b, var = wT Cov(xa) w (5x5).
__global__ __launch_bounds__(64) void k_bn1fin(const float* __restrict__ partial,
                                               const float* __restrict__ w,   // [5][64]
                                               const float* __restrict__ b,
                                               const float* __restrict__ bng,
                                               const float* __restrict__ bnb,
                                               float* __restrict__ sc,
                                               float* __restrict__ sh) {
    int l = threadIdx.x;
    const float invN = 1.0f / (float)N_;
    float m[20];
#pragma unroll
    for (int j = 0; j < 20; ++j) {
        float v = partial[l*20 + j];
#pragma unroll
        for (int off = 32; off > 0; off >>= 1) v += __shfl_xor(v, off, 64);
        m[j] = v * invN;
    }
    int c = l;
    float wc0 = w[c], wc1 = w[64+c], wc2 = w[128+c], wc3 = w[192+c], wc4 = w[256+c];
    float mu = b[c] + m[0]*wc0 + m[1]*wc1 + m[2]*wc2 + m[3]*wc3 + m[4]*wc4;
    float var = 0.f;
    var += (m[5]  - m[0]*m[0]) * wc0*wc0;
    var += (m[6]  - m[0]*m[1]) * wc0*wc1 * 2.f;
    var += (m[7]  - m[0]*m[2]) * wc0*wc2 * 2.f;
    var += (m[8]  - m[0]*m[3]) * wc0*wc3 * 2.f;
    var += (m[9]  - m[0]*m[4]) * wc0*wc4 * 2.f;
    var += (m[10] - m[1]*m[1]) * wc1*wc1;
    var += (m[11] - m[1]*m[2]) * wc1*wc2 * 2.f;
    var += (m[12] - m[1]*m[3]) * wc1*wc3 * 2.f;
    var += (m[13] - m[1]*m[4]) * wc1*wc4 * 2.f;
    var += (m[14] - m[2]*m[2]) * wc2*wc2;
    var += (m[15] - m[2]*m[3]) * wc2*wc3 * 2.f;
    var += (m[16] - m[2]*m[4]) * wc2*wc4 * 2.f;
    var += (m[17] - m[3]*m[3]) * wc3*wc3;
    var += (m[18] - m[3]*m[4]) * wc3*wc4 * 2.f;
    var += (m[19] - m[4]*m[4]) * wc4*wc4;
    float scale = rsqrtf(var + EPSF) * bng[c];
    sc[c] = scale;
    sh[c] = fmaf(b[c], scale, bnb[c] - mu * scale);
}

// ---------------- fused layer-1 apply + SAGE aggregate (wave-per-node) ----------------
// Self post-BN-ReLU -> ab[:,64:128]; neighbor mean of post-BN-ReLU -> ab[:,0:64].
// Neighbor gather hits the 512 KB xa array (L1/L2-resident).
__global__ __launch_bounds__(256) void k_sage_l1(const float* __restrict__ xa,
                                                 const float* __restrict__ sc,
                                                 const float* __restrict__ sh,
                                                 const float* __restrict__ w,   // [5][64]
                                                 const int* __restrict__ rows,
                                                 const int* __restrict__ csr,
                                                 bf16u* __restrict__ ab) {
    int wave = threadIdx.x >> 6, lane = threadIdx.x & 63;
    int i = blockIdx.x * 4 + wave;
    int c = lane;
    float wc0 = w[c], wc1 = w[64+c], wc2 = w[128+c], wc3 = w[192+c], wc4 = w[256+c];
    float scale = sc[c], base = sh[c];
    // self
    {
        const float* p = &xa[(size_t)i*8];
        float t = p[0]*wc0 + p[1]*wc1 + p[2]*wc2 + p[3]*wc3 + p[4]*wc4;
        float v = fmaf(t, scale, base); v = v > 0.f ? v : 0.f;
        ab[(size_t)i*128 + 64 + c] = f2bf(v);
    }
    // neighbors (mean of post-BN-ReLU)
    int e0 = rows[i], e1 = rows[i+1];
    float s = 0.f;
    for (int e = e0; e < e1; ++e) {
        const float* p = &xa[(size_t)csr[e]*8];
        float t = p[0]*wc0 + p[1]*wc1 + p[2]*wc2 + p[3]*wc3 + p[4]*wc4;
        float v = fmaf(t, scale, base); v = v > 0.f ? v : 0.f;
        s += v;
    }
    ab[(size_t)i*128 + c] = f2bf(s / fmaxf((float)(e1 - e0), 1.0f));
}

// ---------------- bf16 MFMA GEMM: C[n,m] = A[n,k]*BT[m,k]^T (+bias), bf16 out ----------------
// 128x128 tile, BK=32, 4 waves x (4x4) mfma_f32_16x16x32_bf16.
// Fused BN stats: 8-slot slabs (slot = blockIdx.y&7) cut same-address atomic
// chains 256 -> 32 deep (round-2 lesson). Consumers sum the 8 slots.
__global__ __launch_bounds__(256) void k_gemm_mfma(const bf16u* __restrict__ A,
                                                   const bf16u* __restrict__ BT,
                                                   const float* __restrict__ bias,
                                                   bf16u* __restrict__ C,
                                                   float* __restrict__ sum,
                                                   float* __restrict__ sumsq,
                                                   int K, int M) {
    __shared__ bf16u As[128][40];
    __shared__ bf16u Bs[128][40];
    int tid = threadIdx.x;
    int wave = tid >> 6, lane = tid & 63;
    int wr = (wave >> 1) * 64, wc = (wave & 1) * 64;
    int row0 = blockIdx.y * 128, col0 = blockIdx.x * 128;
    f4v acc[4][4];
#pragma unroll
    for (int i = 0; i < 4; ++i)
#pragma unroll
        for (int j = 0; j < 4; ++j) acc[i][j] = (f4v)0.0f;

    int sr = tid >> 1;             // 0..127
    int sh = (tid & 1) * 16;       // k-half within BK
    int lr = lane & 15, lq = lane >> 4;

    for (int k0 = 0; k0 < K; k0 += 32) {
        const bf16u* ap = A + (size_t)(row0 + sr) * K + k0 + sh;
        *(uint4*)&As[sr][sh]     = *(const uint4*)ap;
        *(uint4*)&As[sr][sh + 8] = *(const uint4*)(ap + 8);
        const bf16u* bp = BT + (size_t)(col0 + sr) * K + k0 + sh;
        *(uint4*)&Bs[sr][sh]     = *(const uint4*)bp;
        *(uint4*)&Bs[sr][sh + 8] = *(const uint4*)(bp + 8);
        __syncthreads();
        s8v af[4], bfr[4];
#pragma unroll
        for (int i = 0; i < 4; ++i)
            af[i] = *(const s8v*)&As[wr + i*16 + lr][lq*8];
#pragma unroll
        for (int j = 0; j < 4; ++j)
            bfr[j] = *(const s8v*)&Bs[wc + j*16 + lr][lq*8];
#pragma unroll
        for (int i = 0; i < 4; ++i)
#pragma unroll
            for (int j = 0; j < 4; ++j)
                acc[i][j] = __builtin_amdgcn_mfma_f32_16x16x32_bf16(af[i], bfr[j], acc[i][j], 0, 0, 0);
        __syncthreads();
    }

    int slot = (blockIdx.y & 7) << 9;    // 8 slabs of 512 floats
#pragma unroll
    for (int j = 0; j < 4; ++j) {
        int col = col0 + wc + j*16 + lr;
        float bv = bias ? bias[col] : 0.f;
        float s = 0.f, q = 0.f;
#pragma unroll
        for (int i = 0; i < 4; ++i) {
#pragma unroll
            for (int r = 0; r < 4; ++r) {
                float v = acc[i][j][r] + bv;
                int row = row0 + wr + i*16 + lq*4 + r;
                C[(size_t)row * M + col] = f2bf(v);
                s += v; q += v*v;
            }
        }
        if (sum) {
            s += __shfl_xor(s, 16, 64); q += __shfl_xor(q, 16, 64);
            s += __shfl_xor(s, 32, 64); q += __shfl_xor(q, 32, 64);
            if (lq == 0) { atomicAdd(&sum[slot + col], s); atomicAdd(&sumsq[slot + col], q); }
        }
    }
}

// ---------------- BN2 apply + fused GAT attention coefficients (wave-per-node) ----------------
__global__ __launch_bounds__(256) void k_bn_apply2b_attn(
        const bf16u* __restrict__ hp, const float* __restrict__ sum,
        const float* __restrict__ sumsq, const float* __restrict__ g,
        const float* __restrict__ b, const float* __restrict__ ves,
        const float* __restrict__ ved, bf16u* __restrict__ hb,
        float* __restrict__ es, float* __restrict__ ed) {
    int wave = threadIdx.x >> 6, lane = threadIdx.x & 63;
    int i = blockIdx.x * 4 + wave;
    int c = lane * 2;
    const float invN = 1.0f / (float)N_;
    float sx=0.f, sy=0.f, qx=0.f, qy=0.f;
#pragma unroll
    for (int s8 = 0; s8 < 8; ++s8) {
        float2 a = *(const float2*)&sum[s8*512 + c];
        float2 d = *(const float2*)&sumsq[s8*512 + c];
        sx += a.x; sy += a.y; qx += d.x; qy += d.y;
    }
    float2 gg = *(const float2*)&g[c];
    float2 bb = *(const float2*)&b[c];
    float mu0 = sx*invN, mu1 = sy*invN;
    float sc0 = rsqrtf(qx*invN - mu0*mu0 + EPSF)*gg.x, sh0 = bb.x - mu0*sc0;
    float sc1 = rsqrtf(qy*invN - mu1*mu1 + EPSF)*gg.y, sh1 = bb.y - mu1*sc1;
    unsigned pv = *(const unsigned*)&hp[(size_t)i*128 + c];
    float v0 = bf2f((bf16u)(pv & 0xFFFF));
    float v1 = bf2f((bf16u)(pv >> 16));
    v0 = fmaf(v0, sc0, sh0); v0 = v0 > 0.f ? v0 : 0.f;
    v1 = fmaf(v1, sc1, sh1); v1 = v1 > 0.f ? v1 : 0.f;
    unsigned ow = (unsigned)f2bf(v0) | ((unsigned)f2bf(v1) << 16);
    *(unsigned*)&hb[(size_t)i*128 + c] = ow;
    float vs[4], vd[4];
#pragma unroll
    for (int h = 0; h < 4; ++h) {
        float2 a = *(const float2*)&ves[h*128 + c];
        float2 d = *(const float2*)&ved[h*128 + c];
        vs[h] = v0*a.x + v1*a.y;
        vd[h] = v0*d.x + v1*d.y;
    }
#pragma unroll
    for (int off = 32; off > 0; off >>= 1) {
#pragma unroll
        for (int h = 0; h < 4; ++h) {
            vs[h] += __shfl_xor(vs[h], off, 64);
            vd[h] += __shfl_xor(vd[h], off, 64);
        }
    }
    if (lane == 0) {
        *(float4*)&es[i*4] = make_float4(vs[0], vs[1], vs[2], vs[3]);
        *(float4*)&ed[i*4] = make_float4(vd[0], vd[1], vd[2], vd[3]);
    }
}

// ---------------- GAT: fused max + single-pass softmax aggregation of h2b ----------------
__global__ __launch_bounds__(256) void k_gat_agg2(const bf16u* __restrict__ h2b,
                                                  const float* __restrict__ es,
                                                  const float* __restrict__ ed,
                                                  const int* __restrict__ rows,
                                                  const int* __restrict__ csr,
                                                  bf16u* __restrict__ agg) {
    int wave = threadIdx.x >> 6, lane = threadIdx.x & 63;
    int i = blockIdx.x * 4 + wave;
    int c = lane * 2;
    float4 edv = *(const float4*)&ed[i*4];
    float4 sv  = *(const float4*)&es[i*4];
    int e0 = rows[i], e1 = rows[i+1];
    // ---- pass 1: exact per-node logit max (incl self-loop), lane-parallel ----
    float e, m0, m1, m2, m3;
    e = sv.x + edv.x; m0 = e >= 0.f ? e : 0.2f*e;
    e = sv.y + edv.y; m1 = e >= 0.f ? e : 0.2f*e;
    e = sv.z + edv.z; m2 = e >= 0.f ? e : 0.2f*e;
    e = sv.w + edv.w; m3 = e >= 0.f ? e : 0.2f*e;
    for (int ee = e0 + lane; ee < e1; ee += 64) {
        int s = csr[ee];
        float4 s2 = *(const float4*)&es[s*4];
        e = s2.x + edv.x; m0 = fmaxf(m0, e >= 0.f ? e : 0.2f*e);
        e = s2.y + edv.y; m1 = fmaxf(m1, e >= 0.f ? e : 0.2f*e);
        e = s2.z + edv.z; m2 = fmaxf(m2, e >= 0.f ? e : 0.2f*e);
        e = s2.w + edv.w; m3 = fmaxf(m3, e >= 0.f ? e : 0.2f*e);
    }
#pragma unroll
    for (int off = 32; off > 0; off >>= 1) {
        m0 = fmaxf(m0, __shfl_xor(m0, off, 64));
        m1 = fmaxf(m1, __shfl_xor(m1, off, 64));
        m2 = fmaxf(m2, __shfl_xor(m2, off, 64));
        m3 = fmaxf(m3, __shfl_xor(m3, off, 64));
    }
    // ---- pass 2: softmax-weighted aggregation (serial edges, lanes = channels) ----
    float z0, z1, z2, z3;
    float a00, a01, a10, a11, a20, a21, a30, a31;
    {
        e = sv.x + edv.x; e = e >= 0.f ? e : 0.2f*e; z0 = __expf(e - m0);
        e = sv.y + edv.y; e = e >= 0.f ? e : 0.2f*e; z1 = __expf(e - m1);
        e = sv.z + edv.z; e = e >= 0.f ? e : 0.2f*e; z2 = __expf(e - m2);
        e = sv.w + edv.w; e = e >= 0.f ? e : 0.2f*e; z3 = __expf(e - m3);
        unsigned pv = *(const unsigned*)&h2b[(size_t)i*128 + c];
        float v0 = bf2f((bf16u)(pv & 0xFFFF)), v1 = bf2f((bf16u)(pv >> 16));
        a00 = z0*v0; a01 = z0*v1; a10 = z1*v0; a11 = z1*v1;
        a20 = z2*v0; a21 = z2*v1; a30 = z3*v0; a31 = z3*v1;
    }
    for (int ee = e0; ee < e1; ++ee) {
        int s = csr[ee];
        float4 s2 = *(const float4*)&es[s*4];
        unsigned pv = *(const unsigned*)&h2b[(size_t)s*128 + c];
        float v0 = bf2f((bf16u)(pv & 0xFFFF)), v1 = bf2f((bf16u)(pv >> 16));
        float ex;
        e = s2.x + edv.x; e = e >= 0.f ? e : 0.2f*e; ex = __expf(e - m0);
        z0 += ex; a00 = fmaf(ex, v0, a00); a01 = fmaf(ex, v1, a01);
        e = s2.y + edv.y; e = e >= 0.f ? e : 0.2f*e; ex = __expf(e - m1);
        z1 += ex; a10 = fmaf(ex, v0, a10); a11 = fmaf(ex, v1, a11);
        e = s2.z + edv.z; e = e >= 0.f ? e : 0.2f*e; ex = __expf(e - m2);
        z2 += ex; a20 = fmaf(ex, v0, a20); a21 = fmaf(ex, v1, a21);
        e = s2.w + edv.w; e = e >= 0.f ? e : 0.2f*e; ex = __expf(e - m3);
        z3 += ex; a30 = fmaf(ex, v0, a30); a31 = fmaf(ex, v1, a31);
    }
    size_t base = (size_t)i * 512 + c;
    float r; unsigned ow;
    r = 1.f/z0; ow = (unsigned)f2bf(a00*r) | ((unsigned)f2bf(a01*r) << 16);
    *(unsigned*)&agg[base]       = ow;
    r = 1.f/z1; ow = (unsigned)f2bf(a10*r) | ((unsigned)f2bf(a11*r) << 16);
    *(unsigned*)&agg[base + 128] = ow;
    r = 1.f/z2; ow = (unsigned)f2bf(a20*r) | ((unsigned)f2bf(a21*r) << 16);
    *(unsigned*)&agg[base + 256] = ow;
    r = 1.f/z3; ow = (unsigned)f2bf(a30*r) | ((unsigned)f2bf(a31*r) << 16);
    *(unsigned*)&agg[base + 384] = ow;
}

// ---------------- layer 4: fused BN3+ReLU + GCN aggregate (wave-per-node, ushort4) ----------------
__global__ __launch_bounds__(256) void k_gcn4_agg(const bf16u* __restrict__ h3b,
                                                  const float* __restrict__ dis,
                                                  const int* __restrict__ rows,
                                                  const int* __restrict__ csr,
                                                  const float* __restrict__ sum,
                                                  const float* __restrict__ sumsq,
                                                  const float* __restrict__ g,
                                                  const float* __restrict__ b,
                                                  bf16u* __restrict__ xab) {
    int wave = threadIdx.x >> 6, q = threadIdx.x & 63;
    int i = blockIdx.x * 4 + wave;
    int c = q * 4;
    const float invN = 1.0f / (float)N_;
    float4 sm = make_float4(0.f,0.f,0.f,0.f), sq = make_float4(0.f,0.f,0.f,0.f);
#pragma unroll
    for (int s8 = 0; s8 < 8; ++s8) {
        float4 a = *(const float4*)&sum[s8*512 + c];
        float4 d = *(const float4*)&sumsq[s8*512 + c];
        sm.x += a.x; sm.y += a.y; sm.z += a.z; sm.w += a.w;
        sq.x += d.x; sq.y += d.y; sq.z += d.z; sq.w += d.w;
    }
    float4 gg = *(const float4*)&g[c];
    float4 bb = *(const float4*)&b[c];
    float mu, sc0, sc1, sc2, sc3, sh0, sh1, sh2, sh3;
    mu = sm.x*invN; sc0 = rsqrtf(sq.x*invN - mu*mu + EPSF)*gg.x; sh0 = bb.x - mu*sc0;
    mu = sm.y*invN; sc1 = rsqrtf(sq.y*invN - mu*mu + EPSF)*gg.y; sh1 = bb.y - mu*sc1;
    mu = sm.z*invN; sc2 = rsqrtf(sq.z*invN - mu*mu + EPSF)*gg.z; sh2 = bb.z - mu*sc2;
    mu = sm.w*invN; sc3 = rsqrtf(sq.w*invN - mu*mu + EPSF)*gg.w; sh3 = bb.w - mu*sc3;
    float di = dis[i];
    float a0, a1, a2, a3;
    {
        ushort4 u = *(const ushort4*)(h3b + (size_t)i*256 + c);
        float v, dd = di * di;
        v = fmaf(bf2f(u.x), sc0, sh0); v = v > 0.f ? v : 0.f; a0 = v * dd;
        v = fmaf(bf2f(u.y), sc1, sh1); v = v > 0.f ? v : 0.f; a1 = v * dd;
        v = fmaf(bf2f(u.z), sc2, sh2); v = v > 0.f ? v : 0.f; a2 = v * dd;
        v = fmaf(bf2f(u.w), sc3, sh3); v = v > 0.f ? v : 0.f; a3 = v * dd;
    }
    int e0 = rows[i], e1 = rows[i+1];
    for (int e = e0; e < e1; ++e) {
        int s = csr[e];
        float w = dis[s] * di;
        ushort4 u = *(const ushort4*)(h3b + (size_t)s*256 + c);
        float v;
        v = fmaf(bf2f(u.x), sc0, sh0); v = v > 0.f ? v : 0.f; a0 += v * w;
        v = fmaf(bf2f(u.y), sc1, sh1); v = v > 0.f ? v : 0.f; a1 += v * w;
        v = fmaf(bf2f(u.z), sc2, sh2); v = v > 0.f ? v : 0.f; a2 += v * w;
        v = fmaf(bf2f(u.w), sc3, sh3); v = v > 0.f ? v : 0.f; a3 += v * w;
    }
    ushort4 o;
    o.x = f2bf(a0); o.y = f2bf(a1); o.z = f2bf(a2); o.w = f2bf(a3);
    *(ushort4*)(xab + (size_t)i*256 + c) = o;
}

// ---------------- pooling with fused BN4+ReLU (+ folded fc-init blocks) ----------------
__global__ void k_pool(const bf16u* __restrict__ h4b, const int* __restrict__ gb,
                       const float* __restrict__ sum, const float* __restrict__ sumsq,
                       const float* __restrict__ g, const float* __restrict__ b,
                       const float* __restrict__ fcb,
                       float* __restrict__ pooled, float* __restrict__ out) {
    int bidx = blockIdx.x;
    int t = threadIdx.x;
    if (bidx >= 512) {                 // fc-init: out = bias (independent work)
        int i = (bidx - 512) * 256 + t;
        out[i] = fcb[i & 1023];
        return;
    }
    int gi = bidx >> 4;
    int chunk = bidx & 15;
    const float invN = 1.0f / (float)N_;
    float su0=0.f, qq0=0.f, su1=0.f, qq1=0.f;
#pragma unroll
    for (int s8 = 0; s8 < 8; ++s8) {
        su0 += sum[s8*512 + t];       qq0 += sumsq[s8*512 + t];
        su1 += sum[s8*512 + 256 + t]; qq1 += sumsq[s8*512 + 256 + t];
    }
    float mu0 = su0 * invN;
    float sc0 = rsqrtf(qq0 * invN - mu0*mu0 + EPSF) * g[t];
    float sh0 = b[t] - mu0 * sc0;
    float mu1 = su1 * invN;
    float sc1 = rsqrtf(qq1 * invN - mu1*mu1 + EPSF) * g[t+256];
    float sh1 = b[t+256] - mu1 * sc1;
    int r0g = gb[gi], r1g = gb[gi+1];
    int n = r1g - r0g;
    if (n <= 0) return;
    int per = (n + 15) >> 4;
    int r0 = r0g + chunk * per;
    int r1 = min(r0 + per, r1g);
    if (r0 >= r1) return;
    float s0=0.f, s1=0.f, m0=0.f, m1=0.f;   // post-ReLU >= 0: max init 0 valid
    for (int r = r0; r < r1; ++r) {
        float v = fmaf(bf2f(h4b[(size_t)r*512 + t]), sc0, sh0);
        v = v > 0.f ? v : 0.f;
        s0 += v; m0 = fmaxf(m0, v);
        float w = fmaf(bf2f(h4b[(size_t)r*512 + 256 + t]), sc1, sh1);
        w = w > 0.f ? w : 0.f;
        s1 += w; m1 = fmaxf(m1, w);
    }
    atomicAdd(&pooled[gi*1024 + t], s0);
    atomicAdd(&pooled[gi*1024 + 256 + t], s1);
    atomicMax((int*)&pooled[gi*1024 + 512 + t],  __float_as_int(m0));
    atomicMax((int*)&pooled[gi*1024 + 768 + t],  __float_as_int(m1));
}

// ---------------- FC (K-split, float4, atomic reduce; mean-scale folded in) ----------------
#define FCKZ 16
#define FCKC (1024 / FCKZ)   // 64

__global__ __launch_bounds__(256) void k_fc2(const float* __restrict__ pooled,
                                             const float* __restrict__ w,
                                             const int* __restrict__ gb,
                                             float* __restrict__ out) {
    __shared__ float pr[FCKC];
    int g = blockIdx.x;
    int z = blockIdx.y;
    int t = threadIdx.x;
    int k0 = z * FCKC;
    if (t < FCKC) {
        float scale = (z < 8) ? 1.0f / fmaxf((float)(gb[g+1] - gb[g]), 1.0f) : 1.0f;
        pr[t] = pooled[g * 1024 + k0 + t] * scale;   // mean part needs 1/cnt
    }
    __syncthreads();
    int m0 = t * 4;
    float ax = 0.f, ay = 0.f, az = 0.f, aw = 0.f;
#pragma unroll 8
    for (int k = 0; k < FCKC; ++k) {
        const float4 wv = *(const float4*)&w[(size_t)(k0 + k) * 1024 + m0];
        float p = pr[k];
        ax += p * wv.x; ay += p * wv.y; az += p * wv.z; aw += p * wv.w;
    }
    atomicAdd(&out[g * 1024 + m0 + 0], ax);
    atomicAdd(&out[g * 1024 + m0 + 1], ay);
    atomicAdd(&out[g * 1024 + m0 + 2], az);
    atomicAdd(&out[g * 1024 + m0 + 3], aw);
}

// ---------------- host ----------------
extern "C" void kernel_launch(void* const* d_in, const int* in_sizes, int n_in,
                              void* d_out, int out_size, void* d_ws, size_t ws_size,
                              hipStream_t stream) {
    (void)in_sizes; (void)n_in; (void)out_size; (void)ws_size;
    const float* x       = (const float*)d_in[0];
    const int*   ei      = (const int*)d_in[1];
    const int*   batch   = (const int*)d_in[2];
    const float* gcn1_w  = (const float*)d_in[3];
    const float* gcn1_b  = (const float*)d_in[4];
    const float* sage_wl = (const float*)d_in[5];
    const float* sage_wr = (const float*)d_in[6];
    const float* sage_b  = (const float*)d_in[7];
    const float* gat_w   = (const float*)d_in[8];
    const float* gat_as  = (const float*)d_in[9];
    const float* gat_ad  = (const float*)d_in[10];
    const float* gat_b   = (const float*)d_in[11];
    const float* gcn4_w  = (const float*)d_in[12];
    const float* gcn4_b  = (const float*)d_in[13];
    const float* bn1_g   = (const float*)d_in[14];
    const float* bn1_b   = (const float*)d_in[15];
    const float* bn2_g   = (const float*)d_in[16];
    const float* bn2_b   = (const float*)d_in[17];
    const float* bn3_g   = (const float*)d_in[18];
    const float* bn3_b   = (const float*)d_in[19];
    const float* bn4_g   = (const float*)d_in[20];
    const float* bn4_b   = (const float*)d_in[21];
    const float* fc_w    = (const float*)d_in[22];
    const float* fc_b    = (const float*)d_in[23];
    float* out = (float*)d_out;

    char* w8 = (char*)d_ws;
    int*   indeg  = (int*)(w8 + OFF_INDEG);
    int*   rows   = (int*)(w8 + OFF_ROWS);
    int*   cursor = (int*)(w8 + OFF_CURSOR);
    int*   csr    = (int*)(w8 + OFF_CSR);
    float* dis    = (float*)(w8 + OFF_DIS);
    float* es     = (float*)(w8 + OFF_ES);
    float* ed     = (float*)(w8 + OFF_ED);
    float* bns    = (float*)(w8 + OFF_BNS);   // [4][8][512] slabs per layer
    float* bnq    = (float*)(w8 + OFF_BNQ);
    int*   gb     = (int*)(w8 + OFF_GB);
    float* pooled = (float*)(w8 + OFF_POOL);
    float* part   = (float*)(w8 + OFF_PART);
    float* bn1sc  = (float*)(w8 + OFF_BN1C);
    float* bn1sh  = (float*)(w8 + OFF_BN1C + 256);
    float* xa     = (float*)(w8 + OFF_XA);
    bf16u* ab     = (bf16u*)(w8 + OFF_AB);
    bf16u* h2p    = (bf16u*)(w8 + OFF_H2P);
    bf16u* h2b    = (bf16u*)(w8 + OFF_H2B);
    bf16u* h3b    = (bf16u*)(w8 + OFF_H3B);
    bf16u* agg    = (bf16u*)(w8 + OFF_AGG);
    bf16u* xa4b   = (bf16u*)(w8 + OFF_XA4B);
    bf16u* wT1    = (bf16u*)(w8 + OFF_WT1);
    bf16u* wT2    = (bf16u*)(w8 + OFF_WT2);
    bf16u* wT3    = (bf16u*)(w8 + OFF_WT3);
    bf16u* h4b    = (bf16u*)(w8 + OFF_H4B);
    float* ves    = (float*)(w8 + OFF_VES);
    float* ved    = (float*)(w8 + OFF_VED);

    const int* srcE = ei;        // edge_index[0,:]
    const int* dstE = ei + E_;   // edge_index[1,:]

    // ---- setup: ONE memset, then fused setup kernel (weights+gbounds+ves/ved+indeg) ----
    hipMemsetAsync(w8, 0, OFF_MSET, stream);
    k_wconv_all<<<1605, 256, 0, stream>>>(gat_w, gcn4_w, sage_wl, sage_wr, batch,
                                          gat_as, gat_ad, dstE,
                                          wT1, wT2, wT3, gb, ves, ved, indeg);
    k_scan<<<1, 1024, 0, stream>>>(indeg, rows, cursor, dis);
    k_fill<<<E_/256, 256, 0, stream>>>(srcE, dstE, cursor, csr);

    // ---- layer 1+2 front: GCN agg -> xa; analytic BN1 (block-reduce, no atomic chains) ----
    k_gcn1x<<<N_/4, 256, 0, stream>>>(x, dis, rows, csr, xa);
    k_xstats<<<64, 256, 0, stream>>>(xa, part);
    k_bn1fin<<<1, 64, 0, stream>>>(part, gcn1_w, gcn1_b, bn1_g, bn1_b, bn1sc, bn1sh);
    k_sage_l1<<<N_/4, 256, 0, stream>>>(xa, bn1sc, bn1sh, gcn1_w, rows, csr, ab);

    // ---- layer 2: SAGE 64->128 via single MFMA GEMM (stats fused in epilogue) ----
    {
        dim3 grid(1, N_/128);
        k_gemm_mfma<<<grid, 256, 0, stream>>>(ab, wT3, sage_b, h2p,
                                              bns + 4096, bnq + 4096, 128, 128);
    }
    k_bn_apply2b_attn<<<N_/4, 256, 0, stream>>>(h2p, bns + 4096, bnq + 4096, bn2_g, bn2_b,
                                                ves, ved, h2b, es, ed);

    // ---- layer 3: GAT — aggregate h2b per head (fused max+softmax), then 512->256 GEMM ----
    k_gat_agg2<<<N_/4, 256, 0, stream>>>(h2b, es, ed, rows, csr, agg);
    {
        dim3 grid(256/128, N_/128);
        k_gemm_mfma<<<grid, 256, 0, stream>>>(agg, wT1, gat_b, h3b,
                                              bns + 8192, bnq + 8192, 512, 256);
    }

    // ---- layer 4: fused BN3+ReLU+aggregate, MFMA GEMM 256->512 (stats fused) ----
    k_gcn4_agg<<<N_/4, 256, 0, stream>>>(h3b, dis, rows, csr, bns + 8192, bnq + 8192,
                                         bn3_g, bn3_b, xa4b);
    {
        dim3 grid(512/128, N_/128);
        k_gemm_mfma<<<grid, 256, 0, stream>>>(xa4b, wT2, gcn4_b, h4b,
                                              bns + 12288, bnq + 12288, 256, 512);
    }

    // ---- pooling with fused BN4+ReLU (+fc-init blocks) -> [32,1024] ----
    k_pool<<<640, 256, 0, stream>>>(h4b, gb, bns + 12288, bnq + 12288, bn4_g, bn4_b,
                                    fc_b, pooled, out);

    // ---- FC 1024->1024 ----
    {
        dim3 grid(G_, FCKZ);
        k_fc2<<<grid, 256, 0, stream>>>(pooled, fc_w, gb, out);
    }
}

// Round 4
// 287.765 us; speedup vs baseline: 1.4131x; 1.0599x over previous
//
#include <hip/hip_runtime.h>

#define N_ 16384
#define E_ 131072
#define G_ 32
#define EPSF 1e-5f

typedef unsigned short bf16u;
typedef __attribute__((ext_vector_type(8))) short s8v;   // 8 bf16 (4 VGPRs)
typedef __attribute__((ext_vector_type(4))) float f4v;   // 4 fp32 acc

__device__ __forceinline__ bf16u f2bf(float v) {
    union { float f; unsigned u; } x; x.f = v;
    unsigned r = x.u + 0x7FFF + ((x.u >> 16) & 1);   // RNE
    return (bf16u)(r >> 16);
}
__device__ __forceinline__ float bf2f(bf16u u) {
    union { unsigned u; float f; } x; x.u = (unsigned)u << 16;
    return x.f;
}

// ---------------- workspace layout (bytes) ----------------
// Zeroed region [0, OFF_MSET):
static const size_t OFF_INDEG = 0;          // int[N]
static const size_t OFF_ROWS  = 65536;      // int[N+1]
static const size_t OFF_CURSOR= 131584;     // int[N]
static const size_t OFF_CSR   = 197120;     // int[E]
static const size_t OFF_DIS   = 721408;     // float[N]
static const size_t OFF_ES    = 786944;     // float[4N]
static const size_t OFF_ED    = 1049088;    // float[4N]
static const size_t OFF_BNS   = 1311232;    // float[4][8][512] 8-slot stats slabs (64 KB)
static const size_t OFF_BNQ   = 1376768;    // float[4][8][512] (64 KB)
static const size_t OFF_GB    = 1442304;    // int[33]
static const size_t OFF_CNT   = 1442444;    // int  (xstats last-block counter)
static const size_t OFF_POOL  = 1442560;    // float[32*1024]
static const size_t OFF_MSET  = 1573632;    // (memset end marker)
// Unzeroed (fully written before read):
static const size_t OFF_PART  = 1573632;    // float[64][20] xa-moment partials
static const size_t OFF_BN1C  = 1578752;    // float[64] scale + float[64] base
static const size_t OFF_XA    = 1786624;    // float[8N]  512 KB (padded [N][8] GCN1 agg)
static const size_t OFF_AB    = 5980928;    // bf16[128N]   4 MB ([agg|h1] concat)
static const size_t OFF_H2P   = 10175232;   // bf16[128N]   4 MB (pre-BN)
static const size_t OFF_H2B   = 14369536;   // bf16[128N]   4 MB (post-BN)
static const size_t OFF_H3B   = 18563840;   // bf16[256N]   8 MB
static const size_t OFF_AGG   = 35328768;   // bf16[512N]  16 MB (GAT head-agg of h2b)
static const size_t OFF_XA4B  = 52105984;   // bf16[256N]   8 MB
static const size_t OFF_WT1   = 68883200;   // bf16[256*512] (0.25*gat_w stacked-head ^T)
static const size_t OFF_WT2   = 69145344;   // bf16[512*256]
static const size_t OFF_WT3   = 69407488;   // bf16[128*128]
static const size_t OFF_H4B   = 69440256;   // bf16[512N] 16 MB
static const size_t OFF_VES   = 86479616;   // float[4][128]  W_h·a_src_h
static const size_t OFF_VED   = 86481664;   // float[4][128]  W_h·a_dst_h
// total ≈ 86.5 MB

// scan + fused dis + cursor copy
__global__ __launch_bounds__(1024) void k_scan(const int* __restrict__ indeg,
                                               int* __restrict__ rows,
                                               int* __restrict__ cursor,
                                               float* __restrict__ dis) {
    __shared__ int part[1024];
    int t = threadIdx.x;
    int base = t * 16;
    int local[16];
    int s = 0;
#pragma unroll
    for (int i = 0; i < 16; ++i) {
        local[i] = indeg[base + i]; s += local[i];
        dis[base + i] = rsqrtf((float)local[i] + 1.0f);
    }
    part[t] = s;
    __syncthreads();
    for (int off = 1; off < 1024; off <<= 1) {
        int v = (t >= off) ? part[t - off] : 0;
        __syncthreads();
        part[t] += v;
        __syncthreads();
    }
    int run = (t == 0) ? 0 : part[t - 1];
#pragma unroll
    for (int i = 0; i < 16; ++i) {
        rows[base + i] = run; cursor[base + i] = run; run += local[i];
    }
    if (t == 1023) rows[N_] = run;
}

__global__ void k_fill(const int* __restrict__ src, const int* __restrict__ dst,
                       int* __restrict__ cursor, int* __restrict__ csr) {
    int e = blockIdx.x * 256 + threadIdx.x;
    if (e < E_) {
        int p = atomicAdd(&cursor[dst[e]], 1);
        csr[p] = src[e];
    }
}

// ------- fused setup: weight transpose/convert + gbounds + v_es/v_ed + indeg -------
__global__ void k_wconv_all(const float* __restrict__ gat_w,
                            const float* __restrict__ gcn4_w,
                            const float* __restrict__ wl, const float* __restrict__ wr,
                            const int* __restrict__ batch,
                            const float* __restrict__ gat_as,
                            const float* __restrict__ gat_ad,
                            const int* __restrict__ dstE,
                            bf16u* __restrict__ wT1, bf16u* __restrict__ wT2,
                            bf16u* __restrict__ wT3, int* __restrict__ gb,
                            float* __restrict__ ves, float* __restrict__ ved,
                            int* __restrict__ indeg) {
    int idx = blockIdx.x * 256 + threadIdx.x;
    if (idx < 131072) {          // gat_w [128][1024] -> wT1[c][h*128+k] (stacked heads, /4)
        int c = idx >> 9;                        // output channel 0..255
        int kk = idx & 511;                      // h*128+k
        int h = kk >> 7, k = kk & 127;
        wT1[idx] = f2bf(0.25f * gat_w[(size_t)k * 1024 + h * 256 + c]);
    } else if (idx < 262144) {   // gcn4_w [256][512] -> wT2[512][256]
        int j = idx - 131072;
        int m = j >> 8, k = j & 255;
        wT2[j] = f2bf(gcn4_w[(size_t)k * 512 + m]);
    } else if (idx < 278528) {   // [wl;wr] -> wT3[128][128]
        int j = idx - 262144;
        int m = j >> 7, k = j & 127;
        float v = (k < 64) ? wl[k*128 + m] : wr[(k-64)*128 + m];
        wT3[j] = f2bf(v);
    } else if (idx < 278592) {   // graph-batch bounds
        int g = idx - 278528;
        if (g > G_) return;
        if (g == G_) { gb[G_] = N_; return; }
        int lo = 0, hi = N_;
        while (lo < hi) { int mid = (lo + hi) >> 1; if (batch[mid] < g) lo = mid + 1; else hi = mid; }
        gb[g] = lo;
    } else if (idx < 279104) {   // v_es (4 heads x 128 k)
        int j = idx - 278592;
        int h = j >> 7, k = j & 127;
        float s = 0.f;
        for (int c = 0; c < 256; ++c)
            s += gat_w[(size_t)k * 1024 + h*256 + c] * gat_as[h*256 + c];
        ves[j] = s;
    } else if (idx < 279616) {   // v_ed
        int j = idx - 279104;
        int h = j >> 7, k = j & 127;
        float s = 0.f;
        for (int c = 0; c < 256; ++c)
            s += gat_w[(size_t)k * 1024 + h*256 + c] * gat_ad[h*256 + c];
        ved[j] = s;
    } else if (idx < 410688) {   // indeg
        int e = idx - 279616;
        atomicAdd(&indeg[dstE[e]], 1);
    }
}

// ---------------- layer 1: GCN aggregate only -> xa [N][8] fp32 (512 KB) ----------------
__global__ __launch_bounds__(256) void k_gcn1x(const float* __restrict__ x,
                                               const float* __restrict__ dis,
                                               const int* __restrict__ rows,
                                               const int* __restrict__ csr,
                                               float* __restrict__ xa) {
    int wave = threadIdx.x >> 6, lane = threadIdx.x & 63;
    int i = blockIdx.x * 4 + wave;
    float a0=0,a1=0,a2=0,a3=0,a4=0;
    int e0 = rows[i], e1 = rows[i+1];
    for (int e = e0 + lane; e < e1; e += 64) {
        int s = csr[e];
        float wt = dis[s];
        a0 += x[s*5+0]*wt; a1 += x[s*5+1]*wt; a2 += x[s*5+2]*wt;
        a3 += x[s*5+3]*wt; a4 += x[s*5+4]*wt;
    }
#pragma unroll
    for (int off = 32; off > 0; off >>= 1) {
        a0 += __shfl_xor(a0, off, 64); a1 += __shfl_xor(a1, off, 64);
        a2 += __shfl_xor(a2, off, 64); a3 += __shfl_xor(a3, off, 64);
        a4 += __shfl_xor(a4, off, 64);
    }
    float di = dis[i];
    float v0 = di*(a0 + di*x[i*5+0]);
    float v1 = di*(a1 + di*x[i*5+1]);
    float v2 = di*(a2 + di*x[i*5+2]);
    float v3 = di*(a3 + di*x[i*5+3]);
    float v4 = di*(a4 + di*x[i*5+4]);
    if (lane < 5) {
        float v = lane == 0 ? v0 : lane == 1 ? v1 : lane == 2 ? v2 : lane == 3 ? v3 : v4;
        xa[(size_t)i*8 + lane] = v;
    }
}

// ---------------- xa moments + analytic BN1 coeffs, single kernel ----------------
// Stage A: per-block reduce -> partial[64][20] (no global atomic chains, round-2 lesson).
// Stage B: last-block-done (device counter + threadfence) runs the 1-wave finale that
// merges 64 partials and emits BN1 scale/base per channel (saves a launch).
__global__ __launch_bounds__(256) void k_xstats(const float* __restrict__ xa,
                                                float* __restrict__ partial,
                                                int* __restrict__ cnt,
                                                const float* __restrict__ w,   // [5][64]
                                                const float* __restrict__ b,
                                                const float* __restrict__ bng,
                                                const float* __restrict__ bnb,
                                                float* __restrict__ sc,
                                                float* __restrict__ sh) {
    __shared__ float wsum[80];   // 4 waves x 20
    __shared__ int lastFlag;
    int t = threadIdx.x;
    int tid = blockIdx.x * 256 + t;    // grid 64 -> exactly N threads
    float v0 = xa[(size_t)tid*8+0], v1 = xa[(size_t)tid*8+1], v2 = xa[(size_t)tid*8+2];
    float v3 = xa[(size_t)tid*8+3], v4 = xa[(size_t)tid*8+4];
    float m[20];
    m[0]=v0; m[1]=v1; m[2]=v2; m[3]=v3; m[4]=v4;
    m[5]=v0*v0;  m[6]=v0*v1;  m[7]=v0*v2;  m[8]=v0*v3;  m[9]=v0*v4;
    m[10]=v1*v1; m[11]=v1*v2; m[12]=v1*v3; m[13]=v1*v4;
    m[14]=v2*v2; m[15]=v2*v3; m[16]=v2*v4;
    m[17]=v3*v3; m[18]=v3*v4;
    m[19]=v4*v4;
#pragma unroll
    for (int off = 32; off > 0; off >>= 1)
#pragma unroll
        for (int j = 0; j < 20; ++j) m[j] += __shfl_xor(m[j], off, 64);
    int wave = t >> 6, lane = t & 63;
    if (lane == 0)
#pragma unroll
        for (int j = 0; j < 20; ++j) wsum[wave*20 + j] = m[j];
    __syncthreads();
    if (t < 20) {
        partial[blockIdx.x * 20 + t] = wsum[t] + wsum[20+t] + wsum[40+t] + wsum[60+t];
        __threadfence();           // make this block's partial device-visible
    }
    __syncthreads();
    if (t == 0) lastFlag = (atomicAdd(cnt, 1) == 63);
    __syncthreads();
    if (!lastFlag || t >= 64) return;
    // ---- finale: 1 wave merges 64 partials (other blocks' writes fenced+published) ----
    int l = t;
    const float invN = 1.0f / (float)N_;
    float mm[20];
#pragma unroll
    for (int j = 0; j < 20; ++j) {
        float v = partial[l*20 + j];
#pragma unroll
        for (int off = 32; off > 0; off >>= 1) v += __shfl_xor(v, off, 64);
        mm[j] = v * invN;
    }
    int c = l;
    float wc0 = w[c], wc1 = w[64+c], wc2 = w[128+c], wc3 = w[192+c], wc4 = w[256+c];
    float mu = b[c] + mm[0]*wc0 + mm[1]*wc1 + mm[2]*wc2 + mm[3]*wc3 + mm[4]*wc4;
    float var = 0.f;
    var += (mm[5]  - mm[0]*mm[0]) * wc0*wc0;
    var += (mm[6]  - mm[0]*mm[1]) * wc0*wc1 * 2.f;
    var += (mm[7]  - mm[0]*mm[2]) * wc0*wc2 * 2.f;
    var += (mm[8]  - mm[0]*mm[3]) * wc0*wc3 * 2.f;
    var += (mm[9]  - mm[0]*mm[4]) * wc0*wc4 * 2.f;
    var += (mm[10] - mm[1]*mm[1]) * wc1*wc1;
    var += (mm[11] - mm[1]*mm[2]) * wc1*wc2 * 2.f;
    var += (mm[12] - mm[1]*mm[3]) * wc1*wc3 * 2.f;
    var += (mm[13] - mm[1]*mm[4]) * wc1*wc4 * 2.f;
    var += (mm[14] - mm[2]*mm[2]) * wc2*wc2;
    var += (mm[15] - mm[2]*mm[3]) * wc2*wc3 * 2.f;
    var += (mm[16] - mm[2]*mm[4]) * wc2*wc4 * 2.f;
    var += (mm[17] - mm[3]*mm[3]) * wc3*wc3;
    var += (mm[18] - mm[3]*mm[4]) * wc3*wc4 * 2.f;
    var += (mm[19] - mm[4]*mm[4]) * wc4*wc4;
    float scale = rsqrtf(var + EPSF) * bng[c];
    sc[c] = scale;
    sh[c] = fmaf(b[c], scale, bnb[c] - mu * scale);
}

// ---------------- fused layer-1 apply + SAGE aggregate (wave-per-node) ----------------
// Self post-BN-ReLU -> ab[:,64:128]; neighbor mean of post-BN-ReLU -> ab[:,0:64].
// Edge loop unrolled x4 with upfront index loads: cuts the dependent-load chain
// (csr -> xa row) from ~8 serial latencies to ~2 (round-4: latency-bound theory).
__global__ __launch_bounds__(256) void k_sage_l1(const float* __restrict__ xa,
                                                 const float* __restrict__ sc,
                                                 const float* __restrict__ sh,
                                                 const float* __restrict__ w,   // [5][64]
                                                 const int* __restrict__ rows,
                                                 const int* __restrict__ csr,
                                                 bf16u* __restrict__ ab) {
    int wave = threadIdx.x >> 6, lane = threadIdx.x & 63;
    int i = blockIdx.x * 4 + wave;
    int c = lane;
    float wc0 = w[c], wc1 = w[64+c], wc2 = w[128+c], wc3 = w[192+c], wc4 = w[256+c];
    float scale = sc[c], base = sh[c];
    // self
    {
        float4 p = *(const float4*)&xa[(size_t)i*8];
        float p4 = xa[(size_t)i*8 + 4];
        float t = p.x*wc0 + p.y*wc1 + p.z*wc2 + p.w*wc3 + p4*wc4;
        float v = fmaf(t, scale, base); v = v > 0.f ? v : 0.f;
        ab[(size_t)i*128 + 64 + c] = f2bf(v);
    }
    // neighbors (mean of post-BN-ReLU), 4 edges in flight
    int e0 = rows[i], e1 = rows[i+1];
    float s = 0.f;
    int e = e0;
    for (; e + 3 < e1; e += 4) {
        int s0 = csr[e], s1 = csr[e+1], s2 = csr[e+2], s3 = csr[e+3];
        float4 q0 = *(const float4*)&xa[(size_t)s0*8]; float r0 = xa[(size_t)s0*8+4];
        float4 q1 = *(const float4*)&xa[(size_t)s1*8]; float r1 = xa[(size_t)s1*8+4];
        float4 q2 = *(const float4*)&xa[(size_t)s2*8]; float r2 = xa[(size_t)s2*8+4];
        float4 q3 = *(const float4*)&xa[(size_t)s3*8]; float r3 = xa[(size_t)s3*8+4];
        float t0 = q0.x*wc0 + q0.y*wc1 + q0.z*wc2 + q0.w*wc3 + r0*wc4;
        float t1 = q1.x*wc0 + q1.y*wc1 + q1.z*wc2 + q1.w*wc3 + r1*wc4;
        float t2 = q2.x*wc0 + q2.y*wc1 + q2.z*wc2 + q2.w*wc3 + r2*wc4;
        float t3 = q3.x*wc0 + q3.y*wc1 + q3.z*wc2 + q3.w*wc3 + r3*wc4;
        float v;
        v = fmaf(t0, scale, base); s += v > 0.f ? v : 0.f;
        v = fmaf(t1, scale, base); s += v > 0.f ? v : 0.f;
        v = fmaf(t2, scale, base); s += v > 0.f ? v : 0.f;
        v = fmaf(t3, scale, base); s += v > 0.f ? v : 0.f;
    }
    for (; e < e1; ++e) {
        int sI = csr[e];
        float4 q = *(const float4*)&xa[(size_t)sI*8]; float r = xa[(size_t)sI*8+4];
        float t = q.x*wc0 + q.y*wc1 + q.z*wc2 + q.w*wc3 + r*wc4;
        float v = fmaf(t, scale, base); s += v > 0.f ? v : 0.f;
    }
    ab[(size_t)i*128 + c] = f2bf(s / fmaxf((float)(e1 - e0), 1.0f));
}

// ---------------- bf16 MFMA GEMM: C[n,m] = A[n,k]*BT[m,k]^T (+bias), bf16 out ----------------
// 128x128 tile, BK=32, 4 waves x (4x4) mfma_f32_16x16x32_bf16.
// Fused BN stats: 8-slot slabs (slot = blockIdx.y&7) cut same-address atomic
// chains 256 -> 32 deep (round-2 lesson). Consumers sum the 8 slots.
__global__ __launch_bounds__(256) void k_gemm_mfma(const bf16u* __restrict__ A,
                                                   const bf16u* __restrict__ BT,
                                                   const float* __restrict__ bias,
                                                   bf16u* __restrict__ C,
                                                   float* __restrict__ sum,
                                                   float* __restrict__ sumsq,
                                                   int K, int M) {
    __shared__ bf16u As[128][40];
    __shared__ bf16u Bs[128][40];
    int tid = threadIdx.x;
    int wave = tid >> 6, lane = tid & 63;
    int wr = (wave >> 1) * 64, wc = (wave & 1) * 64;
    int row0 = blockIdx.y * 128, col0 = blockIdx.x * 128;
    f4v acc[4][4];
#pragma unroll
    for (int i = 0; i < 4; ++i)
#pragma unroll
        for (int j = 0; j < 4; ++j) acc[i][j] = (f4v)0.0f;

    int sr = tid >> 1;             // 0..127
    int sh = (tid & 1) * 16;       // k-half within BK
    int lr = lane & 15, lq = lane >> 4;

    for (int k0 = 0; k0 < K; k0 += 32) {
        const bf16u* ap = A + (size_t)(row0 + sr) * K + k0 + sh;
        *(uint4*)&As[sr][sh]     = *(const uint4*)ap;
        *(uint4*)&As[sr][sh + 8] = *(const uint4*)(ap + 8);
        const bf16u* bp = BT + (size_t)(col0 + sr) * K + k0 + sh;
        *(uint4*)&Bs[sr][sh]     = *(const uint4*)bp;
        *(uint4*)&Bs[sr][sh + 8] = *(const uint4*)(bp + 8);
        __syncthreads();
        s8v af[4], bfr[4];
#pragma unroll
        for (int i = 0; i < 4; ++i)
            af[i] = *(const s8v*)&As[wr + i*16 + lr][lq*8];
#pragma unroll
        for (int j = 0; j < 4; ++j)
            bfr[j] = *(const s8v*)&Bs[wc + j*16 + lr][lq*8];
#pragma unroll
        for (int i = 0; i < 4; ++i)
#pragma unroll
            for (int j = 0; j < 4; ++j)
                acc[i][j] = __builtin_amdgcn_mfma_f32_16x16x32_bf16(af[i], bfr[j], acc[i][j], 0, 0, 0);
        __syncthreads();
    }

    int slot = (blockIdx.y & 7) << 9;    // 8 slabs of 512 floats
#pragma unroll
    for (int j = 0; j < 4; ++j) {
        int col = col0 + wc + j*16 + lr;
        float bv = bias ? bias[col] : 0.f;
        float s = 0.f, q = 0.f;
#pragma unroll
        for (int i = 0; i < 4; ++i) {
#pragma unroll
            for (int r = 0; r < 4; ++r) {
                float v = acc[i][j][r] + bv;
                int row = row0 + wr + i*16 + lq*4 + r;
                C[(size_t)row * M + col] = f2bf(v);
                s += v; q += v*v;
            }
        }
        if (sum) {
            s += __shfl_xor(s, 16, 64); q += __shfl_xor(q, 16, 64);
            s += __shfl_xor(s, 32, 64); q += __shfl_xor(q, 32, 64);
            if (lq == 0) { atomicAdd(&sum[slot + col], s); atomicAdd(&sumsq[slot + col], q); }
        }
    }
}

// ---------------- BN2 apply + fused GAT attention coefficients (wave-per-node) ----------------
__global__ __launch_bounds__(256) void k_bn_apply2b_attn(
        const bf16u* __restrict__ hp, const float* __restrict__ sum,
        const float* __restrict__ sumsq, const float* __restrict__ g,
        const float* __restrict__ b, const float* __restrict__ ves,
        const float* __restrict__ ved, bf16u* __restrict__ hb,
        float* __restrict__ es, float* __restrict__ ed) {
    int wave = threadIdx.x >> 6, lane = threadIdx.x & 63;
    int i = blockIdx.x * 4 + wave;
    int c = lane * 2;
    const float invN = 1.0f / (float)N_;
    float sx=0.f, sy=0.f, qx=0.f, qy=0.f;
#pragma unroll
    for (int s8 = 0; s8 < 8; ++s8) {
        float2 a = *(const float2*)&sum[s8*512 + c];
        float2 d = *(const float2*)&sumsq[s8*512 + c];
        sx += a.x; sy += a.y; qx += d.x; qy += d.y;
    }
    float2 gg = *(const float2*)&g[c];
    float2 bb = *(const float2*)&b[c];
    float mu0 = sx*invN, mu1 = sy*invN;
    float sc0 = rsqrtf(qx*invN - mu0*mu0 + EPSF)*gg.x, sh0 = bb.x - mu0*sc0;
    float sc1 = rsqrtf(qy*invN - mu1*mu1 + EPSF)*gg.y, sh1 = bb.y - mu1*sc1;
    unsigned pv = *(const unsigned*)&hp[(size_t)i*128 + c];
    float v0 = bf2f((bf16u)(pv & 0xFFFF));
    float v1 = bf2f((bf16u)(pv >> 16));
    v0 = fmaf(v0, sc0, sh0); v0 = v0 > 0.f ? v0 : 0.f;
    v1 = fmaf(v1, sc1, sh1); v1 = v1 > 0.f ? v1 : 0.f;
    unsigned ow = (unsigned)f2bf(v0) | ((unsigned)f2bf(v1) << 16);
    *(unsigned*)&hb[(size_t)i*128 + c] = ow;
    float vs[4], vd[4];
#pragma unroll
    for (int h = 0; h < 4; ++h) {
        float2 a = *(const float2*)&ves[h*128 + c];
        float2 d = *(const float2*)&ved[h*128 + c];
        vs[h] = v0*a.x + v1*a.y;
        vd[h] = v0*d.x + v1*d.y;
    }
#pragma unroll
    for (int off = 32; off > 0; off >>= 1) {
#pragma unroll
        for (int h = 0; h < 4; ++h) {
            vs[h] += __shfl_xor(vs[h], off, 64);
            vd[h] += __shfl_xor(vd[h], off, 64);
        }
    }
    if (lane == 0) {
        *(float4*)&es[i*4] = make_float4(vs[0], vs[1], vs[2], vs[3]);
        *(float4*)&ed[i*4] = make_float4(vd[0], vd[1], vd[2], vd[3]);
    }
}

// ---------------- GAT: fused max + single-pass softmax aggregation of h2b ----------------
// Pass-2 edge loop unrolled x4 (upfront csr/es/h2b loads) to hide L2 latency.
__global__ __launch_bounds__(256) void k_gat_agg2(const bf16u* __restrict__ h2b,
                                                  const float* __restrict__ es,
                                                  const float* __restrict__ ed,
                                                  const int* __restrict__ rows,
                                                  const int* __restrict__ csr,
                                                  bf16u* __restrict__ agg) {
    int wave = threadIdx.x >> 6, lane = threadIdx.x & 63;
    int i = blockIdx.x * 4 + wave;
    int c = lane * 2;
    float4 edv = *(const float4*)&ed[i*4];
    float4 sv  = *(const float4*)&es[i*4];
    int e0 = rows[i], e1 = rows[i+1];
    // ---- pass 1: exact per-node logit max (incl self-loop), lane-parallel ----
    float e, m0, m1, m2, m3;
    e = sv.x + edv.x; m0 = e >= 0.f ? e : 0.2f*e;
    e = sv.y + edv.y; m1 = e >= 0.f ? e : 0.2f*e;
    e = sv.z + edv.z; m2 = e >= 0.f ? e : 0.2f*e;
    e = sv.w + edv.w; m3 = e >= 0.f ? e : 0.2f*e;
    for (int ee = e0 + lane; ee < e1; ee += 64) {
        int s = csr[ee];
        float4 s2 = *(const float4*)&es[s*4];
        e = s2.x + edv.x; m0 = fmaxf(m0, e >= 0.f ? e : 0.2f*e);
        e = s2.y + edv.y; m1 = fmaxf(m1, e >= 0.f ? e : 0.2f*e);
        e = s2.z + edv.z; m2 = fmaxf(m2, e >= 0.f ? e : 0.2f*e);
        e = s2.w + edv.w; m3 = fmaxf(m3, e >= 0.f ? e : 0.2f*e);
    }
#pragma unroll
    for (int off = 32; off > 0; off >>= 1) {
        m0 = fmaxf(m0, __shfl_xor(m0, off, 64));
        m1 = fmaxf(m1, __shfl_xor(m1, off, 64));
        m2 = fmaxf(m2, __shfl_xor(m2, off, 64));
        m3 = fmaxf(m3, __shfl_xor(m3, off, 64));
    }
    // ---- pass 2: softmax-weighted aggregation (lanes = channels), 4 edges in flight ----
    float z0, z1, z2, z3;
    float a00, a01, a10, a11, a20, a21, a30, a31;
    {
        e = sv.x + edv.x; e = e >= 0.f ? e : 0.2f*e; z0 = __expf(e - m0);
        e = sv.y + edv.y; e = e >= 0.f ? e : 0.2f*e; z1 = __expf(e - m1);
        e = sv.z + edv.z; e = e >= 0.f ? e : 0.2f*e; z2 = __expf(e - m2);
        e = sv.w + edv.w; e = e >= 0.f ? e : 0.2f*e; z3 = __expf(e - m3);
        unsigned pv = *(const unsigned*)&h2b[(size_t)i*128 + c];
        float v0 = bf2f((bf16u)(pv & 0xFFFF)), v1 = bf2f((bf16u)(pv >> 16));
        a00 = z0*v0; a01 = z0*v1; a10 = z1*v0; a11 = z1*v1;
        a20 = z2*v0; a21 = z2*v1; a30 = z3*v0; a31 = z3*v1;
    }
    int ee = e0;
    for (; ee + 3 < e1; ee += 4) {
        int s0 = csr[ee], s1 = csr[ee+1], s2i = csr[ee+2], s3i = csr[ee+3];
        float4 q0 = *(const float4*)&es[s0*4];
        float4 q1 = *(const float4*)&es[s1*4];
        float4 q2 = *(const float4*)&es[s2i*4];
        float4 q3 = *(const float4*)&es[s3i*4];
        unsigned p0 = *(const unsigned*)&h2b[(size_t)s0*128 + c];
        unsigned p1 = *(const unsigned*)&h2b[(size_t)s1*128 + c];
        unsigned p2 = *(const unsigned*)&h2b[(size_t)s2i*128 + c];
        unsigned p3 = *(const unsigned*)&h2b[(size_t)s3i*128 + c];
        float v0, v1, ex;
        v0 = bf2f((bf16u)(p0 & 0xFFFF)); v1 = bf2f((bf16u)(p0 >> 16));
        e = q0.x + edv.x; e = e >= 0.f ? e : 0.2f*e; ex = __expf(e - m0);
        z0 += ex; a00 = fmaf(ex, v0, a00); a01 = fmaf(ex, v1, a01);
        e = q0.y + edv.y; e = e >= 0.f ? e : 0.2f*e; ex = __expf(e - m1);
        z1 += ex; a10 = fmaf(ex, v0, a10); a11 = fmaf(ex, v1, a11);
        e = q0.z + edv.z; e = e >= 0.f ? e : 0.2f*e; ex = __expf(e - m2);
        z2 += ex; a20 = fmaf(ex, v0, a20); a21 = fmaf(ex, v1, a21);
        e = q0.w + edv.w; e = e >= 0.f ? e : 0.2f*e; ex = __expf(e - m3);
        z3 += ex; a30 = fmaf(ex, v0, a30); a31 = fmaf(ex, v1, a31);
        v0 = bf2f((bf16u)(p1 & 0xFFFF)); v1 = bf2f((bf16u)(p1 >> 16));
        e = q1.x + edv.x; e = e >= 0.f ? e : 0.2f*e; ex = __expf(e - m0);
        z0 += ex; a00 = fmaf(ex, v0, a00); a01 = fmaf(ex, v1, a01);
        e = q1.y + edv.y; e = e >= 0.f ? e : 0.2f*e; ex = __expf(e - m1);
        z1 += ex; a10 = fmaf(ex, v0, a10); a11 = fmaf(ex, v1, a11);
        e = q1.z + edv.z; e = e >= 0.f ? e : 0.2f*e; ex = __expf(e - m2);
        z2 += ex; a20 = fmaf(ex, v0, a20); a21 = fmaf(ex, v1, a21);
        e = q1.w + edv.w; e = e >= 0.f ? e : 0.2f*e; ex = __expf(e - m3);
        z3 += ex; a30 = fmaf(ex, v0, a30); a31 = fmaf(ex, v1, a31);
        v0 = bf2f((bf16u)(p2 & 0xFFFF)); v1 = bf2f((bf16u)(p2 >> 16));
        e = q2.x + edv.x; e = e >= 0.f ? e : 0.2f*e; ex = __expf(e - m0);
        z0 += ex; a00 = fmaf(ex, v0, a00); a01 = fmaf(ex, v1, a01);
        e = q2.y + edv.y; e = e >= 0.f ? e : 0.2f*e; ex = __expf(e - m1);
        z1 += ex; a10 = fmaf(ex, v0, a10); a11 = fmaf(ex, v1, a11);
        e = q2.z + edv.z; e = e >= 0.f ? e : 0.2f*e; ex = __expf(e - m2);
        z2 += ex; a20 = fmaf(ex, v0, a20); a21 = fmaf(ex, v1, a21);
        e = q2.w + edv.w; e = e >= 0.f ? e : 0.2f*e; ex = __expf(e - m3);
        z3 += ex; a30 = fmaf(ex, v0, a30); a31 = fmaf(ex, v1, a31);
        v0 = bf2f((bf16u)(p3 & 0xFFFF)); v1 = bf2f((bf16u)(p3 >> 16));
        e = q3.x + edv.x; e = e >= 0.f ? e : 0.2f*e; ex = __expf(e - m0);
        z0 += ex; a00 = fmaf(ex, v0, a00); a01 = fmaf(ex, v1, a01);
        e = q3.y + edv.y; e = e >= 0.f ? e : 0.2f*e; ex = __expf(e - m1);
        z1 += ex; a10 = fmaf(ex, v0, a10); a11 = fmaf(ex, v1, a11);
        e = q3.z + edv.z; e = e >= 0.f ? e : 0.2f*e; ex = __expf(e - m2);
        z2 += ex; a20 = fmaf(ex, v0, a20); a21 = fmaf(ex, v1, a21);
        e = q3.w + edv.w; e = e >= 0.f ? e : 0.2f*e; ex = __expf(e - m3);
        z3 += ex; a30 = fmaf(ex, v0, a30); a31 = fmaf(ex, v1, a31);
    }
    for (; ee < e1; ++ee) {
        int s = csr[ee];
        float4 s2 = *(const float4*)&es[s*4];
        unsigned pv = *(const unsigned*)&h2b[(size_t)s*128 + c];
        float v0 = bf2f((bf16u)(pv & 0xFFFF)), v1 = bf2f((bf16u)(pv >> 16));
        float ex;
        e = s2.x + edv.x; e = e >= 0.f ? e : 0.2f*e; ex = __expf(e - m0);
        z0 += ex; a00 = fmaf(ex, v0, a00); a01 = fmaf(ex, v1, a01);
        e = s2.y + edv.y; e = e >= 0.f ? e : 0.2f*e; ex = __expf(e - m1);
        z1 += ex; a10 = fmaf(ex, v0, a10); a11 = fmaf(ex, v1, a11);
        e = s2.z + edv.z; e = e >= 0.f ? e : 0.2f*e; ex = __expf(e - m2);
        z2 += ex; a20 = fmaf(ex, v0, a20); a21 = fmaf(ex, v1, a21);
        e = s2.w + edv.w; e = e >= 0.f ? e : 0.2f*e; ex = __expf(e - m3);
        z3 += ex; a30 = fmaf(ex, v0, a30); a31 = fmaf(ex, v1, a31);
    }
    size_t base = (size_t)i * 512 + c;
    float r; unsigned ow;
    r = 1.f/z0; ow = (unsigned)f2bf(a00*r) | ((unsigned)f2bf(a01*r) << 16);
    *(unsigned*)&agg[base]       = ow;
    r = 1.f/z1; ow = (unsigned)f2bf(a10*r) | ((unsigned)f2bf(a11*r) << 16);
    *(unsigned*)&agg[base + 128] = ow;
    r = 1.f/z2; ow = (unsigned)f2bf(a20*r) | ((unsigned)f2bf(a21*r) << 16);
    *(unsigned*)&agg[base + 256] = ow;
    r = 1.f/z3; ow = (unsigned)f2bf(a30*r) | ((unsigned)f2bf(a31*r) << 16);
    *(unsigned*)&agg[base + 384] = ow;
}

// ---------------- layer 4: fused BN3+ReLU + GCN aggregate (wave-per-node, ushort4, x4 unroll) ----------------
__global__ __launch_bounds__(256) void k_gcn4_agg(const bf16u* __restrict__ h3b,
                                                  const float* __restrict__ dis,
                                                  const int* __restrict__ rows,
                                                  const int* __restrict__ csr,
                                                  const float* __restrict__ sum,
                                                  const float* __restrict__ sumsq,
                                                  const float* __restrict__ g,
                                                  const float* __restrict__ b,
                                                  bf16u* __restrict__ xab) {
    int wave = threadIdx.x >> 6, q = threadIdx.x & 63;
    int i = blockIdx.x * 4 + wave;
    int c = q * 4;
    const float invN = 1.0f / (float)N_;
    float4 sm = make_float4(0.f,0.f,0.f,0.f), sq = make_float4(0.f,0.f,0.f,0.f);
#pragma unroll
    for (int s8 = 0; s8 < 8; ++s8) {
        float4 a = *(const float4*)&sum[s8*512 + c];
        float4 d = *(const float4*)&sumsq[s8*512 + c];
        sm.x += a.x; sm.y += a.y; sm.z += a.z; sm.w += a.w;
        sq.x += d.x; sq.y += d.y; sq.z += d.z; sq.w += d.w;
    }
    float4 gg = *(const float4*)&g[c];
    float4 bb = *(const float4*)&b[c];
    float mu, sc0, sc1, sc2, sc3, sh0, sh1, sh2, sh3;
    mu = sm.x*invN; sc0 = rsqrtf(sq.x*invN - mu*mu + EPSF)*gg.x; sh0 = bb.x - mu*sc0;
    mu = sm.y*invN; sc1 = rsqrtf(sq.y*invN - mu*mu + EPSF)*gg.y; sh1 = bb.y - mu*sc1;
    mu = sm.z*invN; sc2 = rsqrtf(sq.z*invN - mu*mu + EPSF)*gg.z; sh2 = bb.z - mu*sc2;
    mu = sm.w*invN; sc3 = rsqrtf(sq.w*invN - mu*mu + EPSF)*gg.w; sh3 = bb.w - mu*sc3;
    float di = dis[i];
    float a0, a1, a2, a3;
    {
        ushort4 u = *(const ushort4*)(h3b + (size_t)i*256 + c);
        float v, dd = di * di;
        v = fmaf(bf2f(u.x), sc0, sh0); v = v > 0.f ? v : 0.f; a0 = v * dd;
        v = fmaf(bf2f(u.y), sc1, sh1); v = v > 0.f ? v : 0.f; a1 = v * dd;
        v = fmaf(bf2f(u.z), sc2, sh2); v = v > 0.f ? v : 0.f; a2 = v * dd;
        v = fmaf(bf2f(u.w), sc3, sh3); v = v > 0.f ? v : 0.f; a3 = v * dd;
    }
    int e0 = rows[i], e1 = rows[i+1];
    int e = e0;
    for (; e + 3 < e1; e += 4) {
        int s0 = csr[e], s1 = csr[e+1], s2i = csr[e+2], s3i = csr[e+3];
        float w0 = dis[s0] * di, w1 = dis[s1] * di, w2 = dis[s2i] * di, w3 = dis[s3i] * di;
        ushort4 u0 = *(const ushort4*)(h3b + (size_t)s0*256 + c);
        ushort4 u1 = *(const ushort4*)(h3b + (size_t)s1*256 + c);
        ushort4 u2 = *(const ushort4*)(h3b + (size_t)s2i*256 + c);
        ushort4 u3 = *(const ushort4*)(h3b + (size_t)s3i*256 + c);
        float v;
        v = fmaf(bf2f(u0.x), sc0, sh0); v = v > 0.f ? v : 0.f; a0 += v * w0;
        v = fmaf(bf2f(u0.y), sc1, sh1); v = v > 0.f ? v : 0.f; a1 += v * w0;
        v = fmaf(bf2f(u0.z), sc2, sh2); v = v > 0.f ? v : 0.f; a2 += v * w0;
        v = fmaf(bf2f(u0.w), sc3, sh3); v = v > 0.f ? v : 0.f; a3 += v * w0;
        v = fmaf(bf2f(u1.x), sc0, sh0); v = v > 0.f ? v : 0.f; a0 += v * w1;
        v = fmaf(bf2f(u1.y), sc1, sh1); v = v > 0.f ? v : 0.f; a1 += v * w1;
        v = fmaf(bf2f(u1.z), sc2, sh2); v = v > 0.f ? v : 0.f; a2 += v * w1;
        v = fmaf(bf2f(u1.w), sc3, sh3); v = v > 0.f ? v : 0.f; a3 += v * w1;
        v = fmaf(bf2f(u2.x), sc0, sh0); v = v > 0.f ? v : 0.f; a0 += v * w2;
        v = fmaf(bf2f(u2.y), sc1, sh1); v = v > 0.f ? v : 0.f; a1 += v * w2;
        v = fmaf(bf2f(u2.z), sc2, sh2); v = v > 0.f ? v : 0.f; a2 += v * w2;
        v = fmaf(bf2f(u2.w), sc3, sh3); v = v > 0.f ? v : 0.f; a3 += v * w2;
        v = fmaf(bf2f(u3.x), sc0, sh0); v = v > 0.f ? v : 0.f; a0 += v * w3;
        v = fmaf(bf2f(u3.y), sc1, sh1); v = v > 0.f ? v : 0.f; a1 += v * w3;
        v = fmaf(bf2f(u3.z), sc2, sh2); v = v > 0.f ? v : 0.f; a2 += v * w3;
        v = fmaf(bf2f(u3.w), sc3, sh3); v = v > 0.f ? v : 0.f; a3 += v * w3;
    }
    for (; e < e1; ++e) {
        int s = csr[e];
        float w = dis[s] * di;
        ushort4 u = *(const ushort4*)(h3b + (size_t)s*256 + c);
        float v;
        v = fmaf(bf2f(u.x), sc0, sh0); v = v > 0.f ? v : 0.f; a0 += v * w;
        v = fmaf(bf2f(u.y), sc1, sh1); v = v > 0.f ? v : 0.f; a1 += v * w;
        v = fmaf(bf2f(u.z), sc2, sh2); v = v > 0.f ? v : 0.f; a2 += v * w;
        v = fmaf(bf2f(u.w), sc3, sh3); v = v > 0.f ? v : 0.f; a3 += v * w;
    }
    ushort4 o;
    o.x = f2bf(a0); o.y = f2bf(a1); o.z = f2bf(a2); o.w = f2bf(a3);
    *(ushort4*)(xab + (size_t)i*256 + c) = o;
}

// ---------------- pooling with fused BN4+ReLU (+ folded fc-init blocks) ----------------
__global__ void k_pool(const bf16u* __restrict__ h4b, const int* __restrict__ gb,
                       const float* __restrict__ sum, const float* __restrict__ sumsq,
                       const float* __restrict__ g, const float* __restrict__ b,
                       const float* __restrict__ fcb,
                       float* __restrict__ pooled, float* __restrict__ out) {
    int bidx = blockIdx.x;
    int t = threadIdx.x;
    if (bidx >= 512) {                 // fc-init: out = bias (independent work)
        int i = (bidx - 512) * 256 + t;
        out[i] = fcb[i & 1023];
        return;
    }
    int gi = bidx >> 4;
    int chunk = bidx & 15;
    const float invN = 1.0f / (float)N_;
    float su0=0.f, qq0=0.f, su1=0.f, qq1=0.f;
#pragma unroll
    for (int s8 = 0; s8 < 8; ++s8) {
        su0 += sum[s8*512 + t];       qq0 += sumsq[s8*512 + t];
        su1 += sum[s8*512 + 256 + t]; qq1 += sumsq[s8*512 + 256 + t];
    }
    float mu0 = su0 * invN;
    float sc0 = rsqrtf(qq0 * invN - mu0*mu0 + EPSF) * g[t];
    float sh0 = b[t] - mu0 * sc0;
    float mu1 = su1 * invN;
    float sc1 = rsqrtf(qq1 * invN - mu1*mu1 + EPSF) * g[t+256];
    float sh1 = b[t+256] - mu1 * sc1;
    int r0g = gb[gi], r1g = gb[gi+1];
    int n = r1g - r0g;
    if (n <= 0) return;
    int per = (n + 15) >> 4;
    int r0 = r0g + chunk * per;
    int r1 = min(r0 + per, r1g);
    if (r0 >= r1) return;
    float s0=0.f, s1=0.f, m0=0.f, m1=0.f;   // post-ReLU >= 0: max init 0 valid
    for (int r = r0; r < r1; ++r) {
        float v = fmaf(bf2f(h4b[(size_t)r*512 + t]), sc0, sh0);
        v = v > 0.f ? v : 0.f;
        s0 += v; m0 = fmaxf(m0, v);
        float w = fmaf(bf2f(h4b[(size_t)r*512 + 256 + t]), sc1, sh1);
        w = w > 0.f ? w : 0.f;
        s1 += w; m1 = fmaxf(m1, w);
    }
    atomicAdd(&pooled[gi*1024 + t], s0);
    atomicAdd(&pooled[gi*1024 + 256 + t], s1);
    atomicMax((int*)&pooled[gi*1024 + 512 + t],  __float_as_int(m0));
    atomicMax((int*)&pooled[gi*1024 + 768 + t],  __float_as_int(m1));
}

// ---------------- FC (K-split, float4, atomic reduce; mean-scale folded in) ----------------
#define FCKZ 16
#define FCKC (1024 / FCKZ)   // 64

__global__ __launch_bounds__(256) void k_fc2(const float* __restrict__ pooled,
                                             const float* __restrict__ w,
                                             const int* __restrict__ gb,
                                             float* __restrict__ out) {
    __shared__ float pr[FCKC];
    int g = blockIdx.x;
    int z = blockIdx.y;
    int t = threadIdx.x;
    int k0 = z * FCKC;
    if (t < FCKC) {
        float scale = (z < 8) ? 1.0f / fmaxf((float)(gb[g+1] - gb[g]), 1.0f) : 1.0f;
        pr[t] = pooled[g * 1024 + k0 + t] * scale;   // mean part needs 1/cnt
    }
    __syncthreads();
    int m0 = t * 4;
    float ax = 0.f, ay = 0.f, az = 0.f, aw = 0.f;
#pragma unroll 8
    for (int k = 0; k < FCKC; ++k) {
        const float4 wv = *(const float4*)&w[(size_t)(k0 + k) * 1024 + m0];
        float p = pr[k];
        ax += p * wv.x; ay += p * wv.y; az += p * wv.z; aw += p * wv.w;
    }
    atomicAdd(&out[g * 1024 + m0 + 0], ax);
    atomicAdd(&out[g * 1024 + m0 + 1], ay);
    atomicAdd(&out[g * 1024 + m0 + 2], az);
    atomicAdd(&out[g * 1024 + m0 + 3], aw);
}

// ---------------- host ----------------
extern "C" void kernel_launch(void* const* d_in, const int* in_sizes, int n_in,
                              void* d_out, int out_size, void* d_ws, size_t ws_size,
                              hipStream_t stream) {
    (void)in_sizes; (void)n_in; (void)out_size; (void)ws_size;
    const float* x       = (const float*)d_in[0];
    const int*   ei      = (const int*)d_in[1];
    const int*   batch   = (const int*)d_in[2];
    const float* gcn1_w  = (const float*)d_in[3];
    const float* gcn1_b  = (const float*)d_in[4];
    const float* sage_wl = (const float*)d_in[5];
    const float* sage_wr = (const float*)d_in[6];
    const float* sage_b  = (const float*)d_in[7];
    const float* gat_w   = (const float*)d_in[8];
    const float* gat_as  = (const float*)d_in[9];
    const float* gat_ad  = (const float*)d_in[10];
    const float* gat_b   = (const float*)d_in[11];
    const float* gcn4_w  = (const float*)d_in[12];
    const float* gcn4_b  = (const float*)d_in[13];
    const float* bn1_g   = (const float*)d_in[14];
    const float* bn1_b   = (const float*)d_in[15];
    const float* bn2_g   = (const float*)d_in[16];
    const float* bn2_b   = (const float*)d_in[17];
    const float* bn3_g   = (const float*)d_in[18];
    const float* bn3_b   = (const float*)d_in[19];
    const float* bn4_g   = (const float*)d_in[20];
    const float* bn4_b   = (const float*)d_in[21];
    const float* fc_w    = (const float*)d_in[22];
    const float* fc_b    = (const float*)d_in[23];
    float* out = (float*)d_out;

    char* w8 = (char*)d_ws;
    int*   indeg  = (int*)(w8 + OFF_INDEG);
    int*   rows   = (int*)(w8 + OFF_ROWS);
    int*   cursor = (int*)(w8 + OFF_CURSOR);
    int*   csr    = (int*)(w8 + OFF_CSR);
    float* dis    = (float*)(w8 + OFF_DIS);
    float* es     = (float*)(w8 + OFF_ES);
    float* ed     = (float*)(w8 + OFF_ED);
    float* bns    = (float*)(w8 + OFF_BNS);   // [4][8][512] slabs per layer
    float* bnq    = (float*)(w8 + OFF_BNQ);
    int*   gb     = (int*)(w8 + OFF_GB);
    int*   cnt    = (int*)(w8 + OFF_CNT);
    float* pooled = (float*)(w8 + OFF_POOL);
    float* part   = (float*)(w8 + OFF_PART);
    float* bn1sc  = (float*)(w8 + OFF_BN1C);
    float* bn1sh  = (float*)(w8 + OFF_BN1C + 256);
    float* xa     = (float*)(w8 + OFF_XA);
    bf16u* ab     = (bf16u*)(w8 + OFF_AB);
    bf16u* h2p    = (bf16u*)(w8 + OFF_H2P);
    bf16u* h2b    = (bf16u*)(w8 + OFF_H2B);
    bf16u* h3b    = (bf16u*)(w8 + OFF_H3B);
    bf16u* agg    = (bf16u*)(w8 + OFF_AGG);
    bf16u* xa4b   = (bf16u*)(w8 + OFF_XA4B);
    bf16u* wT1    = (bf16u*)(w8 + OFF_WT1);
    bf16u* wT2    = (bf16u*)(w8 + OFF_WT2);
    bf16u* wT3    = (bf16u*)(w8 + OFF_WT3);
    bf16u* h4b    = (bf16u*)(w8 + OFF_H4B);
    float* ves    = (float*)(w8 + OFF_VES);
    float* ved    = (float*)(w8 + OFF_VED);

    const int* srcE = ei;        // edge_index[0,:]
    const int* dstE = ei + E_;   // edge_index[1,:]

    // ---- setup: ONE memset, then fused setup kernel (weights+gbounds+ves/ved+indeg) ----
    hipMemsetAsync(w8, 0, OFF_MSET, stream);
    k_wconv_all<<<1605, 256, 0, stream>>>(gat_w, gcn4_w, sage_wl, sage_wr, batch,
                                          gat_as, gat_ad, dstE,
                                          wT1, wT2, wT3, gb, ves, ved, indeg);
    k_scan<<<1, 1024, 0, stream>>>(indeg, rows, cursor, dis);
    k_fill<<<E_/256, 256, 0, stream>>>(srcE, dstE, cursor, csr);

    // ---- layer 1+2 front: GCN agg -> xa; analytic BN1 (merged stats+finale) ----
    k_gcn1x<<<N_/4, 256, 0, stream>>>(x, dis, rows, csr, xa);
    k_xstats<<<64, 256, 0, stream>>>(xa, part, cnt, gcn1_w, gcn1_b, bn1_g, bn1_b,
                                     bn1sc, bn1sh);
    k_sage_l1<<<N_/4, 256, 0, stream>>>(xa, bn1sc, bn1sh, gcn1_w, rows, csr, ab);

    // ---- layer 2: SAGE 64->128 via single MFMA GEMM (stats fused in epilogue) ----
    {
        dim3 grid(1, N_/128);
        k_gemm_mfma<<<grid, 256, 0, stream>>>(ab, wT3, sage_b, h2p,
                                              bns + 4096, bnq + 4096, 128, 128);
    }
    k_bn_apply2b_attn<<<N_/4, 256, 0, stream>>>(h2p, bns + 4096, bnq + 4096, bn2_g, bn2_b,
                                                ves, ved, h2b, es, ed);

    // ---- layer 3: GAT — aggregate h2b per head (fused max+softmax), then 512->256 GEMM ----
    k_gat_agg2<<<N_/4, 256, 0, stream>>>(h2b, es, ed, rows, csr, agg);
    {
        dim3 grid(256/128, N_/128);
        k_gemm_mfma<<<grid, 256, 0, stream>>>(agg, wT1, gat_b, h3b,
                                              bns + 8192, bnq + 8192, 512, 256);
    }

    // ---- layer 4: fused BN3+ReLU+aggregate, MFMA GEMM 256->512 (stats fused) ----
    k_gcn4_agg<<<N_/4, 256, 0, stream>>>(h3b, dis, rows, csr, bns + 8192, bnq + 8192,
                                         bn3_g, bn3_b, xa4b);
    {
        dim3 grid(512/128, N_/128);
        k_gemm_mfma<<<grid, 256, 0, stream>>>(xa4b, wT2, gcn4_b, h4b,
                                              bns + 12288, bnq + 12288, 256, 512);
    }

    // ---- pooling with fused BN4+ReLU (+fc-init blocks) -> [32,1024] ----
    k_pool<<<640, 256, 0, stream>>>(h4b, gb, bns + 12288, bnq + 12288, bn4_g, bn4_b,
                                    fc_b, pooled, out);

    // ---- FC 1024->1024 ----
    {
        dim3 grid(G_, FCKZ);
        k_fc2<<<grid, 256, 0, stream>>>(pooled, fc_w, gb, out);
    }
}

// Round 5
// 283.878 us; speedup vs baseline: 1.4325x; 1.0137x over previous
//
#include <hip/hip_runtime.h>

#define N_ 16384
#define E_ 131072
#define G_ 32
#define EPSF 1e-5f

typedef unsigned short bf16u;
typedef __attribute__((ext_vector_type(8))) short s8v;   // 8 bf16 (4 VGPRs)
typedef __attribute__((ext_vector_type(4))) float f4v;   // 4 fp32 acc

__device__ __forceinline__ bf16u f2bf(float v) {
    union { float f; unsigned u; } x; x.f = v;
    unsigned r = x.u + 0x7FFF + ((x.u >> 16) & 1);   // RNE
    return (bf16u)(r >> 16);
}
__device__ __forceinline__ float bf2f(bf16u u) {
    union { unsigned u; float f; } x; x.u = (unsigned)u << 16;
    return x.f;
}

// ---------------- workspace layout (bytes) ----------------
// Zeroed region [0, OFF_MSET) — ONLY buffers that need zero-init (atomic targets).
// rows/cursor/csr/dis/es/ed/part/bn1c are fully written before read -> unzeroed.
static const size_t OFF_INDEG = 0;          // int[N]            64 KB
static const size_t OFF_BNS   = 65536;      // float[4][8][512]  64 KB stats slabs
static const size_t OFF_BNQ   = 131072;     // float[4][8][512]  64 KB
static const size_t OFF_POOL  = 196608;     // float[32*1024]   128 KB
static const size_t OFF_GB    = 327680;     // int[33]
static const size_t OFF_CNT   = 327816;     // int (xstats last-block counter)
static const size_t OFF_MSET  = 327936;     // (memset end marker, ~320 KB)
// Unzeroed:
static const size_t OFF_ROWS  = 327936;     // int[N+1]
static const size_t OFF_CURSOR= 393728;     // int[N]
static const size_t OFF_CSR   = 459264;     // int[E]
static const size_t OFF_DIS   = 983552;     // float[N]
static const size_t OFF_ES    = 1049088;    // float[4N]
static const size_t OFF_ED    = 1311232;    // float[4N]
static const size_t OFF_PART  = 1573376;    // float[64][20] xa-moment partials
static const size_t OFF_BN1C  = 1578496;    // float[64] scale + float[64] base
static const size_t OFF_XA    = 1786624;    // float[8N]  512 KB (padded [N][8] GCN1 agg)
static const size_t OFF_AB    = 5980928;    // bf16[128N]   4 MB ([agg|h1] concat)
static const size_t OFF_H2P   = 10175232;   // bf16[128N]   4 MB (pre-BN)
static const size_t OFF_H2B   = 14369536;   // bf16[128N]   4 MB (post-BN)
static const size_t OFF_H3B   = 18563840;   // bf16[256N]   8 MB
static const size_t OFF_AGG   = 35328768;   // bf16[512N]  16 MB (GAT head-agg of h2b)
static const size_t OFF_XA4B  = 52105984;   // bf16[256N]   8 MB
static const size_t OFF_WT1   = 68883200;   // bf16[256*512] (0.25*gat_w stacked-head ^T)
static const size_t OFF_WT2   = 69145344;   // bf16[512*256]
static const size_t OFF_WT3   = 69407488;   // bf16[128*128]
static const size_t OFF_H4B   = 69440256;   // bf16[512N] 16 MB
static const size_t OFF_VES   = 86479616;   // float[4][128]  W_h·a_src_h
static const size_t OFF_VED   = 86481664;   // float[4][128]  W_h·a_dst_h
// total ≈ 86.5 MB

// scan + fused dis + cursor copy: shfl wave-scan, 2 barriers (was 20 — round-5)
__global__ __launch_bounds__(1024) void k_scan(const int* __restrict__ indeg,
                                               int* __restrict__ rows,
                                               int* __restrict__ cursor,
                                               float* __restrict__ dis) {
    __shared__ int wtot[16];
    int t = threadIdx.x;
    int lane = t & 63, wave = t >> 6;
    int base = t * 16;
    int local[16];
    int s = 0;
#pragma unroll
    for (int i = 0; i < 16; ++i) {
        local[i] = indeg[base + i]; s += local[i];
        dis[base + i] = rsqrtf((float)local[i] + 1.0f);
    }
    int own = s;
#pragma unroll
    for (int off = 1; off < 64; off <<= 1) {     // inclusive wave scan
        int v = __shfl_up(s, off, 64);
        if (lane >= off) s += v;
    }
    if (lane == 63) wtot[wave] = s;
    __syncthreads();
    if (wave == 0) {
        int v = (lane < 16) ? wtot[lane] : 0;
#pragma unroll
        for (int off = 1; off < 16; off <<= 1) {
            int u = __shfl_up(v, off, 64);
            if (lane >= off) v += u;
        }
        if (lane < 16) wtot[lane] = v;           // inclusive scan of wave totals
    }
    __syncthreads();
    int run = s - own + (wave > 0 ? wtot[wave - 1] : 0);   // exclusive prefix
#pragma unroll
    for (int i = 0; i < 16; ++i) {
        rows[base + i] = run; cursor[base + i] = run; run += local[i];
    }
    if (t == 1023) rows[N_] = run;
}

__global__ void k_fill(const int* __restrict__ src, const int* __restrict__ dst,
                       int* __restrict__ cursor, int* __restrict__ csr) {
    int e = blockIdx.x * 256 + threadIdx.x;
    if (e < E_) {
        int p = atomicAdd(&cursor[dst[e]], 1);
        csr[p] = src[e];
    }
}

// ------- fused setup: weight transpose/convert + gbounds + v_es/v_ed + indeg -------
// Round-5: transpose segments are READ-coalesced, scatter-WRITE (targets <=256 KB,
// L2-resident; loads stall, stores don't). Old form had 64 lines/wave-load.
__global__ void k_wconv_all(const float* __restrict__ gat_w,
                            const float* __restrict__ gcn4_w,
                            const float* __restrict__ wl, const float* __restrict__ wr,
                            const int* __restrict__ batch,
                            const float* __restrict__ gat_as,
                            const float* __restrict__ gat_ad,
                            const int* __restrict__ dstE,
                            bf16u* __restrict__ wT1, bf16u* __restrict__ wT2,
                            bf16u* __restrict__ wT3, int* __restrict__ gb,
                            float* __restrict__ ves, float* __restrict__ ved,
                            int* __restrict__ indeg) {
    int idx = blockIdx.x * 256 + threadIdx.x;
    if (idx < 131072) {          // gat_w [128][1024]: wT1[c][h*128+k] = 0.25*gat_w[k][h*256+c]
        int k = idx >> 10, col = idx & 1023;
        int h = col >> 8, c = col & 255;
        wT1[(size_t)c * 512 + h * 128 + k] = f2bf(0.25f * gat_w[idx]);
    } else if (idx < 262144) {   // gcn4_w [256][512] -> wT2[m][k]
        int j = idx - 131072;
        int k = j >> 9, m = j & 511;
        wT2[m * 256 + k] = f2bf(gcn4_w[j]);
    } else if (idx < 270336) {   // wl [64][128] -> wT3[m][k]
        int j = idx - 262144;
        int k = j >> 7, m = j & 127;
        wT3[m * 128 + k] = f2bf(wl[j]);
    } else if (idx < 278528) {   // wr [64][128] -> wT3[m][64+k]
        int j = idx - 270336;
        int k = j >> 7, m = j & 127;
        wT3[m * 128 + 64 + k] = f2bf(wr[j]);
    } else if (idx < 278592) {   // graph-batch bounds
        int g = idx - 278528;
        if (g > G_) return;
        if (g == G_) { gb[G_] = N_; return; }
        int lo = 0, hi = N_;
        while (lo < hi) { int mid = (lo + hi) >> 1; if (batch[mid] < g) lo = mid + 1; else hi = mid; }
        gb[g] = lo;
    } else if (idx < 279104) {   // v_es (4 heads x 128 k)
        int j = idx - 278592;
        int h = j >> 7, k = j & 127;
        float s = 0.f;
        for (int c = 0; c < 256; ++c)
            s += gat_w[(size_t)k * 1024 + h*256 + c] * gat_as[h*256 + c];
        ves[j] = s;
    } else if (idx < 279616) {   // v_ed
        int j = idx - 279104;
        int h = j >> 7, k = j & 127;
        float s = 0.f;
        for (int c = 0; c < 256; ++c)
            s += gat_w[(size_t)k * 1024 + h*256 + c] * gat_ad[h*256 + c];
        ved[j] = s;
    } else if (idx < 410688) {   // indeg
        int e = idx - 279616;
        atomicAdd(&indeg[dstE[e]], 1);
    }
}

// ---------------- layer 1: GCN aggregate only -> xa [N][8] fp32 (512 KB) ----------------
__global__ __launch_bounds__(256) void k_gcn1x(const float* __restrict__ x,
                                               const float* __restrict__ dis,
                                               const int* __restrict__ rows,
                                               const int* __restrict__ csr,
                                               float* __restrict__ xa) {
    int wave = threadIdx.x >> 6, lane = threadIdx.x & 63;
    int i = blockIdx.x * 4 + wave;
    float a0=0,a1=0,a2=0,a3=0,a4=0;
    int e0 = rows[i], e1 = rows[i+1];
    for (int e = e0 + lane; e < e1; e += 64) {
        int s = csr[e];
        float wt = dis[s];
        a0 += x[s*5+0]*wt; a1 += x[s*5+1]*wt; a2 += x[s*5+2]*wt;
        a3 += x[s*5+3]*wt; a4 += x[s*5+4]*wt;
    }
#pragma unroll
    for (int off = 32; off > 0; off >>= 1) {
        a0 += __shfl_xor(a0, off, 64); a1 += __shfl_xor(a1, off, 64);
        a2 += __shfl_xor(a2, off, 64); a3 += __shfl_xor(a3, off, 64);
        a4 += __shfl_xor(a4, off, 64);
    }
    float di = dis[i];
    float v0 = di*(a0 + di*x[i*5+0]);
    float v1 = di*(a1 + di*x[i*5+1]);
    float v2 = di*(a2 + di*x[i*5+2]);
    float v3 = di*(a3 + di*x[i*5+3]);
    float v4 = di*(a4 + di*x[i*5+4]);
    if (lane < 5) {
        float v = lane == 0 ? v0 : lane == 1 ? v1 : lane == 2 ? v2 : lane == 3 ? v3 : v4;
        xa[(size_t)i*8 + lane] = v;
    }
}

// ---------------- xa moments + analytic BN1 coeffs, single kernel ----------------
// Stage A: per-block reduce -> partial[64][20] (no global atomic chains, round-2 lesson).
// Stage B: last-block-done (device counter + threadfence) runs the 1-wave finale.
__global__ __launch_bounds__(256) void k_xstats(const float* __restrict__ xa,
                                                float* __restrict__ partial,
                                                int* __restrict__ cnt,
                                                const float* __restrict__ w,   // [5][64]
                                                const float* __restrict__ b,
                                                const float* __restrict__ bng,
                                                const float* __restrict__ bnb,
                                                float* __restrict__ sc,
                                                float* __restrict__ sh) {
    __shared__ float wsum[80];   // 4 waves x 20
    __shared__ int lastFlag;
    int t = threadIdx.x;
    int tid = blockIdx.x * 256 + t;    // grid 64 -> exactly N threads
    float v0 = xa[(size_t)tid*8+0], v1 = xa[(size_t)tid*8+1], v2 = xa[(size_t)tid*8+2];
    float v3 = xa[(size_t)tid*8+3], v4 = xa[(size_t)tid*8+4];
    float m[20];
    m[0]=v0; m[1]=v1; m[2]=v2; m[3]=v3; m[4]=v4;
    m[5]=v0*v0;  m[6]=v0*v1;  m[7]=v0*v2;  m[8]=v0*v3;  m[9]=v0*v4;
    m[10]=v1*v1; m[11]=v1*v2; m[12]=v1*v3; m[13]=v1*v4;
    m[14]=v2*v2; m[15]=v2*v3; m[16]=v2*v4;
    m[17]=v3*v3; m[18]=v3*v4;
    m[19]=v4*v4;
#pragma unroll
    for (int off = 32; off > 0; off >>= 1)
#pragma unroll
        for (int j = 0; j < 20; ++j) m[j] += __shfl_xor(m[j], off, 64);
    int wave = t >> 6, lane = t & 63;
    if (lane == 0)
#pragma unroll
        for (int j = 0; j < 20; ++j) wsum[wave*20 + j] = m[j];
    __syncthreads();
    if (t < 20) {
        partial[blockIdx.x * 20 + t] = wsum[t] + wsum[20+t] + wsum[40+t] + wsum[60+t];
        __threadfence();           // make this block's partial device-visible
    }
    __syncthreads();
    if (t == 0) lastFlag = (atomicAdd(cnt, 1) == 63);
    __syncthreads();
    if (!lastFlag || t >= 64) return;
    // ---- finale: 1 wave merges 64 partials ----
    int l = t;
    const float invN = 1.0f / (float)N_;
    float mm[20];
#pragma unroll
    for (int j = 0; j < 20; ++j) {
        float v = partial[l*20 + j];
#pragma unroll
        for (int off = 32; off > 0; off >>= 1) v += __shfl_xor(v, off, 64);
        mm[j] = v * invN;
    }
    int c = l;
    float wc0 = w[c], wc1 = w[64+c], wc2 = w[128+c], wc3 = w[192+c], wc4 = w[256+c];
    float mu = b[c] + mm[0]*wc0 + mm[1]*wc1 + mm[2]*wc2 + mm[3]*wc3 + mm[4]*wc4;
    float var = 0.f;
    var += (mm[5]  - mm[0]*mm[0]) * wc0*wc0;
    var += (mm[6]  - mm[0]*mm[1]) * wc0*wc1 * 2.f;
    var += (mm[7]  - mm[0]*mm[2]) * wc0*wc2 * 2.f;
    var += (mm[8]  - mm[0]*mm[3]) * wc0*wc3 * 2.f;
    var += (mm[9]  - mm[0]*mm[4]) * wc0*wc4 * 2.f;
    var += (mm[10] - mm[1]*mm[1]) * wc1*wc1;
    var += (mm[11] - mm[1]*mm[2]) * wc1*wc2 * 2.f;
    var += (mm[12] - mm[1]*mm[3]) * wc1*wc3 * 2.f;
    var += (mm[13] - mm[1]*mm[4]) * wc1*wc4 * 2.f;
    var += (mm[14] - mm[2]*mm[2]) * wc2*wc2;
    var += (mm[15] - mm[2]*mm[3]) * wc2*wc3 * 2.f;
    var += (mm[16] - mm[2]*mm[4]) * wc2*wc4 * 2.f;
    var += (mm[17] - mm[3]*mm[3]) * wc3*wc3;
    var += (mm[18] - mm[3]*mm[4]) * wc3*wc4 * 2.f;
    var += (mm[19] - mm[4]*mm[4]) * wc4*wc4;
    float scale = rsqrtf(var + EPSF) * bng[c];
    sc[c] = scale;
    sh[c] = fmaf(b[c], scale, bnb[c] - mu * scale);
}

// ---------------- fused layer-1 apply + SAGE aggregate (wave-per-node, x4 unroll) ----------------
__global__ __launch_bounds__(256) void k_sage_l1(const float* __restrict__ xa,
                                                 const float* __restrict__ sc,
                                                 const float* __restrict__ sh,
                                                 const float* __restrict__ w,   // [5][64]
                                                 const int* __restrict__ rows,
                                                 const int* __restrict__ csr,
                                                 bf16u* __restrict__ ab) {
    int wave = threadIdx.x >> 6, lane = threadIdx.x & 63;
    int i = blockIdx.x * 4 + wave;
    int c = lane;
    float wc0 = w[c], wc1 = w[64+c], wc2 = w[128+c], wc3 = w[192+c], wc4 = w[256+c];
    float scale = sc[c], base = sh[c];
    // self
    {
        float4 p = *(const float4*)&xa[(size_t)i*8];
        float p4 = xa[(size_t)i*8 + 4];
        float t = p.x*wc0 + p.y*wc1 + p.z*wc2 + p.w*wc3 + p4*wc4;
        float v = fmaf(t, scale, base); v = v > 0.f ? v : 0.f;
        ab[(size_t)i*128 + 64 + c] = f2bf(v);
    }
    // neighbors (mean of post-BN-ReLU), 4 edges in flight
    int e0 = rows[i], e1 = rows[i+1];
    float s = 0.f;
    int e = e0;
    for (; e + 3 < e1; e += 4) {
        int s0 = csr[e], s1 = csr[e+1], s2 = csr[e+2], s3 = csr[e+3];
        float4 q0 = *(const float4*)&xa[(size_t)s0*8]; float r0 = xa[(size_t)s0*8+4];
        float4 q1 = *(const float4*)&xa[(size_t)s1*8]; float r1 = xa[(size_t)s1*8+4];
        float4 q2 = *(const float4*)&xa[(size_t)s2*8]; float r2 = xa[(size_t)s2*8+4];
        float4 q3 = *(const float4*)&xa[(size_t)s3*8]; float r3 = xa[(size_t)s3*8+4];
        float t0 = q0.x*wc0 + q0.y*wc1 + q0.z*wc2 + q0.w*wc3 + r0*wc4;
        float t1 = q1.x*wc0 + q1.y*wc1 + q1.z*wc2 + q1.w*wc3 + r1*wc4;
        float t2 = q2.x*wc0 + q2.y*wc1 + q2.z*wc2 + q2.w*wc3 + r2*wc4;
        float t3 = q3.x*wc0 + q3.y*wc1 + q3.z*wc2 + q3.w*wc3 + r3*wc4;
        float v;
        v = fmaf(t0, scale, base); s += v > 0.f ? v : 0.f;
        v = fmaf(t1, scale, base); s += v > 0.f ? v : 0.f;
        v = fmaf(t2, scale, base); s += v > 0.f ? v : 0.f;
        v = fmaf(t3, scale, base); s += v > 0.f ? v : 0.f;
    }
    for (; e < e1; ++e) {
        int sI = csr[e];
        float4 q = *(const float4*)&xa[(size_t)sI*8]; float r = xa[(size_t)sI*8+4];
        float t = q.x*wc0 + q.y*wc1 + q.z*wc2 + q.w*wc3 + r*wc4;
        float v = fmaf(t, scale, base); s += v > 0.f ? v : 0.f;
    }
    ab[(size_t)i*128 + c] = f2bf(s / fmaxf((float)(e1 - e0), 1.0f));
}

// ---------------- bf16 MFMA GEMM: C[n,m] = A[n,k]*BT[m,k]^T (+bias), bf16 out ----------------
// 128x128 tile, BK=32, 4 waves x (4x4) mfma_f32_16x16x32_bf16.
// Fused BN stats: 8-slot slabs (slot = blockIdx.y&7) cut same-address atomic
// chains 256 -> 32 deep (round-2 lesson). Consumers sum the 8 slots.
__global__ __launch_bounds__(256) void k_gemm_mfma(const bf16u* __restrict__ A,
                                                   const bf16u* __restrict__ BT,
                                                   const float* __restrict__ bias,
                                                   bf16u* __restrict__ C,
                                                   float* __restrict__ sum,
                                                   float* __restrict__ sumsq,
                                                   int K, int M) {
    __shared__ bf16u As[128][40];
    __shared__ bf16u Bs[128][40];
    int tid = threadIdx.x;
    int wave = tid >> 6, lane = tid & 63;
    int wr = (wave >> 1) * 64, wc = (wave & 1) * 64;
    int row0 = blockIdx.y * 128, col0 = blockIdx.x * 128;
    f4v acc[4][4];
#pragma unroll
    for (int i = 0; i < 4; ++i)
#pragma unroll
        for (int j = 0; j < 4; ++j) acc[i][j] = (f4v)0.0f;

    int sr = tid >> 1;             // 0..127
    int sh = (tid & 1) * 16;       // k-half within BK
    int lr = lane & 15, lq = lane >> 4;

    for (int k0 = 0; k0 < K; k0 += 32) {
        const bf16u* ap = A + (size_t)(row0 + sr) * K + k0 + sh;
        *(uint4*)&As[sr][sh]     = *(const uint4*)ap;
        *(uint4*)&As[sr][sh + 8] = *(const uint4*)(ap + 8);
        const bf16u* bp = BT + (size_t)(col0 + sr) * K + k0 + sh;
        *(uint4*)&Bs[sr][sh]     = *(const uint4*)bp;
        *(uint4*)&Bs[sr][sh + 8] = *(const uint4*)(bp + 8);
        __syncthreads();
        s8v af[4], bfr[4];
#pragma unroll
        for (int i = 0; i < 4; ++i)
            af[i] = *(const s8v*)&As[wr + i*16 + lr][lq*8];
#pragma unroll
        for (int j = 0; j < 4; ++j)
            bfr[j] = *(const s8v*)&Bs[wc + j*16 + lr][lq*8];
#pragma unroll
        for (int i = 0; i < 4; ++i)
#pragma unroll
            for (int j = 0; j < 4; ++j)
                acc[i][j] = __builtin_amdgcn_mfma_f32_16x16x32_bf16(af[i], bfr[j], acc[i][j], 0, 0, 0);
        __syncthreads();
    }

    int slot = (blockIdx.y & 7) << 9;    // 8 slabs of 512 floats
#pragma unroll
    for (int j = 0; j < 4; ++j) {
        int col = col0 + wc + j*16 + lr;
        float bv = bias ? bias[col] : 0.f;
        float s = 0.f, q = 0.f;
#pragma unroll
        for (int i = 0; i < 4; ++i) {
#pragma unroll
            for (int r = 0; r < 4; ++r) {
                float v = acc[i][j][r] + bv;
                int row = row0 + wr + i*16 + lq*4 + r;
                C[(size_t)row * M + col] = f2bf(v);
                s += v; q += v*v;
            }
        }
        if (sum) {
            s += __shfl_xor(s, 16, 64); q += __shfl_xor(q, 16, 64);
            s += __shfl_xor(s, 32, 64); q += __shfl_xor(q, 32, 64);
            if (lq == 0) { atomicAdd(&sum[slot + col], s); atomicAdd(&sumsq[slot + col], q); }
        }
    }
}

// ---------------- BN2 apply + fused GAT attention coefficients (wave-per-node) ----------------
__global__ __launch_bounds__(256) void k_bn_apply2b_attn(
        const bf16u* __restrict__ hp, const float* __restrict__ sum,
        const float* __restrict__ sumsq, const float* __restrict__ g,
        const float* __restrict__ b, const float* __restrict__ ves,
        const float* __restrict__ ved, bf16u* __restrict__ hb,
        float* __restrict__ es, float* __restrict__ ed) {
    int wave = threadIdx.x >> 6, lane = threadIdx.x & 63;
    int i = blockIdx.x * 4 + wave;
    int c = lane * 2;
    const float invN = 1.0f / (float)N_;
    float sx=0.f, sy=0.f, qx=0.f, qy=0.f;
#pragma unroll
    for (int s8 = 0; s8 < 8; ++s8) {
        float2 a = *(const float2*)&sum[s8*512 + c];
        float2 d = *(const float2*)&sumsq[s8*512 + c];
        sx += a.x; sy += a.y; qx += d.x; qy += d.y;
    }
    float2 gg = *(const float2*)&g[c];
    float2 bb = *(const float2*)&b[c];
    float mu0 = sx*invN, mu1 = sy*invN;
    float sc0 = rsqrtf(qx*invN - mu0*mu0 + EPSF)*gg.x, sh0 = bb.x - mu0*sc0;
    float sc1 = rsqrtf(qy*invN - mu1*mu1 + EPSF)*gg.y, sh1 = bb.y - mu1*sc1;
    unsigned pv = *(const unsigned*)&hp[(size_t)i*128 + c];
    float v0 = bf2f((bf16u)(pv & 0xFFFF));
    float v1 = bf2f((bf16u)(pv >> 16));
    v0 = fmaf(v0, sc0, sh0); v0 = v0 > 0.f ? v0 : 0.f;
    v1 = fmaf(v1, sc1, sh1); v1 = v1 > 0.f ? v1 : 0.f;
    unsigned ow = (unsigned)f2bf(v0) | ((unsigned)f2bf(v1) << 16);
    *(unsigned*)&hb[(size_t)i*128 + c] = ow;
    float vs[4], vd[4];
#pragma unroll
    for (int h = 0; h < 4; ++h) {
        float2 a = *(const float2*)&ves[h*128 + c];
        float2 d = *(const float2*)&ved[h*128 + c];
        vs[h] = v0*a.x + v1*a.y;
        vd[h] = v0*d.x + v1*d.y;
    }
#pragma unroll
    for (int off = 32; off > 0; off >>= 1) {
#pragma unroll
        for (int h = 0; h < 4; ++h) {
            vs[h] += __shfl_xor(vs[h], off, 64);
            vd[h] += __shfl_xor(vd[h], off, 64);
        }
    }
    if (lane == 0) {
        *(float4*)&es[i*4] = make_float4(vs[0], vs[1], vs[2], vs[3]);
        *(float4*)&ed[i*4] = make_float4(vd[0], vd[1], vd[2], vd[3]);
    }
}

// ---------------- GAT: single-pass softmax aggregation, SELF-LOGIT shift ----------------
// Round-5: softmax is shift-invariant; shifting by the self-logit (always present,
// zero extra passes) replaces the exact-max pass. arg clamped at 80 for overflow
// safety (exp(80)=5.5e34, 8 edges * |v|~5 stays < fp32 max).
__global__ __launch_bounds__(256) void k_gat_agg2(const bf16u* __restrict__ h2b,
                                                  const float* __restrict__ es,
                                                  const float* __restrict__ ed,
                                                  const int* __restrict__ rows,
                                                  const int* __restrict__ csr,
                                                  bf16u* __restrict__ agg) {
    int wave = threadIdx.x >> 6, lane = threadIdx.x & 63;
    int i = blockIdx.x * 4 + wave;
    int c = lane * 2;
    float4 edv = *(const float4*)&ed[i*4];
    float4 sv  = *(const float4*)&es[i*4];
    int e0 = rows[i], e1 = rows[i+1];
    float e, m0, m1, m2, m3;                 // shifts = self logits
    e = sv.x + edv.x; m0 = e >= 0.f ? e : 0.2f*e;
    e = sv.y + edv.y; m1 = e >= 0.f ? e : 0.2f*e;
    e = sv.z + edv.z; m2 = e >= 0.f ? e : 0.2f*e;
    e = sv.w + edv.w; m3 = e >= 0.f ? e : 0.2f*e;
    float z0, z1, z2, z3;
    float a00, a01, a10, a11, a20, a21, a30, a31;
    {
        z0 = 1.f; z1 = 1.f; z2 = 1.f; z3 = 1.f;     // exp(self - self)
        unsigned pv = *(const unsigned*)&h2b[(size_t)i*128 + c];
        float v0 = bf2f((bf16u)(pv & 0xFFFF)), v1 = bf2f((bf16u)(pv >> 16));
        a00 = v0; a01 = v1; a10 = v0; a11 = v1;
        a20 = v0; a21 = v1; a30 = v0; a31 = v1;
    }
#define GEXP(Q, EDC, M) __expf(fminf(((Q) + (EDC) >= 0.f ? (Q) + (EDC) : 0.2f*((Q) + (EDC))) - (M), 80.f))
    int ee = e0;
    for (; ee + 3 < e1; ee += 4) {
        int s0 = csr[ee], s1 = csr[ee+1], s2i = csr[ee+2], s3i = csr[ee+3];
        float4 q0 = *(const float4*)&es[s0*4];
        float4 q1 = *(const float4*)&es[s1*4];
        float4 q2 = *(const float4*)&es[s2i*4];
        float4 q3 = *(const float4*)&es[s3i*4];
        unsigned p0 = *(const unsigned*)&h2b[(size_t)s0*128 + c];
        unsigned p1 = *(const unsigned*)&h2b[(size_t)s1*128 + c];
        unsigned p2 = *(const unsigned*)&h2b[(size_t)s2i*128 + c];
        unsigned p3 = *(const unsigned*)&h2b[(size_t)s3i*128 + c];
        float v0, v1, ex;
        v0 = bf2f((bf16u)(p0 & 0xFFFF)); v1 = bf2f((bf16u)(p0 >> 16));
        ex = GEXP(q0.x, edv.x, m0); z0 += ex; a00 = fmaf(ex, v0, a00); a01 = fmaf(ex, v1, a01);
        ex = GEXP(q0.y, edv.y, m1); z1 += ex; a10 = fmaf(ex, v0, a10); a11 = fmaf(ex, v1, a11);
        ex = GEXP(q0.z, edv.z, m2); z2 += ex; a20 = fmaf(ex, v0, a20); a21 = fmaf(ex, v1, a21);
        ex = GEXP(q0.w, edv.w, m3); z3 += ex; a30 = fmaf(ex, v0, a30); a31 = fmaf(ex, v1, a31);
        v0 = bf2f((bf16u)(p1 & 0xFFFF)); v1 = bf2f((bf16u)(p1 >> 16));
        ex = GEXP(q1.x, edv.x, m0); z0 += ex; a00 = fmaf(ex, v0, a00); a01 = fmaf(ex, v1, a01);
        ex = GEXP(q1.y, edv.y, m1); z1 += ex; a10 = fmaf(ex, v0, a10); a11 = fmaf(ex, v1, a11);
        ex = GEXP(q1.z, edv.z, m2); z2 += ex; a20 = fmaf(ex, v0, a20); a21 = fmaf(ex, v1, a21);
        ex = GEXP(q1.w, edv.w, m3); z3 += ex; a30 = fmaf(ex, v0, a30); a31 = fmaf(ex, v1, a31);
        v0 = bf2f((bf16u)(p2 & 0xFFFF)); v1 = bf2f((bf16u)(p2 >> 16));
        ex = GEXP(q2.x, edv.x, m0); z0 += ex; a00 = fmaf(ex, v0, a00); a01 = fmaf(ex, v1, a01);
        ex = GEXP(q2.y, edv.y, m1); z1 += ex; a10 = fmaf(ex, v0, a10); a11 = fmaf(ex, v1, a11);
        ex = GEXP(q2.z, edv.z, m2); z2 += ex; a20 = fmaf(ex, v0, a20); a21 = fmaf(ex, v1, a21);
        ex = GEXP(q2.w, edv.w, m3); z3 += ex; a30 = fmaf(ex, v0, a30); a31 = fmaf(ex, v1, a31);
        v0 = bf2f((bf16u)(p3 & 0xFFFF)); v1 = bf2f((bf16u)(p3 >> 16));
        ex = GEXP(q3.x, edv.x, m0); z0 += ex; a00 = fmaf(ex, v0, a00); a01 = fmaf(ex, v1, a01);
        ex = GEXP(q3.y, edv.y, m1); z1 += ex; a10 = fmaf(ex, v0, a10); a11 = fmaf(ex, v1, a11);
        ex = GEXP(q3.z, edv.z, m2); z2 += ex; a20 = fmaf(ex, v0, a20); a21 = fmaf(ex, v1, a21);
        ex = GEXP(q3.w, edv.w, m3); z3 += ex; a30 = fmaf(ex, v0, a30); a31 = fmaf(ex, v1, a31);
    }
    for (; ee < e1; ++ee) {
        int s = csr[ee];
        float4 s2 = *(const float4*)&es[s*4];
        unsigned pv = *(const unsigned*)&h2b[(size_t)s*128 + c];
        float v0 = bf2f((bf16u)(pv & 0xFFFF)), v1 = bf2f((bf16u)(pv >> 16));
        float ex;
        ex = GEXP(s2.x, edv.x, m0); z0 += ex; a00 = fmaf(ex, v0, a00); a01 = fmaf(ex, v1, a01);
        ex = GEXP(s2.y, edv.y, m1); z1 += ex; a10 = fmaf(ex, v0, a10); a11 = fmaf(ex, v1, a11);
        ex = GEXP(s2.z, edv.z, m2); z2 += ex; a20 = fmaf(ex, v0, a20); a21 = fmaf(ex, v1, a21);
        ex = GEXP(s2.w, edv.w, m3); z3 += ex; a30 = fmaf(ex, v0, a30); a31 = fmaf(ex, v1, a31);
    }
#undef GEXP
    size_t base = (size_t)i * 512 + c;
    float r; unsigned ow;
    r = 1.f/z0; ow = (unsigned)f2bf(a00*r) | ((unsigned)f2bf(a01*r) << 16);
    *(unsigned*)&agg[base]       = ow;
    r = 1.f/z1; ow = (unsigned)f2bf(a10*r) | ((unsigned)f2bf(a11*r) << 16);
    *(unsigned*)&agg[base + 128] = ow;
    r = 1.f/z2; ow = (unsigned)f2bf(a20*r) | ((unsigned)f2bf(a21*r) << 16);
    *(unsigned*)&agg[base + 256] = ow;
    r = 1.f/z3; ow = (unsigned)f2bf(a30*r) | ((unsigned)f2bf(a31*r) << 16);
    *(unsigned*)&agg[base + 384] = ow;
}

// ---------------- layer 4: fused BN3+ReLU + GCN aggregate (wave-per-node, ushort4, x4 unroll) ----------------
__global__ __launch_bounds__(256) void k_gcn4_agg(const bf16u* __restrict__ h3b,
                                                  const float* __restrict__ dis,
                                                  const int* __restrict__ rows,
                                                  const int* __restrict__ csr,
                                                  const float* __restrict__ sum,
                                                  const float* __restrict__ sumsq,
                                                  const float* __restrict__ g,
                                                  const float* __restrict__ b,
                                                  bf16u* __restrict__ xab) {
    int wave = threadIdx.x >> 6, q = threadIdx.x & 63;
    int i = blockIdx.x * 4 + wave;
    int c = q * 4;
    const float invN = 1.0f / (float)N_;
    float4 sm = make_float4(0.f,0.f,0.f,0.f), sq = make_float4(0.f,0.f,0.f,0.f);
#pragma unroll
    for (int s8 = 0; s8 < 8; ++s8) {
        float4 a = *(const float4*)&sum[s8*512 + c];
        float4 d = *(const float4*)&sumsq[s8*512 + c];
        sm.x += a.x; sm.y += a.y; sm.z += a.z; sm.w += a.w;
        sq.x += d.x; sq.y += d.y; sq.z += d.z; sq.w += d.w;
    }
    float4 gg = *(const float4*)&g[c];
    float4 bb = *(const float4*)&b[c];
    float mu, sc0, sc1, sc2, sc3, sh0, sh1, sh2, sh3;
    mu = sm.x*invN; sc0 = rsqrtf(sq.x*invN - mu*mu + EPSF)*gg.x; sh0 = bb.x - mu*sc0;
    mu = sm.y*invN; sc1 = rsqrtf(sq.y*invN - mu*mu + EPSF)*gg.y; sh1 = bb.y - mu*sc1;
    mu = sm.z*invN; sc2 = rsqrtf(sq.z*invN - mu*mu + EPSF)*gg.z; sh2 = bb.z - mu*sc2;
    mu = sm.w*invN; sc3 = rsqrtf(sq.w*invN - mu*mu + EPSF)*gg.w; sh3 = bb.w - mu*sc3;
    float di = dis[i];
    float a0, a1, a2, a3;
    {
        ushort4 u = *(const ushort4*)(h3b + (size_t)i*256 + c);
        float v, dd = di * di;
        v = fmaf(bf2f(u.x), sc0, sh0); v = v > 0.f ? v : 0.f; a0 = v * dd;
        v = fmaf(bf2f(u.y), sc1, sh1); v = v > 0.f ? v : 0.f; a1 = v * dd;
        v = fmaf(bf2f(u.z), sc2, sh2); v = v > 0.f ? v : 0.f; a2 = v * dd;
        v = fmaf(bf2f(u.w), sc3, sh3); v = v > 0.f ? v : 0.f; a3 = v * dd;
    }
    int e0 = rows[i], e1 = rows[i+1];
    int e = e0;
    for (; e + 3 < e1; e += 4) {
        int s0 = csr[e], s1 = csr[e+1], s2i = csr[e+2], s3i = csr[e+3];
        float w0 = dis[s0] * di, w1 = dis[s1] * di, w2 = dis[s2i] * di, w3 = dis[s3i] * di;
        ushort4 u0 = *(const ushort4*)(h3b + (size_t)s0*256 + c);
        ushort4 u1 = *(const ushort4*)(h3b + (size_t)s1*256 + c);
        ushort4 u2 = *(const ushort4*)(h3b + (size_t)s2i*256 + c);
        ushort4 u3 = *(const ushort4*)(h3b + (size_t)s3i*256 + c);
        float v;
        v = fmaf(bf2f(u0.x), sc0, sh0); v = v > 0.f ? v : 0.f; a0 += v * w0;
        v = fmaf(bf2f(u0.y), sc1, sh1); v = v > 0.f ? v : 0.f; a1 += v * w0;
        v = fmaf(bf2f(u0.z), sc2, sh2); v = v > 0.f ? v : 0.f; a2 += v * w0;
        v = fmaf(bf2f(u0.w), sc3, sh3); v = v > 0.f ? v : 0.f; a3 += v * w0;
        v = fmaf(bf2f(u1.x), sc0, sh0); v = v > 0.f ? v : 0.f; a0 += v * w1;
        v = fmaf(bf2f(u1.y), sc1, sh1); v = v > 0.f ? v : 0.f; a1 += v * w1;
        v = fmaf(bf2f(u1.z), sc2, sh2); v = v > 0.f ? v : 0.f; a2 += v * w1;
        v = fmaf(bf2f(u1.w), sc3, sh3); v = v > 0.f ? v : 0.f; a3 += v * w1;
        v = fmaf(bf2f(u2.x), sc0, sh0); v = v > 0.f ? v : 0.f; a0 += v * w2;
        v = fmaf(bf2f(u2.y), sc1, sh1); v = v > 0.f ? v : 0.f; a1 += v * w2;
        v = fmaf(bf2f(u2.z), sc2, sh2); v = v > 0.f ? v : 0.f; a2 += v * w2;
        v = fmaf(bf2f(u2.w), sc3, sh3); v = v > 0.f ? v : 0.f; a3 += v * w2;
        v = fmaf(bf2f(u3.x), sc0, sh0); v = v > 0.f ? v : 0.f; a0 += v * w3;
        v = fmaf(bf2f(u3.y), sc1, sh1); v = v > 0.f ? v : 0.f; a1 += v * w3;
        v = fmaf(bf2f(u3.z), sc2, sh2); v = v > 0.f ? v : 0.f; a2 += v * w3;
        v = fmaf(bf2f(u3.w), sc3, sh3); v = v > 0.f ? v : 0.f; a3 += v * w3;
    }
    for (; e < e1; ++e) {
        int s = csr[e];
        float w = dis[s] * di;
        ushort4 u = *(const ushort4*)(h3b + (size_t)s*256 + c);
        float v;
        v = fmaf(bf2f(u.x), sc0, sh0); v = v > 0.f ? v : 0.f; a0 += v * w;
        v = fmaf(bf2f(u.y), sc1, sh1); v = v > 0.f ? v : 0.f; a1 += v * w;
        v = fmaf(bf2f(u.z), sc2, sh2); v = v > 0.f ? v : 0.f; a2 += v * w;
        v = fmaf(bf2f(u.w), sc3, sh3); v = v > 0.f ? v : 0.f; a3 += v * w;
    }
    ushort4 o;
    o.x = f2bf(a0); o.y = f2bf(a1); o.z = f2bf(a2); o.w = f2bf(a3);
    *(ushort4*)(xab + (size_t)i*256 + c) = o;
}

// ---------------- pooling with fused BN4+ReLU (+ folded fc-init blocks) ----------------
__global__ void k_pool(const bf16u* __restrict__ h4b, const int* __restrict__ gb,
                       const float* __restrict__ sum, const float* __restrict__ sumsq,
                       const float* __restrict__ g, const float* __restrict__ b,
                       const float* __restrict__ fcb,
                       float* __restrict__ pooled, float* __restrict__ out) {
    int bidx = blockIdx.x;
    int t = threadIdx.x;
    if (bidx >= 512) {                 // fc-init: out = bias (independent work)
        int i = (bidx - 512) * 256 + t;
        out[i] = fcb[i & 1023];
        return;
    }
    int gi = bidx >> 4;
    int chunk = bidx & 15;
    const float invN = 1.0f / (float)N_;
    float su0=0.f, qq0=0.f, su1=0.f, qq1=0.f;
#pragma unroll
    for (int s8 = 0; s8 < 8; ++s8) {
        su0 += sum[s8*512 + t];       qq0 += sumsq[s8*512 + t];
        su1 += sum[s8*512 + 256 + t]; qq1 += sumsq[s8*512 + 256 + t];
    }
    float mu0 = su0 * invN;
    float sc0 = rsqrtf(qq0 * invN - mu0*mu0 + EPSF) * g[t];
    float sh0 = b[t] - mu0 * sc0;
    float mu1 = su1 * invN;
    float sc1 = rsqrtf(qq1 * invN - mu1*mu1 + EPSF) * g[t+256];
    float sh1 = b[t+256] - mu1 * sc1;
    int r0g = gb[gi], r1g = gb[gi+1];
    int n = r1g - r0g;
    if (n <= 0) return;
    int per = (n + 15) >> 4;
    int r0 = r0g + chunk * per;
    int r1 = min(r0 + per, r1g);
    if (r0 >= r1) return;
    float s0=0.f, s1=0.f, m0=0.f, m1=0.f;   // post-ReLU >= 0: max init 0 valid
    for (int r = r0; r < r1; ++r) {
        float v = fmaf(bf2f(h4b[(size_t)r*512 + t]), sc0, sh0);
        v = v > 0.f ? v : 0.f;
        s0 += v; m0 = fmaxf(m0, v);
        float w = fmaf(bf2f(h4b[(size_t)r*512 + 256 + t]), sc1, sh1);
        w = w > 0.f ? w : 0.f;
        s1 += w; m1 = fmaxf(m1, w);
    }
    atomicAdd(&pooled[gi*1024 + t], s0);
    atomicAdd(&pooled[gi*1024 + 256 + t], s1);
    atomicMax((int*)&pooled[gi*1024 + 512 + t],  __float_as_int(m0));
    atomicMax((int*)&pooled[gi*1024 + 768 + t],  __float_as_int(m1));
}

// ---------------- FC (K-split, float4, atomic reduce; mean-scale folded in) ----------------
#define FCKZ 16
#define FCKC (1024 / FCKZ)   // 64

__global__ __launch_bounds__(256) void k_fc2(const float* __restrict__ pooled,
                                             const float* __restrict__ w,
                                             const int* __restrict__ gb,
                                             float* __restrict__ out) {
    __shared__ float pr[FCKC];
    int g = blockIdx.x;
    int z = blockIdx.y;
    int t = threadIdx.x;
    int k0 = z * FCKC;
    if (t < FCKC) {
        float scale = (z < 8) ? 1.0f / fmaxf((float)(gb[g+1] - gb[g]), 1.0f) : 1.0f;
        pr[t] = pooled[g * 1024 + k0 + t] * scale;   // mean part needs 1/cnt
    }
    __syncthreads();
    int m0 = t * 4;
    float ax = 0.f, ay = 0.f, az = 0.f, aw = 0.f;
#pragma unroll 8
    for (int k = 0; k < FCKC; ++k) {
        const float4 wv = *(const float4*)&w[(size_t)(k0 + k) * 1024 + m0];
        float p = pr[k];
        ax += p * wv.x; ay += p * wv.y; az += p * wv.z; aw += p * wv.w;
    }
    atomicAdd(&out[g * 1024 + m0 + 0], ax);
    atomicAdd(&out[g * 1024 + m0 + 1], ay);
    atomicAdd(&out[g * 1024 + m0 + 2], az);
    atomicAdd(&out[g * 1024 + m0 + 3], aw);
}

// ---------------- host ----------------
extern "C" void kernel_launch(void* const* d_in, const int* in_sizes, int n_in,
                              void* d_out, int out_size, void* d_ws, size_t ws_size,
                              hipStream_t stream) {
    (void)in_sizes; (void)n_in; (void)out_size; (void)ws_size;
    const float* x       = (const float*)d_in[0];
    const int*   ei      = (const int*)d_in[1];
    const int*   batch   = (const int*)d_in[2];
    const float* gcn1_w  = (const float*)d_in[3];
    const float* gcn1_b  = (const float*)d_in[4];
    const float* sage_wl = (const float*)d_in[5];
    const float* sage_wr = (const float*)d_in[6];
    const float* sage_b  = (const float*)d_in[7];
    const float* gat_w   = (const float*)d_in[8];
    const float* gat_as  = (const float*)d_in[9];
    const float* gat_ad  = (const float*)d_in[10];
    const float* gat_b   = (const float*)d_in[11];
    const float* gcn4_w  = (const float*)d_in[12];
    const float* gcn4_b  = (const float*)d_in[13];
    const float* bn1_g   = (const float*)d_in[14];
    const float* bn1_b   = (const float*)d_in[15];
    const float* bn2_g   = (const float*)d_in[16];
    const float* bn2_b   = (const float*)d_in[17];
    const float* bn3_g   = (const float*)d_in[18];
    const float* bn3_b   = (const float*)d_in[19];
    const float* bn4_g   = (const float*)d_in[20];
    const float* bn4_b   = (const float*)d_in[21];
    const float* fc_w    = (const float*)d_in[22];
    const float* fc_b    = (const float*)d_in[23];
    float* out = (float*)d_out;

    char* w8 = (char*)d_ws;
    int*   indeg  = (int*)(w8 + OFF_INDEG);
    float* bns    = (float*)(w8 + OFF_BNS);   // [4][8][512] slabs per layer
    float* bnq    = (float*)(w8 + OFF_BNQ);
    float* pooled = (float*)(w8 + OFF_POOL);
    int*   gb     = (int*)(w8 + OFF_GB);
    int*   cnt    = (int*)(w8 + OFF_CNT);
    int*   rows   = (int*)(w8 + OFF_ROWS);
    int*   cursor = (int*)(w8 + OFF_CURSOR);
    int*   csr    = (int*)(w8 + OFF_CSR);
    float* dis    = (float*)(w8 + OFF_DIS);
    float* es     = (float*)(w8 + OFF_ES);
    float* ed     = (float*)(w8 + OFF_ED);
    float* part   = (float*)(w8 + OFF_PART);
    float* bn1sc  = (float*)(w8 + OFF_BN1C);
    float* bn1sh  = (float*)(w8 + OFF_BN1C + 256);
    float* xa     = (float*)(w8 + OFF_XA);
    bf16u* ab     = (bf16u*)(w8 + OFF_AB);
    bf16u* h2p    = (bf16u*)(w8 + OFF_H2P);
    bf16u* h2b    = (bf16u*)(w8 + OFF_H2B);
    bf16u* h3b    = (bf16u*)(w8 + OFF_H3B);
    bf16u* agg    = (bf16u*)(w8 + OFF_AGG);
    bf16u* xa4b   = (bf16u*)(w8 + OFF_XA4B);
    bf16u* wT1    = (bf16u*)(w8 + OFF_WT1);
    bf16u* wT2    = (bf16u*)(w8 + OFF_WT2);
    bf16u* wT3    = (bf16u*)(w8 + OFF_WT3);
    bf16u* h4b    = (bf16u*)(w8 + OFF_H4B);
    float* ves    = (float*)(w8 + OFF_VES);
    float* ved    = (float*)(w8 + OFF_VED);

    const int* srcE = ei;        // edge_index[0,:]
    const int* dstE = ei + E_;   // edge_index[1,:]

    // ---- setup: ONE small memset (~320 KB), then fused setup kernel ----
    hipMemsetAsync(w8, 0, OFF_MSET, stream);
    k_wconv_all<<<1605, 256, 0, stream>>>(gat_w, gcn4_w, sage_wl, sage_wr, batch,
                                          gat_as, gat_ad, dstE,
                                          wT1, wT2, wT3, gb, ves, ved, indeg);
    k_scan<<<1, 1024, 0, stream>>>(indeg, rows, cursor, dis);
    k_fill<<<E_/256, 256, 0, stream>>>(srcE, dstE, cursor, csr);

    // ---- layer 1+2 front: GCN agg -> xa; analytic BN1 (merged stats+finale) ----
    k_gcn1x<<<N_/4, 256, 0, stream>>>(x, dis, rows, csr, xa);
    k_xstats<<<64, 256, 0, stream>>>(xa, part, cnt, gcn1_w, gcn1_b, bn1_g, bn1_b,
                                     bn1sc, bn1sh);
    k_sage_l1<<<N_/4, 256, 0, stream>>>(xa, bn1sc, bn1sh, gcn1_w, rows, csr, ab);

    // ---- layer 2: SAGE 64->128 via single MFMA GEMM (stats fused in epilogue) ----
    {
        dim3 grid(1, N_/128);
        k_gemm_mfma<<<grid, 256, 0, stream>>>(ab, wT3, sage_b, h2p,
                                              bns + 4096, bnq + 4096, 128, 128);
    }
    k_bn_apply2b_attn<<<N_/4, 256, 0, stream>>>(h2p, bns + 4096, bnq + 4096, bn2_g, bn2_b,
                                                ves, ved, h2b, es, ed);

    // ---- layer 3: GAT — self-shift softmax aggregate, then 512->256 GEMM ----
    k_gat_agg2<<<N_/4, 256, 0, stream>>>(h2b, es, ed, rows, csr, agg);
    {
        dim3 grid(256/128, N_/128);
        k_gemm_mfma<<<grid, 256, 0, stream>>>(agg, wT1, gat_b, h3b,
                                              bns + 8192, bnq + 8192, 512, 256);
    }

    // ---- layer 4: fused BN3+ReLU+aggregate, MFMA GEMM 256->512 (stats fused) ----
    k_gcn4_agg<<<N_/4, 256, 0, stream>>>(h3b, dis, rows, csr, bns + 8192, bnq + 8192,
                                         bn3_g, bn3_b, xa4b);
    {
        dim3 grid(512/128, N_/128);
        k_gemm_mfma<<<grid, 256, 0, stream>>>(xa4b, wT2, gcn4_b, h4b,
                                              bns + 12288, bnq + 12288, 256, 512);
    }

    // ---- pooling with fused BN4+ReLU (+fc-init blocks) -> [32,1024] ----
    k_pool<<<640, 256, 0, stream>>>(h4b, gb, bns + 12288, bnq + 12288, bn4_g, bn4_b,
                                    fc_b, pooled, out);

    // ---- FC 1024->1024 ----
    {
        dim3 grid(G_, FCKZ);
        k_fc2<<<grid, 256, 0, stream>>>(pooled, fc_w, gb, out);
    }
}